// Round 1
// baseline (702.815 us; speedup 1.0000x reference)
//
#include <hip/hip_runtime.h>
#include <math.h>

#define N_NODES 50000
#define N_EDGES 800000
// dims: IN=128, HIDDEN=128, NUM_CLASSES=64 (hard-coded)

// ---------------- GEMM: C[M x NCOL] = A[M x 128] @ W[128 x NCOL] ----------------
// 64-row x 64-col tile per block, K=128 staged once. LDS = 32KB(A) + 32KB(W) = 64KB.
// A tile stored XOR-swizzled to avoid bank conflicts on the 4-row strided reads.
__global__ __launch_bounds__(256) void gemm_k(const float* __restrict__ A,
                                              const float* __restrict__ W,
                                              float* __restrict__ C,
                                              int M, int NCOL) {
  __shared__ float As[64 * 128];
  __shared__ float Ws[128 * 64];
  const int row0 = blockIdx.x * 64;
  const int col0 = blockIdx.y * 64;
  const int tid  = threadIdx.x;

  // stage A tile (float4, coalesced), swizzle: element (r,k) -> As[r*128 + (k ^ ((r&7)*4))]
  #pragma unroll
  for (int i = 0; i < 8; ++i) {
    int l4 = tid + i * 256;            // 0..2047
    int r  = l4 >> 5;                  // 64 rows
    int k4 = l4 & 31;                  // 32 float4 per row
    float4 v = make_float4(0.f, 0.f, 0.f, 0.f);
    int gr = row0 + r;
    if (gr < M) v = reinterpret_cast<const float4*>(A)[gr * 32 + k4];
    int sw = (4 * k4) ^ ((r & 7) * 4); // stays within [0,128), 4-aligned
    *reinterpret_cast<float4*>(&As[r * 128 + sw]) = v;
  }
  // stage W tile (float4, coalesced), Ws[k*64 + c]
  #pragma unroll
  for (int i = 0; i < 8; ++i) {
    int l4 = tid + i * 256;            // 0..2047
    int k  = l4 >> 4;                  // 128 rows
    int c4 = l4 & 15;                  // 16 float4 per row
    reinterpret_cast<float4*>(Ws)[k * 16 + c4] =
        reinterpret_cast<const float4*>(W + k * NCOL + col0)[c4];
  }
  __syncthreads();

  const int r0 = (tid >> 4) * 4;   // 16 row-groups
  const int c0 = (tid & 15) * 4;   // 16 col-groups
  float acc[4][4] = {};
  #pragma unroll 4
  for (int k = 0; k < 128; ++k) {
    float4 b = *reinterpret_cast<const float4*>(&Ws[k * 64 + c0]);
    #pragma unroll
    for (int i = 0; i < 4; ++i) {
      int rr = r0 + i;
      float a = As[rr * 128 + (k ^ ((rr & 7) * 4))];
      acc[i][0] = fmaf(a, b.x, acc[i][0]);
      acc[i][1] = fmaf(a, b.y, acc[i][1]);
      acc[i][2] = fmaf(a, b.z, acc[i][2]);
      acc[i][3] = fmaf(a, b.w, acc[i][3]);
    }
  }
  #pragma unroll
  for (int i = 0; i < 4; ++i) {
    int gr = row0 + r0 + i;
    if (gr < M)
      *reinterpret_cast<float4*>(&C[gr * NCOL + col0 + c0]) =
          make_float4(acc[i][0], acc[i][1], acc[i][2], acc[i][3]);
  }
}

// ---------------- el/er: per-node dot of h row with attn vectors ----------------
__global__ __launch_bounds__(256) void elr_k(const float* __restrict__ h,
                                             const float* __restrict__ al,
                                             const float* __restrict__ ar,
                                             float* __restrict__ el,
                                             float* __restrict__ er, int N) {
  int w    = (blockIdx.x * 256 + threadIdx.x) >> 6;  // node = global wave id
  int lane = threadIdx.x & 63;
  if (w >= N) return;
  float2 hv = reinterpret_cast<const float2*>(h)[w * 64 + lane];
  float2 a  = reinterpret_cast<const float2*>(al)[lane];
  float2 b  = reinterpret_cast<const float2*>(ar)[lane];
  float sl = hv.x * a.x + hv.y * a.y;
  float sr = hv.x * b.x + hv.y * b.y;
  #pragma unroll
  for (int off = 32; off; off >>= 1) {
    sl += __shfl_xor(sl, off);
    sr += __shfl_xor(sr, off);
  }
  if (lane == 0) { el[w] = sl; er[w] = sr; }
}

// ---------------- CSR build ----------------
__global__ __launch_bounds__(256) void hist_k(const int* __restrict__ dst,
                                              int* __restrict__ deg, int E) {
  int e = blockIdx.x * 256 + threadIdx.x;
  if (e < E) atomicAdd(&deg[dst[e]], 1);
}

__global__ __launch_bounds__(256) void scan1_k(const int* __restrict__ deg,
                                               int* __restrict__ offs,
                                               int* __restrict__ bsum, int N) {
  __shared__ int s[256];
  int t = threadIdx.x;
  int i = blockIdx.x * 256 + t;
  int v = (i < N) ? deg[i] : 0;
  s[t] = v;
  __syncthreads();
  for (int o = 1; o < 256; o <<= 1) {
    int add = (t >= o) ? s[t - o] : 0;
    __syncthreads();
    s[t] += add;
    __syncthreads();
  }
  if (i < N) offs[i] = s[t] - v;          // exclusive within block
  if (t == 255) bsum[blockIdx.x] = s[255]; // block total
}

__global__ __launch_bounds__(256) void scan2_k(int* __restrict__ bsum, int nb) {
  __shared__ int s[256];
  int t = threadIdx.x;
  int v = (t < nb) ? bsum[t] : 0;
  s[t] = v;
  __syncthreads();
  for (int o = 1; o < 256; o <<= 1) {
    int add = (t >= o) ? s[t - o] : 0;
    __syncthreads();
    s[t] += add;
    __syncthreads();
  }
  if (t < nb) bsum[t] = s[t] - v;          // exclusive prefix of block totals
}

__global__ __launch_bounds__(256) void scan3_k(int* __restrict__ offs,
                                               const int* __restrict__ deg,
                                               const int* __restrict__ bsum, int N) {
  int i = blockIdx.x * 256 + threadIdx.x;
  if (i < N) {
    int o = offs[i] + bsum[blockIdx.x];
    offs[i] = o;
    if (i == N - 1) offs[N] = o + deg[i];
  }
}

__global__ __launch_bounds__(256) void scatter_k(const int* __restrict__ src,
                                                 const int* __restrict__ dst,
                                                 const int* __restrict__ offs,
                                                 int* __restrict__ cursor,
                                                 int* __restrict__ csr_src, int E) {
  int e = blockIdx.x * 256 + threadIdx.x;
  if (e < E) {
    int v = dst[e];
    int p = offs[v] + atomicAdd(&cursor[v], 1);
    csr_src[p] = src[e];
  }
}

// ---------------- edge softmax (per dst node, one wave) ----------------
__global__ __launch_bounds__(256) void softmax_k(const int* __restrict__ offs,
                                                 const int* __restrict__ csr_src,
                                                 const float* __restrict__ el,
                                                 const float* __restrict__ er,
                                                 float* __restrict__ alpha, int N) {
  int w    = (blockIdx.x * 256 + threadIdx.x) >> 6;
  int lane = threadIdx.x & 63;
  if (w >= N) return;
  int o0 = offs[w], o1 = offs[w + 1];
  int cnt = o1 - o0;
  if (cnt == 0) return;
  float erv = er[w];
  float m = -3.4e38f;
  for (int i = lane; i < cnt; i += 64) {
    int s = csr_src[o0 + i];
    float ev = el[s] + erv;
    ev = (ev >= 0.f) ? ev : 0.2f * ev;   // leaky_relu(0.2)
    m = fmaxf(m, ev);
  }
  #pragma unroll
  for (int off = 32; off; off >>= 1) m = fmaxf(m, __shfl_xor(m, off));
  float sum = 0.f;
  for (int i = lane; i < cnt; i += 64) {
    int s = csr_src[o0 + i];
    float ev = el[s] + erv;
    ev = (ev >= 0.f) ? ev : 0.2f * ev;
    float ee = __expf(ev - m);
    alpha[o0 + i] = ee;
    sum += ee;
  }
  #pragma unroll
  for (int off = 32; off; off >>= 1) sum += __shfl_xor(sum, off);
  float inv = 1.f / sum;
  for (int i = lane; i < cnt; i += 64) alpha[o0 + i] *= inv;
}

// ---------------- aggregation: out[v] = sum_{e in in(v)} alpha_e * hp[src_e] ----------------
// VEC=2 -> 128 features (float2/lane); VEC=1 -> 64 features. One wave per node.
template <int VEC, bool ELU>
__global__ __launch_bounds__(256) void agg_k(const int* __restrict__ offs,
                                             const int* __restrict__ csr_src,
                                             const float* __restrict__ alpha,
                                             const float* __restrict__ hp,
                                             const float* __restrict__ bias,
                                             float* __restrict__ out, int N) {
  int w    = (blockIdx.x * 256 + threadIdx.x) >> 6;
  int lane = threadIdx.x & 63;
  if (w >= N) return;
  int o0 = offs[w], o1 = offs[w + 1];
  if (VEC == 2) {
    float ax = 0.f, ay = 0.f;
    const float2* hp2 = reinterpret_cast<const float2*>(hp);
    for (int p = o0; p < o1; ++p) {
      float a = alpha[p];
      int s = csr_src[p];
      float2 v = hp2[s * 64 + lane];
      ax = fmaf(a, v.x, ax);
      ay = fmaf(a, v.y, ay);
    }
    if (ELU) {
      ax = (ax > 0.f) ? ax : expm1f(ax);
      ay = (ay > 0.f) ? ay : expm1f(ay);
    }
    if (bias) {
      float2 b = reinterpret_cast<const float2*>(bias)[lane];
      ax += b.x; ay += b.y;
    }
    reinterpret_cast<float2*>(out)[w * 64 + lane] = make_float2(ax, ay);
  } else {
    float ax = 0.f;
    for (int p = o0; p < o1; ++p) {
      float a = alpha[p];
      int s = csr_src[p];
      ax = fmaf(a, hp[s * 64 + lane], ax);
    }
    if (ELU) ax = (ax > 0.f) ? ax : expm1f(ax);
    if (bias) ax += bias[lane];
    out[w * 64 + lane] = ax;
  }
}

// ---------------- launch ----------------
extern "C" void kernel_launch(void* const* d_in, const int* in_sizes, int n_in,
                              void* d_out, int out_size, void* d_ws, size_t ws_size,
                              hipStream_t stream) {
  const float* x      = (const float*)d_in[0];
  const int*   src    = (const int*)d_in[1];
  const int*   dst    = (const int*)d_in[2];
  const float* W_gat  = (const float*)d_in[3];
  const float* attn_l = (const float*)d_in[4];
  const float* attn_r = (const float*)d_in[5];
  const float* W1     = (const float*)d_in[6];
  const float* b1     = (const float*)d_in[7];
  const float* W2     = (const float*)d_in[8];
  const float* b2     = (const float*)d_in[9];
  const float* Wc     = (const float*)d_in[10];
  const float* bc     = (const float*)d_in[11];
  float* out = (float*)d_out;

  char* ws = (char*)d_ws;
  size_t off = 0;
  auto walloc = [&](size_t bytes) -> void* {
    void* p = ws + off;
    off += (bytes + 255) & ~size_t(255);
    return p;
  };
  float* bufA    = (float*)walloc((size_t)N_NODES * 128 * 4);
  float* bufB    = (float*)walloc((size_t)N_NODES * 128 * 4);
  float* el      = (float*)walloc((size_t)N_NODES * 4);
  float* er      = (float*)walloc((size_t)N_NODES * 4);
  int*   deg     = (int*)walloc((size_t)N_NODES * 4);
  int*   offs    = (int*)walloc((size_t)(N_NODES + 1) * 4);
  int*   cursor  = (int*)walloc((size_t)N_NODES * 4);
  int*   csr_src = (int*)walloc((size_t)N_EDGES * 4);
  float* alpha   = (float*)walloc((size_t)N_EDGES * 4);
  int*   bsum    = (int*)walloc(1024);

  hipMemsetAsync(deg, 0, (size_t)N_NODES * 4, stream);
  hipMemsetAsync(cursor, 0, (size_t)N_NODES * 4, stream);

  const dim3 blk(256);
  const int nwave_blocks = (N_NODES + 3) / 4;        // 4 waves (nodes) per block
  const int nedge_blocks = (N_EDGES + 255) / 256;
  const int nscan_blocks = (N_NODES + 255) / 256;    // 196
  const int nrow_tiles   = (N_NODES + 63) / 64;      // 782

  // h = x @ W_gat
  gemm_k<<<dim3(nrow_tiles, 2), blk, 0, stream>>>(x, W_gat, bufA, N_NODES, 128);
  // el/er
  elr_k<<<dim3(nwave_blocks), blk, 0, stream>>>(bufA, attn_l, attn_r, el, er, N_NODES);
  // CSR by dst
  hist_k<<<dim3(nedge_blocks), blk, 0, stream>>>(dst, deg, N_EDGES);
  scan1_k<<<dim3(nscan_blocks), blk, 0, stream>>>(deg, offs, bsum, N_NODES);
  scan2_k<<<dim3(1), blk, 0, stream>>>(bsum, nscan_blocks);
  scan3_k<<<dim3(nscan_blocks), blk, 0, stream>>>(offs, deg, bsum, N_NODES);
  scatter_k<<<dim3(nedge_blocks), blk, 0, stream>>>(src, dst, offs, cursor, csr_src, N_EDGES);
  // edge softmax -> alpha (CSR order)
  softmax_k<<<dim3(nwave_blocks), blk, 0, stream>>>(offs, csr_src, el, er, alpha, N_NODES);
  // h1 = elu(agg(h))
  agg_k<2, true><<<dim3(nwave_blocks), blk, 0, stream>>>(offs, csr_src, alpha, bufA, nullptr, bufB, N_NODES);
  // gconv1: hp1 = h1 @ W1 ; h2 = agg(hp1) + b1
  gemm_k<<<dim3(nrow_tiles, 2), blk, 0, stream>>>(bufB, W1, bufA, N_NODES, 128);
  agg_k<2, false><<<dim3(nwave_blocks), blk, 0, stream>>>(offs, csr_src, alpha, bufA, b1, bufB, N_NODES);
  // gconv2
  gemm_k<<<dim3(nrow_tiles, 2), blk, 0, stream>>>(bufB, W2, bufA, N_NODES, 128);
  agg_k<2, false><<<dim3(nwave_blocks), blk, 0, stream>>>(offs, csr_src, alpha, bufA, b2, bufB, N_NODES);
  // classifier gconv: hp3 = h3 @ Wc (128->64) ; logits = agg(hp3) + bc
  gemm_k<<<dim3(nrow_tiles, 1), blk, 0, stream>>>(bufB, Wc, bufA, N_NODES, 64);
  agg_k<1, false><<<dim3(nwave_blocks), blk, 0, stream>>>(offs, csr_src, alpha, bufA, bc, out, N_NODES);
}

// Round 3
// 551.729 us; speedup vs baseline: 1.2738x; 1.2738x over previous
//
#include <hip/hip_runtime.h>
#include <math.h>

#define N_NODES 50000
#define N_EDGES 800000
// dims: IN=128, HIDDEN=128, NUM_CLASSES=64 (hard-coded)

// ---------------- GEMM: C[M x NCOL] = A[M x 128] @ W[128 x NCOL] ----------------
__global__ __launch_bounds__(256) void gemm_k(const float* __restrict__ A,
                                              const float* __restrict__ W,
                                              float* __restrict__ C,
                                              int M, int NCOL) {
  __shared__ float As[64 * 128];
  __shared__ float Ws[128 * 64];
  const int row0 = blockIdx.x * 64;
  const int col0 = blockIdx.y * 64;
  const int tid  = threadIdx.x;

  #pragma unroll
  for (int i = 0; i < 8; ++i) {
    int l4 = tid + i * 256;
    int r  = l4 >> 5;
    int k4 = l4 & 31;
    float4 v = make_float4(0.f, 0.f, 0.f, 0.f);
    int gr = row0 + r;
    if (gr < M) v = reinterpret_cast<const float4*>(A)[gr * 32 + k4];
    int sw = (4 * k4) ^ ((r & 7) * 4);
    *reinterpret_cast<float4*>(&As[r * 128 + sw]) = v;
  }
  #pragma unroll
  for (int i = 0; i < 8; ++i) {
    int l4 = tid + i * 256;
    int k  = l4 >> 4;
    int c4 = l4 & 15;
    reinterpret_cast<float4*>(Ws)[k * 16 + c4] =
        reinterpret_cast<const float4*>(W + k * NCOL + col0)[c4];
  }
  __syncthreads();

  const int r0 = (tid >> 4) * 4;
  const int c0 = (tid & 15) * 4;
  float acc[4][4] = {};
  #pragma unroll 4
  for (int k = 0; k < 128; ++k) {
    float4 b = *reinterpret_cast<const float4*>(&Ws[k * 64 + c0]);
    #pragma unroll
    for (int i = 0; i < 4; ++i) {
      int rr = r0 + i;
      float a = As[rr * 128 + (k ^ ((rr & 7) * 4))];
      acc[i][0] = fmaf(a, b.x, acc[i][0]);
      acc[i][1] = fmaf(a, b.y, acc[i][1]);
      acc[i][2] = fmaf(a, b.z, acc[i][2]);
      acc[i][3] = fmaf(a, b.w, acc[i][3]);
    }
  }
  #pragma unroll
  for (int i = 0; i < 4; ++i) {
    int gr = row0 + r0 + i;
    if (gr < M)
      *reinterpret_cast<float4*>(&C[gr * NCOL + col0 + c0]) =
          make_float4(acc[i][0], acc[i][1], acc[i][2], acc[i][3]);
  }
}

// ---------------- el/er ----------------
__global__ __launch_bounds__(256) void elr_k(const float* __restrict__ h,
                                             const float* __restrict__ al,
                                             const float* __restrict__ ar,
                                             float* __restrict__ el,
                                             float* __restrict__ er, int N) {
  int w    = (blockIdx.x * 256 + threadIdx.x) >> 6;
  int lane = threadIdx.x & 63;
  if (w >= N) return;
  float2 hv = reinterpret_cast<const float2*>(h)[w * 64 + lane];
  float2 a  = reinterpret_cast<const float2*>(al)[lane];
  float2 b  = reinterpret_cast<const float2*>(ar)[lane];
  float sl = hv.x * a.x + hv.y * a.y;
  float sr = hv.x * b.x + hv.y * b.y;
  #pragma unroll
  for (int off = 32; off; off >>= 1) {
    sl += __shfl_xor(sl, off);
    sr += __shfl_xor(sr, off);
  }
  if (lane == 0) { el[w] = sl; er[w] = sr; }
}

// ---------------- CSR build ----------------
__global__ __launch_bounds__(256) void hist_k(const int* __restrict__ dst,
                                              int* __restrict__ deg, int E) {
  int e = blockIdx.x * 256 + threadIdx.x;
  if (e < E) atomicAdd(&deg[dst[e]], 1);
}

__global__ __launch_bounds__(256) void scan1_k(const int* __restrict__ deg,
                                               int* __restrict__ offs,
                                               int* __restrict__ bsum, int N) {
  __shared__ int s[256];
  int t = threadIdx.x;
  int i = blockIdx.x * 256 + t;
  int v = (i < N) ? deg[i] : 0;
  s[t] = v;
  __syncthreads();
  for (int o = 1; o < 256; o <<= 1) {
    int add = (t >= o) ? s[t - o] : 0;
    __syncthreads();
    s[t] += add;
    __syncthreads();
  }
  if (i < N) offs[i] = s[t] - v;
  if (t == 255) bsum[blockIdx.x] = s[255];
}

__global__ __launch_bounds__(256) void scan2_k(int* __restrict__ bsum, int nb) {
  __shared__ int s[256];
  int t = threadIdx.x;
  int v = (t < nb) ? bsum[t] : 0;
  s[t] = v;
  __syncthreads();
  for (int o = 1; o < 256; o <<= 1) {
    int add = (t >= o) ? s[t - o] : 0;
    __syncthreads();
    s[t] += add;
    __syncthreads();
  }
  if (t < nb) bsum[t] = s[t] - v;
}

__global__ __launch_bounds__(256) void scan3_k(int* __restrict__ offs,
                                               const int* __restrict__ deg,
                                               const int* __restrict__ bsum, int N) {
  int i = blockIdx.x * 256 + threadIdx.x;
  if (i < N) {
    int o = offs[i] + bsum[blockIdx.x];
    offs[i] = o;
    if (i == N - 1) offs[N] = o + deg[i];
  }
}

__global__ __launch_bounds__(256) void scatter_k(const int* __restrict__ src,
                                                 const int* __restrict__ dst,
                                                 const int* __restrict__ offs,
                                                 int* __restrict__ cursor,
                                                 int* __restrict__ csr_src, int E) {
  int e = blockIdx.x * 256 + threadIdx.x;
  if (e < E) {
    int v = dst[e];
    int p = offs[v] + atomicAdd(&cursor[v], 1);
    csr_src[p] = src[e];
  }
}

// ---------------- edge softmax: register-cached single pass (cnt<=64 fast path) ----------------
// All __shfl_xor reductions execute fully converged (no divergent branch around them).
__global__ __launch_bounds__(256) void softmax_k(const int* __restrict__ offs,
                                                 const int* __restrict__ csr_src,
                                                 const float* __restrict__ el,
                                                 const float* __restrict__ er,
                                                 float* __restrict__ alpha, int N) {
  int w    = (blockIdx.x * 256 + threadIdx.x) >> 6;
  int lane = threadIdx.x & 63;
  if (w >= N) return;
  int o0 = offs[w], o1 = offs[w + 1];
  int cnt = o1 - o0;
  if (cnt == 0) return;
  float erv = er[w];
  if (cnt <= 64) {
    bool valid = lane < cnt;
    float ev = -3.4e38f;
    if (valid) {
      int s = csr_src[o0 + lane];
      float e0 = el[s] + erv;
      ev = (e0 >= 0.f) ? e0 : 0.2f * e0;
    }
    float m = ev;
    #pragma unroll
    for (int off = 32; off; off >>= 1) m = fmaxf(m, __shfl_xor(m, off));
    float ee = valid ? __expf(ev - m) : 0.f;
    float sum = ee;
    #pragma unroll
    for (int off = 32; off; off >>= 1) sum += __shfl_xor(sum, off);
    if (valid) alpha[o0 + lane] = ee / sum;
  } else {
    float m = -3.4e38f;
    for (int i = lane; i < cnt; i += 64) {
      int s = csr_src[o0 + i];
      float ev = el[s] + erv;
      ev = (ev >= 0.f) ? ev : 0.2f * ev;
      m = fmaxf(m, ev);
    }
    #pragma unroll
    for (int off = 32; off; off >>= 1) m = fmaxf(m, __shfl_xor(m, off));
    float sum = 0.f;
    for (int i = lane; i < cnt; i += 64) {
      int s = csr_src[o0 + i];
      float ev = el[s] + erv;
      ev = (ev >= 0.f) ? ev : 0.2f * ev;
      float ee = __expf(ev - m);
      alpha[o0 + i] = ee;
      sum += ee;
    }
    #pragma unroll
    for (int off = 32; off; off >>= 1) sum += __shfl_xor(sum, off);
    float inv = 1.f / sum;
    for (int i = lane; i < cnt; i += 64) alpha[o0 + i] *= inv;
  }
}

// ---------------- agg 128-feat: half-wave x float4, 2 edge slots, WAVE-UNIFORM loop ----------------
// Loop trip count is uniform across the wave, so every __shfl executes with all 64
// lanes active (divergent-trip-count shfl reads from inactive lanes = undefined — the R2 bug).
// Out-of-range edge slots are harmless: lanes >= cnt preloaded myA=0 (fma adds 0; myS=0 is
// a valid row to gather).
template <bool ELU>
__global__ __launch_bounds__(256) void agg128_k(const int* __restrict__ offs,
                                                const int* __restrict__ csr_src,
                                                const float* __restrict__ alpha,
                                                const float* __restrict__ hp,
                                                const float* __restrict__ bias,
                                                float* __restrict__ out, int N) {
  int w    = (blockIdx.x * 256 + threadIdx.x) >> 6;
  int lane = threadIdx.x & 63;
  if (w >= N) return;
  int o0 = offs[w], o1 = offs[w + 1];
  int cnt  = o1 - o0;
  int half = lane >> 5;          // edge slot 0/1
  int fl   = lane & 31;          // feature float4 lane (32 x 16B = 512B row)
  const float4* hp4 = reinterpret_cast<const float4*>(hp);

  int   myS = 0;
  float myA = 0.f;
  if (lane < cnt) { myS = csr_src[o0 + lane]; myA = alpha[o0 + lane]; }

  float4 acc0 = make_float4(0.f, 0.f, 0.f, 0.f);
  float4 acc1 = make_float4(0.f, 0.f, 0.f, 0.f);
  int cntc = cnt < 64 ? cnt : 64;
  for (int base = 0; base < cntc; base += 4) {   // uniform trip count
    int iA = base + half;        // covers base..base+1
    int iB = base + 2 + half;    // covers base+2..base+3  (max 63)
    int   sA = __shfl(myS, iA);
    float aA = __shfl(myA, iA);
    int   sB = __shfl(myS, iB);
    float aB = __shfl(myA, iB);
    float4 vA = hp4[sA * 32 + fl];
    float4 vB = hp4[sB * 32 + fl];
    acc0.x = fmaf(aA, vA.x, acc0.x); acc0.y = fmaf(aA, vA.y, acc0.y);
    acc0.z = fmaf(aA, vA.z, acc0.z); acc0.w = fmaf(aA, vA.w, acc0.w);
    acc1.x = fmaf(aB, vB.x, acc1.x); acc1.y = fmaf(aB, vB.y, acc1.y);
    acc1.z = fmaf(aB, vB.z, acc1.z); acc1.w = fmaf(aB, vB.w, acc1.w);
  }
  // rare tail: degree > 64 (direct loads, no shfl -> divergence-safe)
  for (int p = o0 + 64 + half; p < o1; p += 2) {
    int   s = csr_src[p];
    float a = alpha[p];
    float4 v = hp4[s * 32 + fl];
    acc0.x = fmaf(a, v.x, acc0.x); acc0.y = fmaf(a, v.y, acc0.y);
    acc0.z = fmaf(a, v.z, acc0.z); acc0.w = fmaf(a, v.w, acc0.w);
  }
  acc0.x += acc1.x; acc0.y += acc1.y; acc0.z += acc1.z; acc0.w += acc1.w;
  acc0.x += __shfl_xor(acc0.x, 32);
  acc0.y += __shfl_xor(acc0.y, 32);
  acc0.z += __shfl_xor(acc0.z, 32);
  acc0.w += __shfl_xor(acc0.w, 32);
  if (half == 0) {
    if (ELU) {
      acc0.x = (acc0.x > 0.f) ? acc0.x : expm1f(acc0.x);
      acc0.y = (acc0.y > 0.f) ? acc0.y : expm1f(acc0.y);
      acc0.z = (acc0.z > 0.f) ? acc0.z : expm1f(acc0.z);
      acc0.w = (acc0.w > 0.f) ? acc0.w : expm1f(acc0.w);
    }
    if (bias) {
      float4 b = reinterpret_cast<const float4*>(bias)[fl];
      acc0.x += b.x; acc0.y += b.y; acc0.z += b.z; acc0.w += b.w;
    }
    reinterpret_cast<float4*>(out)[w * 32 + fl] = acc0;
  }
}

// ---------------- agg 64-feat (classifier): quarter-wave x float4, 4+4 edge slots, uniform loop ----------------
__global__ __launch_bounds__(256) void agg64_k(const int* __restrict__ offs,
                                               const int* __restrict__ csr_src,
                                               const float* __restrict__ alpha,
                                               const float* __restrict__ hp,
                                               const float* __restrict__ bias,
                                               float* __restrict__ out, int N) {
  int w    = (blockIdx.x * 256 + threadIdx.x) >> 6;
  int lane = threadIdx.x & 63;
  if (w >= N) return;
  int o0 = offs[w], o1 = offs[w + 1];
  int cnt     = o1 - o0;
  int quarter = lane >> 4;       // edge slot 0..3
  int fl      = lane & 15;       // 16 x 16B = 256B = 64-float row
  const float4* hp4 = reinterpret_cast<const float4*>(hp);

  int   myS = 0;
  float myA = 0.f;
  if (lane < cnt) { myS = csr_src[o0 + lane]; myA = alpha[o0 + lane]; }

  float4 acc0 = make_float4(0.f, 0.f, 0.f, 0.f);
  float4 acc1 = make_float4(0.f, 0.f, 0.f, 0.f);
  int cntc = cnt < 64 ? cnt : 64;
  for (int base = 0; base < cntc; base += 8) {   // uniform trip count
    int iA = base + quarter;       // covers base..base+3
    int iB = base + 4 + quarter;   // covers base+4..base+7 (max 63)
    int   sA = __shfl(myS, iA);
    float aA = __shfl(myA, iA);
    int   sB = __shfl(myS, iB);
    float aB = __shfl(myA, iB);
    float4 vA = hp4[sA * 16 + fl];
    float4 vB = hp4[sB * 16 + fl];
    acc0.x = fmaf(aA, vA.x, acc0.x); acc0.y = fmaf(aA, vA.y, acc0.y);
    acc0.z = fmaf(aA, vA.z, acc0.z); acc0.w = fmaf(aA, vA.w, acc0.w);
    acc1.x = fmaf(aB, vB.x, acc1.x); acc1.y = fmaf(aB, vB.y, acc1.y);
    acc1.z = fmaf(aB, vB.z, acc1.z); acc1.w = fmaf(aB, vB.w, acc1.w);
  }
  for (int p = o0 + 64 + quarter; p < o1; p += 4) {
    int   s = csr_src[p];
    float a = alpha[p];
    float4 v = hp4[s * 16 + fl];
    acc0.x = fmaf(a, v.x, acc0.x); acc0.y = fmaf(a, v.y, acc0.y);
    acc0.z = fmaf(a, v.z, acc0.z); acc0.w = fmaf(a, v.w, acc0.w);
  }
  acc0.x += acc1.x; acc0.y += acc1.y; acc0.z += acc1.z; acc0.w += acc1.w;
  #pragma unroll
  for (int off = 16; off <= 32; off <<= 1) {
    acc0.x += __shfl_xor(acc0.x, off);
    acc0.y += __shfl_xor(acc0.y, off);
    acc0.z += __shfl_xor(acc0.z, off);
    acc0.w += __shfl_xor(acc0.w, off);
  }
  if (quarter == 0) {
    if (bias) {
      float4 b = reinterpret_cast<const float4*>(bias)[fl];
      acc0.x += b.x; acc0.y += b.y; acc0.z += b.z; acc0.w += b.w;
    }
    reinterpret_cast<float4*>(out)[w * 16 + fl] = acc0;
  }
}

// ---------------- launch ----------------
extern "C" void kernel_launch(void* const* d_in, const int* in_sizes, int n_in,
                              void* d_out, int out_size, void* d_ws, size_t ws_size,
                              hipStream_t stream) {
  const float* x      = (const float*)d_in[0];
  const int*   src    = (const int*)d_in[1];
  const int*   dst    = (const int*)d_in[2];
  const float* W_gat  = (const float*)d_in[3];
  const float* attn_l = (const float*)d_in[4];
  const float* attn_r = (const float*)d_in[5];
  const float* W1     = (const float*)d_in[6];
  const float* b1     = (const float*)d_in[7];
  const float* W2     = (const float*)d_in[8];
  const float* b2     = (const float*)d_in[9];
  const float* Wc     = (const float*)d_in[10];
  const float* bc     = (const float*)d_in[11];
  float* out = (float*)d_out;

  char* ws = (char*)d_ws;
  size_t off = 0;
  auto walloc = [&](size_t bytes) -> void* {
    void* p = ws + off;
    off += (bytes + 255) & ~size_t(255);
    return p;
  };
  float* bufA    = (float*)walloc((size_t)N_NODES * 128 * 4);
  float* bufB    = (float*)walloc((size_t)N_NODES * 128 * 4);
  float* el      = (float*)walloc((size_t)N_NODES * 4);
  float* er      = (float*)walloc((size_t)N_NODES * 4);
  int*   deg     = (int*)walloc((size_t)N_NODES * 2 * 4);  // deg + cursor adjacent
  int*   cursor  = deg + N_NODES;
  int*   offs    = (int*)walloc((size_t)(N_NODES + 1) * 4);
  int*   csr_src = (int*)walloc((size_t)N_EDGES * 4);
  float* alpha   = (float*)walloc((size_t)N_EDGES * 4);
  int*   bsum    = (int*)walloc(1024);

  hipMemsetAsync(deg, 0, (size_t)N_NODES * 2 * 4, stream);

  const dim3 blk(256);
  const int nwave_blocks = (N_NODES + 3) / 4;
  const int nedge_blocks = (N_EDGES + 255) / 256;
  const int nscan_blocks = (N_NODES + 255) / 256;
  const int nrow_tiles   = (N_NODES + 63) / 64;

  gemm_k<<<dim3(nrow_tiles, 2), blk, 0, stream>>>(x, W_gat, bufA, N_NODES, 128);
  elr_k<<<dim3(nwave_blocks), blk, 0, stream>>>(bufA, attn_l, attn_r, el, er, N_NODES);
  hist_k<<<dim3(nedge_blocks), blk, 0, stream>>>(dst, deg, N_EDGES);
  scan1_k<<<dim3(nscan_blocks), blk, 0, stream>>>(deg, offs, bsum, N_NODES);
  scan2_k<<<dim3(1), blk, 0, stream>>>(bsum, nscan_blocks);
  scan3_k<<<dim3(nscan_blocks), blk, 0, stream>>>(offs, deg, bsum, N_NODES);
  scatter_k<<<dim3(nedge_blocks), blk, 0, stream>>>(src, dst, offs, cursor, csr_src, N_EDGES);
  softmax_k<<<dim3(nwave_blocks), blk, 0, stream>>>(offs, csr_src, el, er, alpha, N_NODES);

  agg128_k<true><<<dim3(nwave_blocks), blk, 0, stream>>>(offs, csr_src, alpha, bufA, nullptr, bufB, N_NODES);
  gemm_k<<<dim3(nrow_tiles, 2), blk, 0, stream>>>(bufB, W1, bufA, N_NODES, 128);
  agg128_k<false><<<dim3(nwave_blocks), blk, 0, stream>>>(offs, csr_src, alpha, bufA, b1, bufB, N_NODES);
  gemm_k<<<dim3(nrow_tiles, 2), blk, 0, stream>>>(bufB, W2, bufA, N_NODES, 128);
  agg128_k<false><<<dim3(nwave_blocks), blk, 0, stream>>>(offs, csr_src, alpha, bufA, b2, bufB, N_NODES);
  gemm_k<<<dim3(nrow_tiles, 1), blk, 0, stream>>>(bufB, Wc, bufA, N_NODES, 64);
  agg64_k<<<dim3(nwave_blocks), blk, 0, stream>>>(offs, csr_src, alpha, bufA, bc, out, N_NODES);
}

// Round 4
// 551.619 us; speedup vs baseline: 1.2741x; 1.0002x over previous
//
#include <hip/hip_runtime.h>
#include <math.h>

#define N_NODES 50000
#define N_EDGES 800000
// dims: IN=128, HIDDEN=128, NUM_CLASSES=64 (hard-coded)

// ---------------- GEMM: C[M x NCOL] = A[M x 128] @ W[128 x NCOL] ----------------
__global__ __launch_bounds__(256) void gemm_k(const float* __restrict__ A,
                                              const float* __restrict__ W,
                                              float* __restrict__ C,
                                              int M, int NCOL) {
  __shared__ float As[64 * 128];
  __shared__ float Ws[128 * 64];
  const int row0 = blockIdx.x * 64;
  const int col0 = blockIdx.y * 64;
  const int tid  = threadIdx.x;

  #pragma unroll
  for (int i = 0; i < 8; ++i) {
    int l4 = tid + i * 256;
    int r  = l4 >> 5;
    int k4 = l4 & 31;
    float4 v = make_float4(0.f, 0.f, 0.f, 0.f);
    int gr = row0 + r;
    if (gr < M) v = reinterpret_cast<const float4*>(A)[gr * 32 + k4];
    int sw = (4 * k4) ^ ((r & 7) * 4);
    *reinterpret_cast<float4*>(&As[r * 128 + sw]) = v;
  }
  #pragma unroll
  for (int i = 0; i < 8; ++i) {
    int l4 = tid + i * 256;
    int k  = l4 >> 4;
    int c4 = l4 & 15;
    reinterpret_cast<float4*>(Ws)[k * 16 + c4] =
        reinterpret_cast<const float4*>(W + k * NCOL + col0)[c4];
  }
  __syncthreads();

  const int r0 = (tid >> 4) * 4;
  const int c0 = (tid & 15) * 4;
  float acc[4][4] = {};
  #pragma unroll 4
  for (int k = 0; k < 128; ++k) {
    float4 b = *reinterpret_cast<const float4*>(&Ws[k * 64 + c0]);
    #pragma unroll
    for (int i = 0; i < 4; ++i) {
      int rr = r0 + i;
      float a = As[rr * 128 + (k ^ ((rr & 7) * 4))];
      acc[i][0] = fmaf(a, b.x, acc[i][0]);
      acc[i][1] = fmaf(a, b.y, acc[i][1]);
      acc[i][2] = fmaf(a, b.z, acc[i][2]);
      acc[i][3] = fmaf(a, b.w, acc[i][3]);
    }
  }
  #pragma unroll
  for (int i = 0; i < 4; ++i) {
    int gr = row0 + r0 + i;
    if (gr < M)
      *reinterpret_cast<float4*>(&C[gr * NCOL + col0 + c0]) =
          make_float4(acc[i][0], acc[i][1], acc[i][2], acc[i][3]);
  }
}

// ---------------- el/er ----------------
__global__ __launch_bounds__(256) void elr_k(const float* __restrict__ h,
                                             const float* __restrict__ al,
                                             const float* __restrict__ ar,
                                             float* __restrict__ el,
                                             float* __restrict__ er, int N) {
  int w    = (blockIdx.x * 256 + threadIdx.x) >> 6;
  int lane = threadIdx.x & 63;
  if (w >= N) return;
  float2 hv = reinterpret_cast<const float2*>(h)[w * 64 + lane];
  float2 a  = reinterpret_cast<const float2*>(al)[lane];
  float2 b  = reinterpret_cast<const float2*>(ar)[lane];
  float sl = hv.x * a.x + hv.y * a.y;
  float sr = hv.x * b.x + hv.y * b.y;
  #pragma unroll
  for (int off = 32; off; off >>= 1) {
    sl += __shfl_xor(sl, off);
    sr += __shfl_xor(sr, off);
  }
  if (lane == 0) { el[w] = sl; er[w] = sr; }
}

// ---------------- CSR build ----------------
__global__ __launch_bounds__(256) void hist_k(const int* __restrict__ dst,
                                              int* __restrict__ deg, int E) {
  int e = blockIdx.x * 256 + threadIdx.x;
  if (e < E) atomicAdd(&deg[dst[e]], 1);
}

__global__ __launch_bounds__(256) void scan1_k(const int* __restrict__ deg,
                                               int* __restrict__ offs,
                                               int* __restrict__ bsum, int N) {
  __shared__ int s[256];
  int t = threadIdx.x;
  int i = blockIdx.x * 256 + t;
  int v = (i < N) ? deg[i] : 0;
  s[t] = v;
  __syncthreads();
  for (int o = 1; o < 256; o <<= 1) {
    int add = (t >= o) ? s[t - o] : 0;
    __syncthreads();
    s[t] += add;
    __syncthreads();
  }
  if (i < N) offs[i] = s[t] - v;
  if (t == 255) bsum[blockIdx.x] = s[255];
}

__global__ __launch_bounds__(256) void scan2_k(int* __restrict__ bsum, int nb) {
  __shared__ int s[256];
  int t = threadIdx.x;
  int v = (t < nb) ? bsum[t] : 0;
  s[t] = v;
  __syncthreads();
  for (int o = 1; o < 256; o <<= 1) {
    int add = (t >= o) ? s[t - o] : 0;
    __syncthreads();
    s[t] += add;
    __syncthreads();
  }
  if (t < nb) bsum[t] = s[t] - v;
}

__global__ __launch_bounds__(256) void scan3_k(int* __restrict__ offs,
                                               const int* __restrict__ deg,
                                               const int* __restrict__ bsum, int N) {
  int i = blockIdx.x * 256 + threadIdx.x;
  if (i < N) {
    int o = offs[i] + bsum[blockIdx.x];
    offs[i] = o;
    if (i == N - 1) offs[N] = o + deg[i];
  }
}

__global__ __launch_bounds__(256) void scatter_k(const int* __restrict__ src,
                                                 const int* __restrict__ dst,
                                                 const int* __restrict__ offs,
                                                 int* __restrict__ cursor,
                                                 int* __restrict__ csr_src, int E) {
  int e = blockIdx.x * 256 + threadIdx.x;
  if (e < E) {
    int v = dst[e];
    int p = offs[v] + atomicAdd(&cursor[v], 1);
    csr_src[p] = src[e];
  }
}

// ---------------- edge softmax ----------------
__global__ __launch_bounds__(256) void softmax_k(const int* __restrict__ offs,
                                                 const int* __restrict__ csr_src,
                                                 const float* __restrict__ el,
                                                 const float* __restrict__ er,
                                                 float* __restrict__ alpha, int N) {
  int w    = (blockIdx.x * 256 + threadIdx.x) >> 6;
  int lane = threadIdx.x & 63;
  if (w >= N) return;
  int o0 = offs[w], o1 = offs[w + 1];
  int cnt = o1 - o0;
  if (cnt == 0) return;
  float erv = er[w];
  if (cnt <= 64) {
    bool valid = lane < cnt;
    float ev = -3.4e38f;
    if (valid) {
      int s = csr_src[o0 + lane];
      float e0 = el[s] + erv;
      ev = (e0 >= 0.f) ? e0 : 0.2f * e0;
    }
    float m = ev;
    #pragma unroll
    for (int off = 32; off; off >>= 1) m = fmaxf(m, __shfl_xor(m, off));
    float ee = valid ? __expf(ev - m) : 0.f;
    float sum = ee;
    #pragma unroll
    for (int off = 32; off; off >>= 1) sum += __shfl_xor(sum, off);
    if (valid) alpha[o0 + lane] = ee / sum;
  } else {
    float m = -3.4e38f;
    for (int i = lane; i < cnt; i += 64) {
      int s = csr_src[o0 + i];
      float ev = el[s] + erv;
      ev = (ev >= 0.f) ? ev : 0.2f * ev;
      m = fmaxf(m, ev);
    }
    #pragma unroll
    for (int off = 32; off; off >>= 1) m = fmaxf(m, __shfl_xor(m, off));
    float sum = 0.f;
    for (int i = lane; i < cnt; i += 64) {
      int s = csr_src[o0 + i];
      float ev = el[s] + erv;
      ev = (ev >= 0.f) ? ev : 0.2f * ev;
      float ee = __expf(ev - m);
      alpha[o0 + i] = ee;
      sum += ee;
    }
    #pragma unroll
    for (int off = 32; off; off >>= 1) sum += __shfl_xor(sum, off);
    float inv = 1.f / sum;
    for (int i = lane; i < cnt; i += 64) alpha[o0 + i] *= inv;
  }
}

// ---------------- agg 128-feat: 4 gathers in flight, software-pipelined ----------------
// Half-wave (32 lanes x float4) covers one 512B row; slots half,2+half,4+half,6+half
// process 8 edges/iter. Trip count rounded UP to a multiple of 8: padded slots are
// safe because lanes >= cnt preloaded myA=0 (fma adds 0) and myS=0 (valid row).
// All __shfl run fully converged; next iter's 4 loads issue before current 16 FMAs.
template <bool ELU>
__global__ __launch_bounds__(256) void agg128_k(const int* __restrict__ offs,
                                                const int* __restrict__ csr_src,
                                                const float* __restrict__ alpha,
                                                const float* __restrict__ hp,
                                                const float* __restrict__ bias,
                                                float* __restrict__ out, int N) {
  int w    = (blockIdx.x * 256 + threadIdx.x) >> 6;
  int lane = threadIdx.x & 63;
  if (w >= N) return;
  int o0 = offs[w], o1 = offs[w + 1];
  int cnt  = o1 - o0;
  int half = lane >> 5;
  int fl   = lane & 31;
  const float4* hp4 = reinterpret_cast<const float4*>(hp);

  int   myS = 0;
  float myA = 0.f;
  if (lane < cnt) { myS = csr_src[o0 + lane]; myA = alpha[o0 + lane]; }

  float4 acc0 = make_float4(0.f, 0.f, 0.f, 0.f);
  float4 acc1 = make_float4(0.f, 0.f, 0.f, 0.f);
  float4 acc2 = make_float4(0.f, 0.f, 0.f, 0.f);
  float4 acc3 = make_float4(0.f, 0.f, 0.f, 0.f);
  int cntc = cnt < 64 ? cnt : 64;
  if (cntc > 0) {                       // wave-uniform branch
    int cr = (cntc + 7) & ~7;           // <= 64
    // prologue: slots 0..7
    int   sA = __shfl(myS, half),     sB = __shfl(myS, 2 + half);
    int   sC = __shfl(myS, 4 + half), sD = __shfl(myS, 6 + half);
    float aA = __shfl(myA, half),     aB = __shfl(myA, 2 + half);
    float aC = __shfl(myA, 4 + half), aD = __shfl(myA, 6 + half);
    float4 vA = hp4[sA * 32 + fl], vB = hp4[sB * 32 + fl];
    float4 vC = hp4[sC * 32 + fl], vD = hp4[sD * 32 + fl];
    for (int base = 8; base < cr; base += 8) {
      // issue next 4 gathers before consuming current
      int   tA = __shfl(myS, base + half),     tB = __shfl(myS, base + 2 + half);
      int   tC = __shfl(myS, base + 4 + half), tD = __shfl(myS, base + 6 + half);
      float nA = __shfl(myA, base + half),     nB = __shfl(myA, base + 2 + half);
      float nC = __shfl(myA, base + 4 + half), nD = __shfl(myA, base + 6 + half);
      float4 wA = hp4[tA * 32 + fl], wB = hp4[tB * 32 + fl];
      float4 wC = hp4[tC * 32 + fl], wD = hp4[tD * 32 + fl];
      acc0.x = fmaf(aA, vA.x, acc0.x); acc0.y = fmaf(aA, vA.y, acc0.y);
      acc0.z = fmaf(aA, vA.z, acc0.z); acc0.w = fmaf(aA, vA.w, acc0.w);
      acc1.x = fmaf(aB, vB.x, acc1.x); acc1.y = fmaf(aB, vB.y, acc1.y);
      acc1.z = fmaf(aB, vB.z, acc1.z); acc1.w = fmaf(aB, vB.w, acc1.w);
      acc2.x = fmaf(aC, vC.x, acc2.x); acc2.y = fmaf(aC, vC.y, acc2.y);
      acc2.z = fmaf(aC, vC.z, acc2.z); acc2.w = fmaf(aC, vC.w, acc2.w);
      acc3.x = fmaf(aD, vD.x, acc3.x); acc3.y = fmaf(aD, vD.y, acc3.y);
      acc3.z = fmaf(aD, vD.z, acc3.z); acc3.w = fmaf(aD, vD.w, acc3.w);
      vA = wA; vB = wB; vC = wC; vD = wD;
      aA = nA; aB = nB; aC = nC; aD = nD;
    }
    acc0.x = fmaf(aA, vA.x, acc0.x); acc0.y = fmaf(aA, vA.y, acc0.y);
    acc0.z = fmaf(aA, vA.z, acc0.z); acc0.w = fmaf(aA, vA.w, acc0.w);
    acc1.x = fmaf(aB, vB.x, acc1.x); acc1.y = fmaf(aB, vB.y, acc1.y);
    acc1.z = fmaf(aB, vB.z, acc1.z); acc1.w = fmaf(aB, vB.w, acc1.w);
    acc2.x = fmaf(aC, vC.x, acc2.x); acc2.y = fmaf(aC, vC.y, acc2.y);
    acc2.z = fmaf(aC, vC.z, acc2.z); acc2.w = fmaf(aC, vC.w, acc2.w);
    acc3.x = fmaf(aD, vD.x, acc3.x); acc3.y = fmaf(aD, vD.y, acc3.y);
    acc3.z = fmaf(aD, vD.z, acc3.z); acc3.w = fmaf(aD, vD.w, acc3.w);
  }
  // rare tail: degree > 64 (direct loads, no shfl)
  for (int p = o0 + 64 + half; p < o1; p += 2) {
    int   s = csr_src[p];
    float a = alpha[p];
    float4 v = hp4[s * 32 + fl];
    acc0.x = fmaf(a, v.x, acc0.x); acc0.y = fmaf(a, v.y, acc0.y);
    acc0.z = fmaf(a, v.z, acc0.z); acc0.w = fmaf(a, v.w, acc0.w);
  }
  acc0.x += acc1.x + acc2.x + acc3.x;
  acc0.y += acc1.y + acc2.y + acc3.y;
  acc0.z += acc1.z + acc2.z + acc3.z;
  acc0.w += acc1.w + acc2.w + acc3.w;
  acc0.x += __shfl_xor(acc0.x, 32);
  acc0.y += __shfl_xor(acc0.y, 32);
  acc0.z += __shfl_xor(acc0.z, 32);
  acc0.w += __shfl_xor(acc0.w, 32);
  if (half == 0) {
    if (ELU) {
      acc0.x = (acc0.x > 0.f) ? acc0.x : expm1f(acc0.x);
      acc0.y = (acc0.y > 0.f) ? acc0.y : expm1f(acc0.y);
      acc0.z = (acc0.z > 0.f) ? acc0.z : expm1f(acc0.z);
      acc0.w = (acc0.w > 0.f) ? acc0.w : expm1f(acc0.w);
    }
    if (bias) {
      float4 b = reinterpret_cast<const float4*>(bias)[fl];
      acc0.x += b.x; acc0.y += b.y; acc0.z += b.z; acc0.w += b.w;
    }
    reinterpret_cast<float4*>(out)[w * 32 + fl] = acc0;
  }
}

// ---------------- agg 64-feat: quarter-wave rows, 4 gathers in flight, pipelined ----------------
__global__ __launch_bounds__(256) void agg64_k(const int* __restrict__ offs,
                                               const int* __restrict__ csr_src,
                                               const float* __restrict__ alpha,
                                               const float* __restrict__ hp,
                                               const float* __restrict__ bias,
                                               float* __restrict__ out, int N) {
  int w    = (blockIdx.x * 256 + threadIdx.x) >> 6;
  int lane = threadIdx.x & 63;
  if (w >= N) return;
  int o0 = offs[w], o1 = offs[w + 1];
  int cnt = o1 - o0;
  int q   = lane >> 4;          // edge slot within group of 4
  int fl  = lane & 15;          // 16 x float4 = 256B row
  const float4* hp4 = reinterpret_cast<const float4*>(hp);

  int   myS = 0;
  float myA = 0.f;
  if (lane < cnt) { myS = csr_src[o0 + lane]; myA = alpha[o0 + lane]; }

  float4 acc0 = make_float4(0.f, 0.f, 0.f, 0.f);
  float4 acc1 = make_float4(0.f, 0.f, 0.f, 0.f);
  float4 acc2 = make_float4(0.f, 0.f, 0.f, 0.f);
  float4 acc3 = make_float4(0.f, 0.f, 0.f, 0.f);
  int cntc = cnt < 64 ? cnt : 64;
  if (cntc > 0) {
    int cr = (cntc + 15) & ~15;        // <= 64; base max 48, idx max 63
    int   sA = __shfl(myS, q),      sB = __shfl(myS, 4 + q);
    int   sC = __shfl(myS, 8 + q),  sD = __shfl(myS, 12 + q);
    float aA = __shfl(myA, q),      aB = __shfl(myA, 4 + q);
    float aC = __shfl(myA, 8 + q),  aD = __shfl(myA, 12 + q);
    float4 vA = hp4[sA * 16 + fl], vB = hp4[sB * 16 + fl];
    float4 vC = hp4[sC * 16 + fl], vD = hp4[sD * 16 + fl];
    for (int base = 16; base < cr; base += 16) {
      int   tA = __shfl(myS, base + q),      tB = __shfl(myS, base + 4 + q);
      int   tC = __shfl(myS, base + 8 + q),  tD = __shfl(myS, base + 12 + q);
      float nA = __shfl(myA, base + q),      nB = __shfl(myA, base + 4 + q);
      float nC = __shfl(myA, base + 8 + q),  nD = __shfl(myA, base + 12 + q);
      float4 wA = hp4[tA * 16 + fl], wB = hp4[tB * 16 + fl];
      float4 wC = hp4[tC * 16 + fl], wD = hp4[tD * 16 + fl];
      acc0.x = fmaf(aA, vA.x, acc0.x); acc0.y = fmaf(aA, vA.y, acc0.y);
      acc0.z = fmaf(aA, vA.z, acc0.z); acc0.w = fmaf(aA, vA.w, acc0.w);
      acc1.x = fmaf(aB, vB.x, acc1.x); acc1.y = fmaf(aB, vB.y, acc1.y);
      acc1.z = fmaf(aB, vB.z, acc1.z); acc1.w = fmaf(aB, vB.w, acc1.w);
      acc2.x = fmaf(aC, vC.x, acc2.x); acc2.y = fmaf(aC, vC.y, acc2.y);
      acc2.z = fmaf(aC, vC.z, acc2.z); acc2.w = fmaf(aC, vC.w, acc2.w);
      acc3.x = fmaf(aD, vD.x, acc3.x); acc3.y = fmaf(aD, vD.y, acc3.y);
      acc3.z = fmaf(aD, vD.z, acc3.z); acc3.w = fmaf(aD, vD.w, acc3.w);
      vA = wA; vB = wB; vC = wC; vD = wD;
      aA = nA; aB = nB; aC = nC; aD = nD;
    }
    acc0.x = fmaf(aA, vA.x, acc0.x); acc0.y = fmaf(aA, vA.y, acc0.y);
    acc0.z = fmaf(aA, vA.z, acc0.z); acc0.w = fmaf(aA, vA.w, acc0.w);
    acc1.x = fmaf(aB, vB.x, acc1.x); acc1.y = fmaf(aB, vB.y, acc1.y);
    acc1.z = fmaf(aB, vB.z, acc1.z); acc1.w = fmaf(aB, vB.w, acc1.w);
    acc2.x = fmaf(aC, vC.x, acc2.x); acc2.y = fmaf(aC, vC.y, acc2.y);
    acc2.z = fmaf(aC, vC.z, acc2.z); acc2.w = fmaf(aC, vC.w, acc2.w);
    acc3.x = fmaf(aD, vD.x, acc3.x); acc3.y = fmaf(aD, vD.y, acc3.y);
    acc3.z = fmaf(aD, vD.z, acc3.z); acc3.w = fmaf(aD, vD.w, acc3.w);
  }
  for (int p = o0 + 64 + q; p < o1; p += 4) {
    int   s = csr_src[p];
    float a = alpha[p];
    float4 v = hp4[s * 16 + fl];
    acc0.x = fmaf(a, v.x, acc0.x); acc0.y = fmaf(a, v.y, acc0.y);
    acc0.z = fmaf(a, v.z, acc0.z); acc0.w = fmaf(a, v.w, acc0.w);
  }
  acc0.x += acc1.x + acc2.x + acc3.x;
  acc0.y += acc1.y + acc2.y + acc3.y;
  acc0.z += acc1.z + acc2.z + acc3.z;
  acc0.w += acc1.w + acc2.w + acc3.w;
  #pragma unroll
  for (int off = 16; off <= 32; off <<= 1) {
    acc0.x += __shfl_xor(acc0.x, off);
    acc0.y += __shfl_xor(acc0.y, off);
    acc0.z += __shfl_xor(acc0.z, off);
    acc0.w += __shfl_xor(acc0.w, off);
  }
  if (q == 0) {
    if (bias) {
      float4 b = reinterpret_cast<const float4*>(bias)[fl];
      acc0.x += b.x; acc0.y += b.y; acc0.z += b.z; acc0.w += b.w;
    }
    reinterpret_cast<float4*>(out)[w * 16 + fl] = acc0;
  }
}

// ---------------- launch ----------------
extern "C" void kernel_launch(void* const* d_in, const int* in_sizes, int n_in,
                              void* d_out, int out_size, void* d_ws, size_t ws_size,
                              hipStream_t stream) {
  const float* x      = (const float*)d_in[0];
  const int*   src    = (const int*)d_in[1];
  const int*   dst    = (const int*)d_in[2];
  const float* W_gat  = (const float*)d_in[3];
  const float* attn_l = (const float*)d_in[4];
  const float* attn_r = (const float*)d_in[5];
  const float* W1     = (const float*)d_in[6];
  const float* b1     = (const float*)d_in[7];
  const float* W2     = (const float*)d_in[8];
  const float* b2     = (const float*)d_in[9];
  const float* Wc     = (const float*)d_in[10];
  const float* bc     = (const float*)d_in[11];
  float* out = (float*)d_out;

  char* ws = (char*)d_ws;
  size_t off = 0;
  auto walloc = [&](size_t bytes) -> void* {
    void* p = ws + off;
    off += (bytes + 255) & ~size_t(255);
    return p;
  };
  float* bufA    = (float*)walloc((size_t)N_NODES * 128 * 4);
  float* bufB    = (float*)walloc((size_t)N_NODES * 128 * 4);
  float* el      = (float*)walloc((size_t)N_NODES * 4);
  float* er      = (float*)walloc((size_t)N_NODES * 4);
  int*   deg     = (int*)walloc((size_t)N_NODES * 2 * 4);  // deg + cursor adjacent
  int*   cursor  = deg + N_NODES;
  int*   offs    = (int*)walloc((size_t)(N_NODES + 1) * 4);
  int*   csr_src = (int*)walloc((size_t)N_EDGES * 4);
  float* alpha   = (float*)walloc((size_t)N_EDGES * 4);
  int*   bsum    = (int*)walloc(1024);

  hipMemsetAsync(deg, 0, (size_t)N_NODES * 2 * 4, stream);

  const dim3 blk(256);
  const int nwave_blocks = (N_NODES + 3) / 4;
  const int nedge_blocks = (N_EDGES + 255) / 256;
  const int nscan_blocks = (N_NODES + 255) / 256;
  const int nrow_tiles   = (N_NODES + 63) / 64;

  gemm_k<<<dim3(nrow_tiles, 2), blk, 0, stream>>>(x, W_gat, bufA, N_NODES, 128);
  elr_k<<<dim3(nwave_blocks), blk, 0, stream>>>(bufA, attn_l, attn_r, el, er, N_NODES);
  hist_k<<<dim3(nedge_blocks), blk, 0, stream>>>(dst, deg, N_EDGES);
  scan1_k<<<dim3(nscan_blocks), blk, 0, stream>>>(deg, offs, bsum, N_NODES);
  scan2_k<<<dim3(1), blk, 0, stream>>>(bsum, nscan_blocks);
  scan3_k<<<dim3(nscan_blocks), blk, 0, stream>>>(offs, deg, bsum, N_NODES);
  scatter_k<<<dim3(nedge_blocks), blk, 0, stream>>>(src, dst, offs, cursor, csr_src, N_EDGES);
  softmax_k<<<dim3(nwave_blocks), blk, 0, stream>>>(offs, csr_src, el, er, alpha, N_NODES);

  agg128_k<true><<<dim3(nwave_blocks), blk, 0, stream>>>(offs, csr_src, alpha, bufA, nullptr, bufB, N_NODES);
  gemm_k<<<dim3(nrow_tiles, 2), blk, 0, stream>>>(bufB, W1, bufA, N_NODES, 128);
  agg128_k<false><<<dim3(nwave_blocks), blk, 0, stream>>>(offs, csr_src, alpha, bufA, b1, bufB, N_NODES);
  gemm_k<<<dim3(nrow_tiles, 2), blk, 0, stream>>>(bufB, W2, bufA, N_NODES, 128);
  agg128_k<false><<<dim3(nwave_blocks), blk, 0, stream>>>(offs, csr_src, alpha, bufA, b2, bufB, N_NODES);
  gemm_k<<<dim3(nrow_tiles, 1), blk, 0, stream>>>(bufB, Wc, bufA, N_NODES, 64);
  agg64_k<<<dim3(nwave_blocks), blk, 0, stream>>>(offs, csr_src, alpha, bufA, bc, out, N_NODES);
}

// Round 5
// 461.465 us; speedup vs baseline: 1.5230x; 1.1954x over previous
//
#include <hip/hip_runtime.h>
#include <hip/hip_fp16.h>
#include <math.h>

#define N_NODES 50000
#define N_EDGES 800000
// dims: IN=128, HIDDEN=128, NUM_CLASSES=64 (hard-coded)

// ---------------- GEMM: C16[M x NCOL] = fp16(A[M x 128] @ W[128 x NCOL]) ----------------
// Output fp16: it is only consumed by the gather-aggregations (halves gather traffic).
// ELR variant (gemm0) also computes el/er = h @ attn_{l,r} from in-register f32 accs
// (partial per 64-col block, shfl-reduced, atomicAdd; el/er pre-zeroed by memset).
template <bool ELR>
__global__ __launch_bounds__(256) void gemm_k(const float* __restrict__ A,
                                              const float* __restrict__ W,
                                              __half* __restrict__ C16,
                                              int M, int NCOL,
                                              const float* __restrict__ al,
                                              const float* __restrict__ ar,
                                              float* __restrict__ el,
                                              float* __restrict__ er) {
  __shared__ float As[64 * 128];
  __shared__ float Ws[128 * 64];
  const int row0 = blockIdx.x * 64;
  const int col0 = blockIdx.y * 64;
  const int tid  = threadIdx.x;

  #pragma unroll
  for (int i = 0; i < 8; ++i) {
    int l4 = tid + i * 256;
    int r  = l4 >> 5;
    int k4 = l4 & 31;
    float4 v = make_float4(0.f, 0.f, 0.f, 0.f);
    int gr = row0 + r;
    if (gr < M) v = reinterpret_cast<const float4*>(A)[gr * 32 + k4];
    int sw = (4 * k4) ^ ((r & 7) * 4);
    *reinterpret_cast<float4*>(&As[r * 128 + sw]) = v;
  }
  #pragma unroll
  for (int i = 0; i < 8; ++i) {
    int l4 = tid + i * 256;
    int k  = l4 >> 4;
    int c4 = l4 & 15;
    reinterpret_cast<float4*>(Ws)[k * 16 + c4] =
        reinterpret_cast<const float4*>(W + k * NCOL + col0)[c4];
  }
  __syncthreads();

  const int r0 = (tid >> 4) * 4;
  const int c0 = (tid & 15) * 4;
  float acc[4][4] = {};
  #pragma unroll 4
  for (int k = 0; k < 128; ++k) {
    float4 b = *reinterpret_cast<const float4*>(&Ws[k * 64 + c0]);
    #pragma unroll
    for (int i = 0; i < 4; ++i) {
      int rr = r0 + i;
      float a = As[rr * 128 + (k ^ ((rr & 7) * 4))];
      acc[i][0] = fmaf(a, b.x, acc[i][0]);
      acc[i][1] = fmaf(a, b.y, acc[i][1]);
      acc[i][2] = fmaf(a, b.z, acc[i][2]);
      acc[i][3] = fmaf(a, b.w, acc[i][3]);
    }
  }
  #pragma unroll
  for (int i = 0; i < 4; ++i) {
    int gr = row0 + r0 + i;
    if (gr < M) {
      __half2 h01 = __floats2half2_rn(acc[i][0], acc[i][1]);
      __half2 h23 = __floats2half2_rn(acc[i][2], acc[i][3]);
      uint2 pk;
      pk.x = *reinterpret_cast<unsigned int*>(&h01);
      pk.y = *reinterpret_cast<unsigned int*>(&h23);
      *reinterpret_cast<uint2*>(&C16[gr * NCOL + col0 + c0]) = pk;
    }
  }
  if (ELR) {
    float4 a4 = *reinterpret_cast<const float4*>(al + col0 + c0);
    float4 b4 = *reinterpret_cast<const float4*>(ar + col0 + c0);
    float pl[4], pr[4];
    #pragma unroll
    for (int i = 0; i < 4; ++i) {
      pl[i] = acc[i][0] * a4.x + acc[i][1] * a4.y + acc[i][2] * a4.z + acc[i][3] * a4.w;
      pr[i] = acc[i][0] * b4.x + acc[i][1] * b4.y + acc[i][2] * b4.z + acc[i][3] * b4.w;
    }
    #pragma unroll
    for (int off = 1; off <= 8; off <<= 1) {
      #pragma unroll
      for (int i = 0; i < 4; ++i) {
        pl[i] += __shfl_xor(pl[i], off);
        pr[i] += __shfl_xor(pr[i], off);
      }
    }
    if ((tid & 15) == 0) {
      #pragma unroll
      for (int i = 0; i < 4; ++i) {
        int gr = row0 + r0 + i;
        if (gr < M) {
          atomicAdd(&el[gr], pl[i]);
          atomicAdd(&er[gr], pr[i]);
        }
      }
    }
  }
}

// ---------------- CSR build ----------------
__global__ __launch_bounds__(256) void hist_k(const int* __restrict__ dst,
                                              int* __restrict__ deg, int E) {
  int e = blockIdx.x * 256 + threadIdx.x;
  if (e < E) atomicAdd(&deg[dst[e]], 1);
}

__global__ __launch_bounds__(256) void scan1_k(const int* __restrict__ deg,
                                               int* __restrict__ offs,
                                               int* __restrict__ bsum, int N) {
  __shared__ int s[256];
  int t = threadIdx.x;
  int i = blockIdx.x * 256 + t;
  int v = (i < N) ? deg[i] : 0;
  s[t] = v;
  __syncthreads();
  for (int o = 1; o < 256; o <<= 1) {
    int add = (t >= o) ? s[t - o] : 0;
    __syncthreads();
    s[t] += add;
    __syncthreads();
  }
  if (i < N) offs[i] = s[t] - v;
  if (t == 255) bsum[blockIdx.x] = s[255];
}

__global__ __launch_bounds__(256) void scan2_k(int* __restrict__ bsum, int nb) {
  __shared__ int s[256];
  int t = threadIdx.x;
  int v = (t < nb) ? bsum[t] : 0;
  s[t] = v;
  __syncthreads();
  for (int o = 1; o < 256; o <<= 1) {
    int add = (t >= o) ? s[t - o] : 0;
    __syncthreads();
    s[t] += add;
    __syncthreads();
  }
  if (t < nb) bsum[t] = s[t] - v;
}

__global__ __launch_bounds__(256) void scan3_k(int* __restrict__ offs,
                                               const int* __restrict__ deg,
                                               const int* __restrict__ bsum, int N) {
  int i = blockIdx.x * 256 + threadIdx.x;
  if (i < N) {
    int o = offs[i] + bsum[blockIdx.x];
    offs[i] = o;
    if (i == N - 1) offs[N] = o + deg[i];
  }
}

__global__ __launch_bounds__(256) void scatter_k(const int* __restrict__ src,
                                                 const int* __restrict__ dst,
                                                 const int* __restrict__ offs,
                                                 int* __restrict__ cursor,
                                                 int* __restrict__ csr_src, int E) {
  int e = blockIdx.x * 256 + threadIdx.x;
  if (e < E) {
    int v = dst[e];
    int p = offs[v] + atomicAdd(&cursor[v], 1);
    csr_src[p] = src[e];
  }
}

// ---------------- edge softmax ----------------
__global__ __launch_bounds__(256) void softmax_k(const int* __restrict__ offs,
                                                 const int* __restrict__ csr_src,
                                                 const float* __restrict__ el,
                                                 const float* __restrict__ er,
                                                 float* __restrict__ alpha, int N) {
  int w    = (blockIdx.x * 256 + threadIdx.x) >> 6;
  int lane = threadIdx.x & 63;
  if (w >= N) return;
  int o0 = offs[w], o1 = offs[w + 1];
  int cnt = o1 - o0;
  if (cnt == 0) return;
  float erv = er[w];
  if (cnt <= 64) {
    bool valid = lane < cnt;
    float ev = -3.4e38f;
    if (valid) {
      int s = csr_src[o0 + lane];
      float e0 = el[s] + erv;
      ev = (e0 >= 0.f) ? e0 : 0.2f * e0;
    }
    float m = ev;
    #pragma unroll
    for (int off = 32; off; off >>= 1) m = fmaxf(m, __shfl_xor(m, off));
    float ee = valid ? __expf(ev - m) : 0.f;
    float sum = ee;
    #pragma unroll
    for (int off = 32; off; off >>= 1) sum += __shfl_xor(sum, off);
    if (valid) alpha[o0 + lane] = ee / sum;
  } else {
    float m = -3.4e38f;
    for (int i = lane; i < cnt; i += 64) {
      int s = csr_src[o0 + i];
      float ev = el[s] + erv;
      ev = (ev >= 0.f) ? ev : 0.2f * ev;
      m = fmaxf(m, ev);
    }
    #pragma unroll
    for (int off = 32; off; off >>= 1) m = fmaxf(m, __shfl_xor(m, off));
    float sum = 0.f;
    for (int i = lane; i < cnt; i += 64) {
      int s = csr_src[o0 + i];
      float ev = el[s] + erv;
      ev = (ev >= 0.f) ? ev : 0.2f * ev;
      float ee = __expf(ev - m);
      alpha[o0 + i] = ee;
      sum += ee;
    }
    #pragma unroll
    for (int off = 32; off; off >>= 1) sum += __shfl_xor(sum, off);
    float inv = 1.f / sum;
    for (int i = lane; i < cnt; i += 64) alpha[o0 + i] *= inv;
  }
}

__device__ inline void fma8(float2 acc[4], uint4 u, float a) {
  __half2* h = reinterpret_cast<__half2*>(&u);
  #pragma unroll
  for (int j = 0; j < 4; ++j) {
    float2 f = __half22float2(h[j]);
    acc[j].x = fmaf(a, f.x, acc[j].x);
    acc[j].y = fmaf(a, f.y, acc[j].y);
  }
}

// ---------------- agg 128-feat fp16 gather: quarter-wave rows (16 lanes x 16B = 256B) ----------------
// 4 edge slots per load instr, 2-deep pipeline -> 8 edges/iter. Wave-uniform loop,
// padded slots safe (alpha=0, src=0). Accumulate f32, write f32.
template <bool ELU>
__global__ __launch_bounds__(256) void agg128h_k(const int* __restrict__ offs,
                                                 const int* __restrict__ csr_src,
                                                 const float* __restrict__ alpha,
                                                 const __half* __restrict__ hp,
                                                 const float* __restrict__ bias,
                                                 float* __restrict__ out, int N) {
  int w    = (blockIdx.x * 256 + threadIdx.x) >> 6;
  int lane = threadIdx.x & 63;
  if (w >= N) return;
  int o0 = offs[w], o1 = offs[w + 1];
  int cnt = o1 - o0;
  int q   = lane >> 4;           // edge slot 0..3
  int fl  = lane & 15;           // 16B feature chunk (8 halves)
  const uint4* hpq = reinterpret_cast<const uint4*>(hp);

  int   myS = 0;
  float myA = 0.f;
  if (lane < cnt) { myS = csr_src[o0 + lane]; myA = alpha[o0 + lane]; }

  float2 acc0[4] = {}, acc1[4] = {};
  int cntc = cnt < 64 ? cnt : 64;
  if (cntc > 0) {                         // wave-uniform
    int cr = (cntc + 7) & ~7;             // <= 64
    int   sA = __shfl(myS, q),     sB = __shfl(myS, 4 + q);
    float aA = __shfl(myA, q),     aB = __shfl(myA, 4 + q);
    uint4 vA = hpq[sA * 16 + fl], vB = hpq[sB * 16 + fl];
    for (int base = 8; base < cr; base += 8) {
      int   tA = __shfl(myS, base + q),     tB = __shfl(myS, base + 4 + q);
      float nA = __shfl(myA, base + q),     nB = __shfl(myA, base + 4 + q);
      uint4 wA = hpq[tA * 16 + fl], wB = hpq[tB * 16 + fl];
      fma8(acc0, vA, aA);
      fma8(acc1, vB, aB);
      vA = wA; vB = wB; aA = nA; aB = nB;
    }
    fma8(acc0, vA, aA);
    fma8(acc1, vB, aB);
  }
  // rare tail: degree > 64
  for (int p = o0 + 64 + q; p < o1; p += 4) {
    int   s = csr_src[p];
    float a = alpha[p];
    fma8(acc0, hpq[s * 16 + fl], a);
  }
  #pragma unroll
  for (int j = 0; j < 4; ++j) {
    acc0[j].x += acc1[j].x; acc0[j].y += acc1[j].y;
  }
  #pragma unroll
  for (int off = 16; off <= 32; off <<= 1) {
    #pragma unroll
    for (int j = 0; j < 4; ++j) {
      acc0[j].x += __shfl_xor(acc0[j].x, off);
      acc0[j].y += __shfl_xor(acc0[j].y, off);
    }
  }
  if (q == 0) {                 // lanes 0..15 write features [fl*8 .. fl*8+7]
    float o8[8];
    #pragma unroll
    for (int j = 0; j < 4; ++j) { o8[2 * j] = acc0[j].x; o8[2 * j + 1] = acc0[j].y; }
    if (ELU) {
      #pragma unroll
      for (int j = 0; j < 8; ++j) o8[j] = (o8[j] > 0.f) ? o8[j] : expm1f(o8[j]);
    }
    if (bias) {
      float4 b0 = reinterpret_cast<const float4*>(bias)[fl * 2];
      float4 b1 = reinterpret_cast<const float4*>(bias)[fl * 2 + 1];
      o8[0] += b0.x; o8[1] += b0.y; o8[2] += b0.z; o8[3] += b0.w;
      o8[4] += b1.x; o8[5] += b1.y; o8[6] += b1.z; o8[7] += b1.w;
    }
    float4* outp = reinterpret_cast<float4*>(out);
    outp[w * 32 + fl * 2]     = make_float4(o8[0], o8[1], o8[2], o8[3]);
    outp[w * 32 + fl * 2 + 1] = make_float4(o8[4], o8[5], o8[6], o8[7]);
  }
}

// ---------------- agg 64-feat fp16 gather: eighth-wave rows (8 lanes x 16B = 128B) ----------------
// 8 edge slots per load instr, 2-deep pipeline -> 16 edges/iter.
__global__ __launch_bounds__(256) void agg64h_k(const int* __restrict__ offs,
                                                const int* __restrict__ csr_src,
                                                const float* __restrict__ alpha,
                                                const __half* __restrict__ hp,
                                                const float* __restrict__ bias,
                                                float* __restrict__ out, int N) {
  int w    = (blockIdx.x * 256 + threadIdx.x) >> 6;
  int lane = threadIdx.x & 63;
  if (w >= N) return;
  int o0 = offs[w], o1 = offs[w + 1];
  int cnt = o1 - o0;
  int o   = lane >> 3;           // edge slot 0..7
  int fl  = lane & 7;            // 16B feature chunk (8 halves)
  const uint4* hpq = reinterpret_cast<const uint4*>(hp);

  int   myS = 0;
  float myA = 0.f;
  if (lane < cnt) { myS = csr_src[o0 + lane]; myA = alpha[o0 + lane]; }

  float2 acc0[4] = {}, acc1[4] = {};
  int cntc = cnt < 64 ? cnt : 64;
  if (cntc > 0) {
    int cr = (cntc + 15) & ~15;           // <= 64
    int   sA = __shfl(myS, o),     sB = __shfl(myS, 8 + o);
    float aA = __shfl(myA, o),     aB = __shfl(myA, 8 + o);
    uint4 vA = hpq[sA * 8 + fl], vB = hpq[sB * 8 + fl];
    for (int base = 16; base < cr; base += 16) {
      int   tA = __shfl(myS, base + o),     tB = __shfl(myS, base + 8 + o);
      float nA = __shfl(myA, base + o),     nB = __shfl(myA, base + 8 + o);
      uint4 wA = hpq[tA * 8 + fl], wB = hpq[tB * 8 + fl];
      fma8(acc0, vA, aA);
      fma8(acc1, vB, aB);
      vA = wA; vB = wB; aA = nA; aB = nB;
    }
    fma8(acc0, vA, aA);
    fma8(acc1, vB, aB);
  }
  for (int p = o0 + 64 + o; p < o1; p += 8) {
    int   s = csr_src[p];
    float a = alpha[p];
    fma8(acc0, hpq[s * 8 + fl], a);
  }
  #pragma unroll
  for (int j = 0; j < 4; ++j) {
    acc0[j].x += acc1[j].x; acc0[j].y += acc1[j].y;
  }
  #pragma unroll
  for (int off = 8; off <= 32; off <<= 1) {
    #pragma unroll
    for (int j = 0; j < 4; ++j) {
      acc0[j].x += __shfl_xor(acc0[j].x, off);
      acc0[j].y += __shfl_xor(acc0[j].y, off);
    }
  }
  if (o == 0) {                 // lanes 0..7 write features [fl*8 .. fl*8+7]
    float o8[8];
    #pragma unroll
    for (int j = 0; j < 4; ++j) { o8[2 * j] = acc0[j].x; o8[2 * j + 1] = acc0[j].y; }
    if (bias) {
      float4 b0 = reinterpret_cast<const float4*>(bias)[fl * 2];
      float4 b1 = reinterpret_cast<const float4*>(bias)[fl * 2 + 1];
      o8[0] += b0.x; o8[1] += b0.y; o8[2] += b0.z; o8[3] += b0.w;
      o8[4] += b1.x; o8[5] += b1.y; o8[6] += b1.z; o8[7] += b1.w;
    }
    float4* outp = reinterpret_cast<float4*>(out);
    outp[w * 16 + fl * 2]     = make_float4(o8[0], o8[1], o8[2], o8[3]);
    outp[w * 16 + fl * 2 + 1] = make_float4(o8[4], o8[5], o8[6], o8[7]);
  }
}

// ---------------- launch ----------------
extern "C" void kernel_launch(void* const* d_in, const int* in_sizes, int n_in,
                              void* d_out, int out_size, void* d_ws, size_t ws_size,
                              hipStream_t stream) {
  const float* x      = (const float*)d_in[0];
  const int*   src    = (const int*)d_in[1];
  const int*   dst    = (const int*)d_in[2];
  const float* W_gat  = (const float*)d_in[3];
  const float* attn_l = (const float*)d_in[4];
  const float* attn_r = (const float*)d_in[5];
  const float* W1     = (const float*)d_in[6];
  const float* b1     = (const float*)d_in[7];
  const float* W2     = (const float*)d_in[8];
  const float* b2     = (const float*)d_in[9];
  const float* Wc     = (const float*)d_in[10];
  const float* bc     = (const float*)d_in[11];
  float* out = (float*)d_out;

  char* ws = (char*)d_ws;
  size_t off = 0;
  auto walloc = [&](size_t bytes) -> void* {
    void* p = ws + off;
    off += (bytes + 255) & ~size_t(255);
    return p;
  };
  float*  F       = (float*)walloc((size_t)N_NODES * 128 * 4);   // f32 node features
  __half* H16     = (__half*)walloc((size_t)N_NODES * 128 * 2);  // fp16 gather operand
  int*    zblock  = (int*)walloc((size_t)N_NODES * 4 * 4);       // [deg|cursor|el|er], one memset
  int*    deg     = zblock;
  int*    cursor  = zblock + N_NODES;
  float*  el      = (float*)(zblock + 2 * N_NODES);
  float*  er      = (float*)(zblock + 3 * N_NODES);
  int*    offs    = (int*)walloc((size_t)(N_NODES + 1) * 4);
  int*    csr_src = (int*)walloc((size_t)N_EDGES * 4);
  float*  alpha   = (float*)walloc((size_t)N_EDGES * 4);
  int*    bsum    = (int*)walloc(1024);

  hipMemsetAsync(zblock, 0, (size_t)N_NODES * 4 * 4, stream);

  const dim3 blk(256);
  const int nwave_blocks = (N_NODES + 3) / 4;
  const int nedge_blocks = (N_EDGES + 255) / 256;
  const int nscan_blocks = (N_NODES + 255) / 256;
  const int nrow_tiles   = (N_NODES + 63) / 64;

  // h16 = fp16(x @ W_gat); el/er fused in epilogue
  gemm_k<true><<<dim3(nrow_tiles, 2), blk, 0, stream>>>(x, W_gat, H16, N_NODES, 128,
                                                        attn_l, attn_r, el, er);
  hist_k<<<dim3(nedge_blocks), blk, 0, stream>>>(dst, deg, N_EDGES);
  scan1_k<<<dim3(nscan_blocks), blk, 0, stream>>>(deg, offs, bsum, N_NODES);
  scan2_k<<<dim3(1), blk, 0, stream>>>(bsum, nscan_blocks);
  scan3_k<<<dim3(nscan_blocks), blk, 0, stream>>>(offs, deg, bsum, N_NODES);
  scatter_k<<<dim3(nedge_blocks), blk, 0, stream>>>(src, dst, offs, cursor, csr_src, N_EDGES);
  softmax_k<<<dim3(nwave_blocks), blk, 0, stream>>>(offs, csr_src, el, er, alpha, N_NODES);

  // h1 = elu(agg(h16))
  agg128h_k<true><<<dim3(nwave_blocks), blk, 0, stream>>>(offs, csr_src, alpha, H16, nullptr, F, N_NODES);
  // hp1 = fp16(h1 @ W1); h2 = agg(hp1) + b1
  gemm_k<false><<<dim3(nrow_tiles, 2), blk, 0, stream>>>(F, W1, H16, N_NODES, 128,
                                                         nullptr, nullptr, nullptr, nullptr);
  agg128h_k<false><<<dim3(nwave_blocks), blk, 0, stream>>>(offs, csr_src, alpha, H16, b1, F, N_NODES);
  // layer 2
  gemm_k<false><<<dim3(nrow_tiles, 2), blk, 0, stream>>>(F, W2, H16, N_NODES, 128,
                                                         nullptr, nullptr, nullptr, nullptr);
  agg128h_k<false><<<dim3(nwave_blocks), blk, 0, stream>>>(offs, csr_src, alpha, H16, b2, F, N_NODES);
  // classifier: hpc = fp16(h3 @ Wc); logits = agg(hpc) + bc
  gemm_k<false><<<dim3(nrow_tiles, 1), blk, 0, stream>>>(F, Wc, H16, N_NODES, 64,
                                                         nullptr, nullptr, nullptr, nullptr);
  agg64h_k<<<dim3(nwave_blocks), blk, 0, stream>>>(offs, csr_src, alpha, H16, bc, out, N_NODES);
}

// Round 6
// 356.702 us; speedup vs baseline: 1.9703x; 1.2937x over previous
//
#include <hip/hip_runtime.h>
#include <hip/hip_fp16.h>
#include <math.h>

#define N_NODES 50000
#define N_EDGES 800000
// dims: IN=128, HIDDEN=128, NUM_CLASSES=64 (hard-coded)

typedef _Float16 half8 __attribute__((ext_vector_type(8)));
typedef float floatx16 __attribute__((ext_vector_type(16)));

// ---------------- weight prep: W(f32) -> [hi|lo] fp16 in MFMA-B fragment layout ----------------
// Layout per matrix: half idx = (c*NCOL + n)*8 + j, where k = c*8 + j (chunk-major).
// hi at region base, lo at +K*NCOL halves. Regions: Wg@0, W1@32768, W2@65536, Wc@98304.
__global__ __launch_bounds__(256) void prep_k(const float* __restrict__ Wg,
                                              const float* __restrict__ W1,
                                              const float* __restrict__ W2,
                                              const float* __restrict__ Wc,
                                              __half* __restrict__ out) {
  int e = blockIdx.x * 256 + threadIdx.x;
  const float* W; _Float16* o; int sh, local;
  _Float16* ob = (_Float16*)out;
  if (e < 16384)      { W = Wg; o = ob;         sh = 7; local = e; }
  else if (e < 32768) { W = W1; o = ob + 32768; sh = 7; local = e - 16384; }
  else if (e < 49152) { W = W2; o = ob + 65536; sh = 7; local = e - 32768; }
  else if (e < 57344) { W = Wc; o = ob + 98304; sh = 6; local = e - 49152; }
  else return;
  int NC = 1 << sh;
  int k = local >> sh, n = local & (NC - 1);
  float w = W[k * NC + n];
  _Float16 hi = (_Float16)w;
  float lo = w - (float)hi;
  int oi = (((k >> 3) * NC + n) << 3) | (k & 7);
  o[oi] = hi;
  o[(NC << 7) + oi] = (_Float16)lo;   // +K*NC halves
}

// ---------------- MFMA GEMM: C16[M x NCOL] = fp16( A[M x 128] @ (Whi+Wlo) ) ----------------
// 128 rows/block, 4 waves, each wave owns a 32-row strip and all NCOL/32 col-tiles.
// A staged in LDS as [chunk=k>>3][row][j=k&7] (b128 frag reads, conflict-free).
// B fragments loaded directly from global (prep_k layout, L1/L2-resident).
// Split-W: D = A*Wlo + A*Whi accumulated in one f32 acc -> ~22-bit effective W.
// ELR (gemm0): el/er = h @ attn_{l,r} computed from EXACT f32 accs (pre-fp16-round),
// half-wave shfl reduction, direct store (block owns its rows; no atomics).
template <int NCOL, bool A16, bool ELR>
__global__ __launch_bounds__(256) void mgemm_k(const void* __restrict__ Ap,
                                               const __half* __restrict__ Whl,
                                               __half* __restrict__ C16, int M,
                                               const float* __restrict__ al,
                                               const float* __restrict__ ar,
                                               float* __restrict__ el,
                                               float* __restrict__ er) {
  __shared__ __half Al[16][129][8];   // 129-row pad: breaks chunk-stride bank aliasing on writes
  const int tid  = threadIdx.x;
  const int row0 = blockIdx.x * 128;
  const int lane = tid & 63;
  const int lane31 = lane & 31;
  const int q = lane >> 5;
  const int r = tid >> 6;             // wave id 0..3 = 32-row strip

  // ---- stage A tile (128 rows x 128 k) as fp16 fragments ----
  if (A16) {
    const uint4* A8 = (const uint4*)Ap;
    #pragma unroll
    for (int i = 0; i < 8; ++i) {
      int idx = tid + i * 256;
      int row = idx >> 4, c = idx & 15;
      int grow = row0 + row;
      uint4 v = make_uint4(0u, 0u, 0u, 0u);
      if (grow < M) v = A8[grow * 16 + c];
      *reinterpret_cast<uint4*>(&Al[c][row][0]) = v;
    }
  } else {
    const float4* A4 = (const float4*)Ap;
    #pragma unroll
    for (int i = 0; i < 8; ++i) {
      int idx = tid + i * 256;
      int row = idx >> 4, c = idx & 15;
      int grow = row0 + row;
      half8 hv = {};
      if (grow < M) {
        float4 a0 = A4[grow * 32 + c * 2];
        float4 a1 = A4[grow * 32 + c * 2 + 1];
        hv[0] = (_Float16)a0.x; hv[1] = (_Float16)a0.y;
        hv[2] = (_Float16)a0.z; hv[3] = (_Float16)a0.w;
        hv[4] = (_Float16)a1.x; hv[5] = (_Float16)a1.y;
        hv[6] = (_Float16)a1.z; hv[7] = (_Float16)a1.w;
      }
      *reinterpret_cast<half8*>(&Al[c][row][0]) = hv;
    }
  }
  __syncthreads();

  // ---- A fragments: afr[s] covers k = s*16 + q*8 + j for rows r*32 + lane31 ----
  half8 afr[8];
  #pragma unroll
  for (int s = 0; s < 8; ++s)
    afr[s] = *reinterpret_cast<const half8*>(&Al[2 * s + q][r * 32 + lane31][0]);

  const half8* B8 = reinterpret_cast<const half8*>(Whl);
  const int KN8 = 16 * NCOL;          // half8 count per W copy

  float elp[16], erp[16];
  if (ELR) {
    #pragma unroll
    for (int i = 0; i < 16; ++i) { elp[i] = 0.f; erp[i] = 0.f; }
  }

  #pragma unroll
  for (int tc = 0; tc < NCOL / 32; ++tc) {
    floatx16 acc = {};
    int nbase = tc * 32 + lane31;
    #pragma unroll
    for (int s = 0; s < 8; ++s) {
      int ci = (2 * s + q) * NCOL + nbase;
      half8 bl = B8[KN8 + ci];
      half8 bh = B8[ci];
      acc = __builtin_amdgcn_mfma_f32_32x32x16_f16(afr[s], bl, acc, 0, 0, 0);
      acc = __builtin_amdgcn_mfma_f32_32x32x16_f16(afr[s], bh, acc, 0, 0, 0);
    }
    if (ELR) {
      float alv = al[nbase], arv = ar[nbase];
      #pragma unroll
      for (int i = 0; i < 16; ++i) {
        elp[i] = fmaf(acc[i], alv, elp[i]);
        erp[i] = fmaf(acc[i], arv, erp[i]);
      }
    }
    #pragma unroll
    for (int i = 0; i < 16; ++i) {
      int rl = (i & 3) + 8 * (i >> 2) + 4 * q;   // C/D: col=lane31, row=rl
      int grow = row0 + r * 32 + rl;
      if (grow < M) C16[grow * NCOL + nbase] = __float2half(acc[i]);
    }
  }

  if (ELR) {
    #pragma unroll
    for (int off = 1; off <= 16; off <<= 1) {
      #pragma unroll
      for (int i = 0; i < 16; ++i) {
        elp[i] += __shfl_xor(elp[i], off);
        erp[i] += __shfl_xor(erp[i], off);
      }
    }
    if (lane31 == 0) {
      #pragma unroll
      for (int i = 0; i < 16; ++i) {
        int rl = (i & 3) + 8 * (i >> 2) + 4 * q;
        int grow = row0 + r * 32 + rl;
        if (grow < M) { el[grow] = elp[i]; er[grow] = erp[i]; }
      }
    }
  }
}

// ---------------- CSR build ----------------
__global__ __launch_bounds__(256) void hist_k(const int* __restrict__ dst,
                                              int* __restrict__ deg, int E) {
  int e = blockIdx.x * 256 + threadIdx.x;
  if (e < E) atomicAdd(&deg[dst[e]], 1);
}

__global__ __launch_bounds__(256) void scan1_k(const int* __restrict__ deg,
                                               int* __restrict__ offs,
                                               int* __restrict__ bsum, int N) {
  __shared__ int s[256];
  int t = threadIdx.x;
  int i = blockIdx.x * 256 + t;
  int v = (i < N) ? deg[i] : 0;
  s[t] = v;
  __syncthreads();
  for (int o = 1; o < 256; o <<= 1) {
    int add = (t >= o) ? s[t - o] : 0;
    __syncthreads();
    s[t] += add;
    __syncthreads();
  }
  if (i < N) offs[i] = s[t] - v;
  if (t == 255) bsum[blockIdx.x] = s[255];
}

__global__ __launch_bounds__(256) void scan2_k(int* __restrict__ bsum, int nb) {
  __shared__ int s[256];
  int t = threadIdx.x;
  int v = (t < nb) ? bsum[t] : 0;
  s[t] = v;
  __syncthreads();
  for (int o = 1; o < 256; o <<= 1) {
    int add = (t >= o) ? s[t - o] : 0;
    __syncthreads();
    s[t] += add;
    __syncthreads();
  }
  if (t < nb) bsum[t] = s[t] - v;
}

__global__ __launch_bounds__(256) void scan3_k(int* __restrict__ offs,
                                               const int* __restrict__ deg,
                                               const int* __restrict__ bsum, int N) {
  int i = blockIdx.x * 256 + threadIdx.x;
  if (i < N) {
    int o = offs[i] + bsum[blockIdx.x];
    offs[i] = o;
    if (i == N - 1) offs[N] = o + deg[i];
  }
}

__global__ __launch_bounds__(256) void scatter_k(const int* __restrict__ src,
                                                 const int* __restrict__ dst,
                                                 const int* __restrict__ offs,
                                                 int* __restrict__ cursor,
                                                 int* __restrict__ csr_src, int E) {
  int e = blockIdx.x * 256 + threadIdx.x;
  if (e < E) {
    int v = dst[e];
    int p = offs[v] + atomicAdd(&cursor[v], 1);
    csr_src[p] = src[e];
  }
}

// ---------------- edge softmax ----------------
__global__ __launch_bounds__(256) void softmax_k(const int* __restrict__ offs,
                                                 const int* __restrict__ csr_src,
                                                 const float* __restrict__ el,
                                                 const float* __restrict__ er,
                                                 float* __restrict__ alpha, int N) {
  int w    = (blockIdx.x * 256 + threadIdx.x) >> 6;
  int lane = threadIdx.x & 63;
  if (w >= N) return;
  int o0 = offs[w], o1 = offs[w + 1];
  int cnt = o1 - o0;
  if (cnt == 0) return;
  float erv = er[w];
  if (cnt <= 64) {
    bool valid = lane < cnt;
    float ev = -3.4e38f;
    if (valid) {
      int s = csr_src[o0 + lane];
      float e0 = el[s] + erv;
      ev = (e0 >= 0.f) ? e0 : 0.2f * e0;
    }
    float m = ev;
    #pragma unroll
    for (int off = 32; off; off >>= 1) m = fmaxf(m, __shfl_xor(m, off));
    float ee = valid ? __expf(ev - m) : 0.f;
    float sum = ee;
    #pragma unroll
    for (int off = 32; off; off >>= 1) sum += __shfl_xor(sum, off);
    if (valid) alpha[o0 + lane] = ee / sum;
  } else {
    float m = -3.4e38f;
    for (int i = lane; i < cnt; i += 64) {
      int s = csr_src[o0 + i];
      float ev = el[s] + erv;
      ev = (ev >= 0.f) ? ev : 0.2f * ev;
      m = fmaxf(m, ev);
    }
    #pragma unroll
    for (int off = 32; off; off >>= 1) m = fmaxf(m, __shfl_xor(m, off));
    float sum = 0.f;
    for (int i = lane; i < cnt; i += 64) {
      int s = csr_src[o0 + i];
      float ev = el[s] + erv;
      ev = (ev >= 0.f) ? ev : 0.2f * ev;
      float ee = __expf(ev - m);
      alpha[o0 + i] = ee;
      sum += ee;
    }
    #pragma unroll
    for (int off = 32; off; off >>= 1) sum += __shfl_xor(sum, off);
    float inv = 1.f / sum;
    for (int i = lane; i < cnt; i += 64) alpha[o0 + i] *= inv;
  }
}

__device__ inline void fma8(float2 acc[4], uint4 u, float a) {
  __half2* h = reinterpret_cast<__half2*>(&u);
  #pragma unroll
  for (int j = 0; j < 4; ++j) {
    float2 f = __half22float2(h[j]);
    acc[j].x = fmaf(a, f.x, acc[j].x);
    acc[j].y = fmaf(a, f.y, acc[j].y);
  }
}

// ---------------- agg 128-feat fp16 gather -> fp16 out: quarter-wave rows ----------------
template <bool ELU>
__global__ __launch_bounds__(256) void agg128h_k(const int* __restrict__ offs,
                                                 const int* __restrict__ csr_src,
                                                 const float* __restrict__ alpha,
                                                 const __half* __restrict__ hp,
                                                 const float* __restrict__ bias,
                                                 __half* __restrict__ out, int N) {
  int w    = (blockIdx.x * 256 + threadIdx.x) >> 6;
  int lane = threadIdx.x & 63;
  if (w >= N) return;
  int o0 = offs[w], o1 = offs[w + 1];
  int cnt = o1 - o0;
  int q   = lane >> 4;           // edge slot 0..3
  int fl  = lane & 15;           // 16B feature chunk (8 halves)
  const uint4* hpq = reinterpret_cast<const uint4*>(hp);

  int   myS = 0;
  float myA = 0.f;
  if (lane < cnt) { myS = csr_src[o0 + lane]; myA = alpha[o0 + lane]; }

  float2 acc0[4] = {}, acc1[4] = {};
  int cntc = cnt < 64 ? cnt : 64;
  if (cntc > 0) {                         // wave-uniform
    int cr = (cntc + 7) & ~7;             // <= 64
    int   sA = __shfl(myS, q),     sB = __shfl(myS, 4 + q);
    float aA = __shfl(myA, q),     aB = __shfl(myA, 4 + q);
    uint4 vA = hpq[sA * 16 + fl], vB = hpq[sB * 16 + fl];
    for (int base = 8; base < cr; base += 8) {
      int   tA = __shfl(myS, base + q),     tB = __shfl(myS, base + 4 + q);
      float nA = __shfl(myA, base + q),     nB = __shfl(myA, base + 4 + q);
      uint4 wA = hpq[tA * 16 + fl], wB = hpq[tB * 16 + fl];
      fma8(acc0, vA, aA);
      fma8(acc1, vB, aB);
      vA = wA; vB = wB; aA = nA; aB = nB;
    }
    fma8(acc0, vA, aA);
    fma8(acc1, vB, aB);
  }
  for (int p = o0 + 64 + q; p < o1; p += 4) {
    fma8(acc0, hpq[csr_src[p] * 16 + fl], alpha[p]);
  }
  #pragma unroll
  for (int j = 0; j < 4; ++j) { acc0[j].x += acc1[j].x; acc0[j].y += acc1[j].y; }
  #pragma unroll
  for (int off = 16; off <= 32; off <<= 1) {
    #pragma unroll
    for (int j = 0; j < 4; ++j) {
      acc0[j].x += __shfl_xor(acc0[j].x, off);
      acc0[j].y += __shfl_xor(acc0[j].y, off);
    }
  }
  if (q == 0) {                 // lanes 0..15 write features [fl*8 .. fl*8+7]
    float o8[8];
    #pragma unroll
    for (int j = 0; j < 4; ++j) { o8[2 * j] = acc0[j].x; o8[2 * j + 1] = acc0[j].y; }
    if (ELU) {
      #pragma unroll
      for (int j = 0; j < 8; ++j) o8[j] = (o8[j] > 0.f) ? o8[j] : expm1f(o8[j]);
    }
    if (bias) {
      float4 b0 = reinterpret_cast<const float4*>(bias)[fl * 2];
      float4 b1 = reinterpret_cast<const float4*>(bias)[fl * 2 + 1];
      o8[0] += b0.x; o8[1] += b0.y; o8[2] += b0.z; o8[3] += b0.w;
      o8[4] += b1.x; o8[5] += b1.y; o8[6] += b1.z; o8[7] += b1.w;
    }
    __half2 p0 = __floats2half2_rn(o8[0], o8[1]);
    __half2 p1 = __floats2half2_rn(o8[2], o8[3]);
    __half2 p2 = __floats2half2_rn(o8[4], o8[5]);
    __half2 p3 = __floats2half2_rn(o8[6], o8[7]);
    uint4 pk;
    pk.x = *reinterpret_cast<unsigned*>(&p0);
    pk.y = *reinterpret_cast<unsigned*>(&p1);
    pk.z = *reinterpret_cast<unsigned*>(&p2);
    pk.w = *reinterpret_cast<unsigned*>(&p3);
    *reinterpret_cast<uint4*>(&out[w * 128 + fl * 8]) = pk;
  }
}

// ---------------- agg 64-feat fp16 gather -> f32 out (final logits) ----------------
__global__ __launch_bounds__(256) void agg64h_k(const int* __restrict__ offs,
                                                const int* __restrict__ csr_src,
                                                const float* __restrict__ alpha,
                                                const __half* __restrict__ hp,
                                                const float* __restrict__ bias,
                                                float* __restrict__ out, int N) {
  int w    = (blockIdx.x * 256 + threadIdx.x) >> 6;
  int lane = threadIdx.x & 63;
  if (w >= N) return;
  int o0 = offs[w], o1 = offs[w + 1];
  int cnt = o1 - o0;
  int o   = lane >> 3;           // edge slot 0..7
  int fl  = lane & 7;            // 16B feature chunk (8 halves)
  const uint4* hpq = reinterpret_cast<const uint4*>(hp);

  int   myS = 0;
  float myA = 0.f;
  if (lane < cnt) { myS = csr_src[o0 + lane]; myA = alpha[o0 + lane]; }

  float2 acc0[4] = {}, acc1[4] = {};
  int cntc = cnt < 64 ? cnt : 64;
  if (cntc > 0) {
    int cr = (cntc + 15) & ~15;           // <= 64
    int   sA = __shfl(myS, o),     sB = __shfl(myS, 8 + o);
    float aA = __shfl(myA, o),     aB = __shfl(myA, 8 + o);
    uint4 vA = hpq[sA * 8 + fl], vB = hpq[sB * 8 + fl];
    for (int base = 16; base < cr; base += 16) {
      int   tA = __shfl(myS, base + o),     tB = __shfl(myS, base + 8 + o);
      float nA = __shfl(myA, base + o),     nB = __shfl(myA, base + 8 + o);
      uint4 wA = hpq[tA * 8 + fl], wB = hpq[tB * 8 + fl];
      fma8(acc0, vA, aA);
      fma8(acc1, vB, aB);
      vA = wA; vB = wB; aA = nA; aB = nB;
    }
    fma8(acc0, vA, aA);
    fma8(acc1, vB, aB);
  }
  for (int p = o0 + 64 + o; p < o1; p += 8) {
    fma8(acc0, hpq[csr_src[p] * 8 + fl], alpha[p]);
  }
  #pragma unroll
  for (int j = 0; j < 4; ++j) { acc0[j].x += acc1[j].x; acc0[j].y += acc1[j].y; }
  #pragma unroll
  for (int off = 8; off <= 32; off <<= 1) {
    #pragma unroll
    for (int j = 0; j < 4; ++j) {
      acc0[j].x += __shfl_xor(acc0[j].x, off);
      acc0[j].y += __shfl_xor(acc0[j].y, off);
    }
  }
  if (o == 0) {                 // lanes 0..7 write features [fl*8 .. fl*8+7]
    float o8[8];
    #pragma unroll
    for (int j = 0; j < 4; ++j) { o8[2 * j] = acc0[j].x; o8[2 * j + 1] = acc0[j].y; }
    if (bias) {
      float4 b0 = reinterpret_cast<const float4*>(bias)[fl * 2];
      float4 b1 = reinterpret_cast<const float4*>(bias)[fl * 2 + 1];
      o8[0] += b0.x; o8[1] += b0.y; o8[2] += b0.z; o8[3] += b0.w;
      o8[4] += b1.x; o8[5] += b1.y; o8[6] += b1.z; o8[7] += b1.w;
    }
    float4* outp = reinterpret_cast<float4*>(out);
    outp[w * 16 + fl * 2]     = make_float4(o8[0], o8[1], o8[2], o8[3]);
    outp[w * 16 + fl * 2 + 1] = make_float4(o8[4], o8[5], o8[6], o8[7]);
  }
}

// ---------------- launch ----------------
extern "C" void kernel_launch(void* const* d_in, const int* in_sizes, int n_in,
                              void* d_out, int out_size, void* d_ws, size_t ws_size,
                              hipStream_t stream) {
  const float* x      = (const float*)d_in[0];
  const int*   src    = (const int*)d_in[1];
  const int*   dst    = (const int*)d_in[2];
  const float* W_gat  = (const float*)d_in[3];
  const float* attn_l = (const float*)d_in[4];
  const float* attn_r = (const float*)d_in[5];
  const float* W1     = (const float*)d_in[6];
  const float* b1     = (const float*)d_in[7];
  const float* W2     = (const float*)d_in[8];
  const float* b2     = (const float*)d_in[9];
  const float* Wc     = (const float*)d_in[10];
  const float* bc     = (const float*)d_in[11];
  float* out = (float*)d_out;

  char* ws = (char*)d_ws;
  size_t off = 0;
  auto walloc = [&](size_t bytes) -> void* {
    void* p = ws + off;
    off += (bytes + 255) & ~size_t(255);
    return p;
  };
  __half* P16     = (__half*)walloc((size_t)N_NODES * 128 * 2);  // gemm out / gather operand
  __half* F16     = (__half*)walloc((size_t)N_NODES * 128 * 2);  // agg out / gemm A operand
  float*  el      = (float*)walloc((size_t)N_NODES * 4);
  float*  er      = (float*)walloc((size_t)N_NODES * 4);
  int*    deg     = (int*)walloc((size_t)N_NODES * 2 * 4);       // [deg|cursor]
  int*    cursor  = deg + N_NODES;
  int*    offs    = (int*)walloc((size_t)(N_NODES + 1) * 4);
  int*    csr_src = (int*)walloc((size_t)N_EDGES * 4);
  float*  alpha   = (float*)walloc((size_t)N_EDGES * 4);
  int*    bsum    = (int*)walloc(1024);
  __half* Whl     = (__half*)walloc((size_t)114688 * 2);         // hi/lo frags, 4 matrices
  __half* Wg_hl   = Whl;
  __half* W1_hl   = Whl + 32768;
  __half* W2_hl   = Whl + 65536;
  __half* Wc_hl   = Whl + 98304;

  hipMemsetAsync(deg, 0, (size_t)N_NODES * 2 * 4, stream);

  const dim3 blk(256);
  const int nwave_blocks = (N_NODES + 3) / 4;
  const int nedge_blocks = (N_EDGES + 255) / 256;
  const int nscan_blocks = (N_NODES + 255) / 256;
  const int ngemm_blocks = (N_NODES + 127) / 128;   // 391

  prep_k<<<dim3(224), blk, 0, stream>>>(W_gat, W1, W2, Wc, Whl);

  // h16 = fp16(x @ W_gat); el/er exact from f32 accs in epilogue
  mgemm_k<128, false, true><<<dim3(ngemm_blocks), blk, 0, stream>>>(
      x, Wg_hl, P16, N_NODES, attn_l, attn_r, el, er);

  hist_k<<<dim3(nedge_blocks), blk, 0, stream>>>(dst, deg, N_EDGES);
  scan1_k<<<dim3(nscan_blocks), blk, 0, stream>>>(deg, offs, bsum, N_NODES);
  scan2_k<<<dim3(1), blk, 0, stream>>>(bsum, nscan_blocks);
  scan3_k<<<dim3(nscan_blocks), blk, 0, stream>>>(offs, deg, bsum, N_NODES);
  scatter_k<<<dim3(nedge_blocks), blk, 0, stream>>>(src, dst, offs, cursor, csr_src, N_EDGES);
  softmax_k<<<dim3(nwave_blocks), blk, 0, stream>>>(offs, csr_src, el, er, alpha, N_NODES);

  // h1 = elu(agg(h16))  [fp16]
  agg128h_k<true><<<dim3(nwave_blocks), blk, 0, stream>>>(offs, csr_src, alpha, P16, nullptr, F16, N_NODES);
  // layer 1
  mgemm_k<128, true, false><<<dim3(ngemm_blocks), blk, 0, stream>>>(
      F16, W1_hl, P16, N_NODES, nullptr, nullptr, nullptr, nullptr);
  agg128h_k<false><<<dim3(nwave_blocks), blk, 0, stream>>>(offs, csr_src, alpha, P16, b1, F16, N_NODES);
  // layer 2
  mgemm_k<128, true, false><<<dim3(ngemm_blocks), blk, 0, stream>>>(
      F16, W2_hl, P16, N_NODES, nullptr, nullptr, nullptr, nullptr);
  agg128h_k<false><<<dim3(nwave_blocks), blk, 0, stream>>>(offs, csr_src, alpha, P16, b2, F16, N_NODES);
  // classifier
  mgemm_k<64, true, false><<<dim3(ngemm_blocks), blk, 0, stream>>>(
      F16, Wc_hl, P16, N_NODES, nullptr, nullptr, nullptr, nullptr);
  agg64h_k<<<dim3(nwave_blocks), blk, 0, stream>>>(offs, csr_src, alpha, P16, bc, out, N_NODES);
}

// Round 7
// 344.978 us; speedup vs baseline: 2.0373x; 1.0340x over previous
//
#include <hip/hip_runtime.h>
#include <hip/hip_fp16.h>
#include <math.h>

#define N_NODES 50000
#define N_EDGES 800000
// dims: IN=128, HIDDEN=128, NUM_CLASSES=64 (hard-coded)

typedef _Float16 half8 __attribute__((ext_vector_type(8)));
typedef float floatx16 __attribute__((ext_vector_type(16)));

// ---------------- weight prep: W(f32) -> [hi|lo] fp16 in MFMA-B fragment layout ----------------
__global__ __launch_bounds__(256) void prep_k(const float* __restrict__ Wg,
                                              const float* __restrict__ W1,
                                              const float* __restrict__ W2,
                                              const float* __restrict__ Wc,
                                              __half* __restrict__ out) {
  int e = blockIdx.x * 256 + threadIdx.x;
  const float* W; _Float16* o; int sh, local;
  _Float16* ob = (_Float16*)out;
  if (e < 16384)      { W = Wg; o = ob;         sh = 7; local = e; }
  else if (e < 32768) { W = W1; o = ob + 32768; sh = 7; local = e - 16384; }
  else if (e < 49152) { W = W2; o = ob + 65536; sh = 7; local = e - 32768; }
  else if (e < 57344) { W = Wc; o = ob + 98304; sh = 6; local = e - 49152; }
  else return;
  int NC = 1 << sh;
  int k = local >> sh, n = local & (NC - 1);
  float w = W[k * NC + n];
  _Float16 hi = (_Float16)w;
  float lo = w - (float)hi;
  int oi = (((k >> 3) * NC + n) << 3) | (k & 7);
  o[oi] = hi;
  o[(NC << 7) + oi] = (_Float16)lo;   // +K*NC halves
}

// ---------------- MFMA GEMM: C16[M x NCOL] = fp16( A[M x 128] @ (Whi+Wlo) ) ----------------
template <int NCOL, bool A16, bool ELR>
__global__ __launch_bounds__(256) void mgemm_k(const void* __restrict__ Ap,
                                               const __half* __restrict__ Whl,
                                               __half* __restrict__ C16, int M,
                                               const float* __restrict__ al,
                                               const float* __restrict__ ar,
                                               float* __restrict__ el,
                                               float* __restrict__ er) {
  __shared__ __half Al[16][129][8];
  const int tid  = threadIdx.x;
  const int row0 = blockIdx.x * 128;
  const int lane = tid & 63;
  const int lane31 = lane & 31;
  const int q = lane >> 5;
  const int r = tid >> 6;

  if (A16) {
    const uint4* A8 = (const uint4*)Ap;
    #pragma unroll
    for (int i = 0; i < 8; ++i) {
      int idx = tid + i * 256;
      int row = idx >> 4, c = idx & 15;
      int grow = row0 + row;
      uint4 v = make_uint4(0u, 0u, 0u, 0u);
      if (grow < M) v = A8[grow * 16 + c];
      *reinterpret_cast<uint4*>(&Al[c][row][0]) = v;
    }
  } else {
    const float4* A4 = (const float4*)Ap;
    #pragma unroll
    for (int i = 0; i < 8; ++i) {
      int idx = tid + i * 256;
      int row = idx >> 4, c = idx & 15;
      int grow = row0 + row;
      half8 hv = {};
      if (grow < M) {
        float4 a0 = A4[grow * 32 + c * 2];
        float4 a1 = A4[grow * 32 + c * 2 + 1];
        hv[0] = (_Float16)a0.x; hv[1] = (_Float16)a0.y;
        hv[2] = (_Float16)a0.z; hv[3] = (_Float16)a0.w;
        hv[4] = (_Float16)a1.x; hv[5] = (_Float16)a1.y;
        hv[6] = (_Float16)a1.z; hv[7] = (_Float16)a1.w;
      }
      *reinterpret_cast<half8*>(&Al[c][row][0]) = hv;
    }
  }
  __syncthreads();

  half8 afr[8];
  #pragma unroll
  for (int s = 0; s < 8; ++s)
    afr[s] = *reinterpret_cast<const half8*>(&Al[2 * s + q][r * 32 + lane31][0]);

  const half8* B8 = reinterpret_cast<const half8*>(Whl);
  const int KN8 = 16 * NCOL;

  float elp[16], erp[16];
  if (ELR) {
    #pragma unroll
    for (int i = 0; i < 16; ++i) { elp[i] = 0.f; erp[i] = 0.f; }
  }

  #pragma unroll
  for (int tc = 0; tc < NCOL / 32; ++tc) {
    floatx16 acc = {};
    int nbase = tc * 32 + lane31;
    #pragma unroll
    for (int s = 0; s < 8; ++s) {
      int ci = (2 * s + q) * NCOL + nbase;
      half8 bl = B8[KN8 + ci];
      half8 bh = B8[ci];
      acc = __builtin_amdgcn_mfma_f32_32x32x16_f16(afr[s], bl, acc, 0, 0, 0);
      acc = __builtin_amdgcn_mfma_f32_32x32x16_f16(afr[s], bh, acc, 0, 0, 0);
    }
    if (ELR) {
      float alv = al[nbase], arv = ar[nbase];
      #pragma unroll
      for (int i = 0; i < 16; ++i) {
        elp[i] = fmaf(acc[i], alv, elp[i]);
        erp[i] = fmaf(acc[i], arv, erp[i]);
      }
    }
    #pragma unroll
    for (int i = 0; i < 16; ++i) {
      int rl = (i & 3) + 8 * (i >> 2) + 4 * q;
      int grow = row0 + r * 32 + rl;
      if (grow < M) C16[grow * NCOL + nbase] = __float2half(acc[i]);
    }
  }

  if (ELR) {
    #pragma unroll
    for (int off = 1; off <= 16; off <<= 1) {
      #pragma unroll
      for (int i = 0; i < 16; ++i) {
        elp[i] += __shfl_xor(elp[i], off);
        erp[i] += __shfl_xor(erp[i], off);
      }
    }
    if (lane31 == 0) {
      #pragma unroll
      for (int i = 0; i < 16; ++i) {
        int rl = (i & 3) + 8 * (i >> 2) + 4 * q;
        int grow = row0 + r * 32 + rl;
        if (grow < M) { el[grow] = elp[i]; er[grow] = erp[i]; }
      }
    }
  }
}

// ---------------- CSR build ----------------
// hist: deg histogram AND per-edge rank (atomicAdd return) -> scatter needs no atomics.
__global__ __launch_bounds__(256) void hist_k(const int* __restrict__ dst,
                                              int* __restrict__ deg,
                                              int* __restrict__ rank, int E) {
  int e = blockIdx.x * 256 + threadIdx.x;
  if (e < E) rank[e] = atomicAdd(&deg[dst[e]], 1);
}

__global__ __launch_bounds__(256) void scan1_k(const int* __restrict__ deg,
                                               int* __restrict__ offs,
                                               int* __restrict__ bsum, int N) {
  __shared__ int s[256];
  int t = threadIdx.x;
  int i = blockIdx.x * 256 + t;
  int v = (i < N) ? deg[i] : 0;
  s[t] = v;
  __syncthreads();
  for (int o = 1; o < 256; o <<= 1) {
    int add = (t >= o) ? s[t - o] : 0;
    __syncthreads();
    s[t] += add;
    __syncthreads();
  }
  if (i < N) offs[i] = s[t] - v;
  if (t == 255) bsum[blockIdx.x] = s[255];
}

__global__ __launch_bounds__(256) void scan2_k(int* __restrict__ bsum, int nb) {
  __shared__ int s[256];
  int t = threadIdx.x;
  int v = (t < nb) ? bsum[t] : 0;
  s[t] = v;
  __syncthreads();
  for (int o = 1; o < 256; o <<= 1) {
    int add = (t >= o) ? s[t - o] : 0;
    __syncthreads();
    s[t] += add;
    __syncthreads();
  }
  if (t < nb) bsum[t] = s[t] - v;
}

__global__ __launch_bounds__(256) void scan3_k(int* __restrict__ offs,
                                               const int* __restrict__ deg,
                                               const int* __restrict__ bsum, int N) {
  int i = blockIdx.x * 256 + threadIdx.x;
  if (i < N) {
    int o = offs[i] + bsum[blockIdx.x];
    offs[i] = o;
    if (i == N - 1) offs[N] = o + deg[i];
  }
}

// atomic-free scatter: position = offs[dst] + precomputed rank
__global__ __launch_bounds__(256) void scatter_k(const int* __restrict__ src,
                                                 const int* __restrict__ dst,
                                                 const int* __restrict__ offs,
                                                 const int* __restrict__ rank,
                                                 int* __restrict__ csr_src, int E) {
  int e = blockIdx.x * 256 + threadIdx.x;
  if (e < E) {
    csr_src[offs[dst[e]] + rank[e]] = src[e];
  }
}

// ---------------- edge softmax ----------------
__global__ __launch_bounds__(256) void softmax_k(const int* __restrict__ offs,
                                                 const int* __restrict__ csr_src,
                                                 const float* __restrict__ el,
                                                 const float* __restrict__ er,
                                                 float* __restrict__ alpha, int N) {
  int w    = (blockIdx.x * 256 + threadIdx.x) >> 6;
  int lane = threadIdx.x & 63;
  if (w >= N) return;
  int o0 = offs[w], o1 = offs[w + 1];
  int cnt = o1 - o0;
  if (cnt == 0) return;
  float erv = er[w];
  if (cnt <= 64) {
    bool valid = lane < cnt;
    float ev = -3.4e38f;
    if (valid) {
      int s = csr_src[o0 + lane];
      float e0 = el[s] + erv;
      ev = (e0 >= 0.f) ? e0 : 0.2f * e0;
    }
    float m = ev;
    #pragma unroll
    for (int off = 32; off; off >>= 1) m = fmaxf(m, __shfl_xor(m, off));
    float ee = valid ? __expf(ev - m) : 0.f;
    float sum = ee;
    #pragma unroll
    for (int off = 32; off; off >>= 1) sum += __shfl_xor(sum, off);
    if (valid) alpha[o0 + lane] = ee / sum;
  } else {
    float m = -3.4e38f;
    for (int i = lane; i < cnt; i += 64) {
      int s = csr_src[o0 + i];
      float ev = el[s] + erv;
      ev = (ev >= 0.f) ? ev : 0.2f * ev;
      m = fmaxf(m, ev);
    }
    #pragma unroll
    for (int off = 32; off; off >>= 1) m = fmaxf(m, __shfl_xor(m, off));
    float sum = 0.f;
    for (int i = lane; i < cnt; i += 64) {
      int s = csr_src[o0 + i];
      float ev = el[s] + erv;
      ev = (ev >= 0.f) ? ev : 0.2f * ev;
      float ee = __expf(ev - m);
      alpha[o0 + i] = ee;
      sum += ee;
    }
    #pragma unroll
    for (int off = 32; off; off >>= 1) sum += __shfl_xor(sum, off);
    float inv = 1.f / sum;
    for (int i = lane; i < cnt; i += 64) alpha[o0 + i] *= inv;
  }
}

__device__ inline void fma8(float2 acc[4], uint4 u, float a) {
  __half2* h = reinterpret_cast<__half2*>(&u);
  #pragma unroll
  for (int j = 0; j < 4; ++j) {
    float2 f = __half22float2(h[j]);
    acc[j].x = fmaf(a, f.x, acc[j].x);
    acc[j].y = fmaf(a, f.y, acc[j].y);
  }
}

// ---------------- agg 128-feat fp16 gather -> fp16 out ----------------
// Quarter-wave rows (16 lanes x 16B = 256B); 4 slot groups x 4-deep pipeline ->
// 16 edges/iter, 4 gathers in flight per lane. Wave-uniform trip count (round up
// to 16); padded slots safe: lanes >= cnt preloaded alpha=0 (fma adds 0), src=0.
template <bool ELU>
__global__ __launch_bounds__(256) void agg128h_k(const int* __restrict__ offs,
                                                 const int* __restrict__ csr_src,
                                                 const float* __restrict__ alpha,
                                                 const __half* __restrict__ hp,
                                                 const float* __restrict__ bias,
                                                 __half* __restrict__ out, int N) {
  int w    = (blockIdx.x * 256 + threadIdx.x) >> 6;
  int lane = threadIdx.x & 63;
  if (w >= N) return;
  int o0 = offs[w], o1 = offs[w + 1];
  int cnt = o1 - o0;
  int q   = lane >> 4;           // slot-in-group 0..3
  int fl  = lane & 15;           // 16B feature chunk (8 halves)
  const uint4* hpq = reinterpret_cast<const uint4*>(hp);

  int   myS = 0;
  float myA = 0.f;
  if (lane < cnt) { myS = csr_src[o0 + lane]; myA = alpha[o0 + lane]; }

  float2 acc0[4] = {}, acc1[4] = {}, acc2[4] = {}, acc3[4] = {};
  int cntc = cnt < 64 ? cnt : 64;
  if (cntc > 0) {                         // wave-uniform
    int cr = (cntc + 15) & ~15;           // <= 64
    int   sA = __shfl(myS, q),          sB = __shfl(myS, 4 + q);
    int   sC = __shfl(myS, 8 + q),      sD = __shfl(myS, 12 + q);
    float aA = __shfl(myA, q),          aB = __shfl(myA, 4 + q);
    float aC = __shfl(myA, 8 + q),      aD = __shfl(myA, 12 + q);
    uint4 vA = hpq[sA * 16 + fl], vB = hpq[sB * 16 + fl];
    uint4 vC = hpq[sC * 16 + fl], vD = hpq[sD * 16 + fl];
    for (int base = 16; base < cr; base += 16) {
      int   tA = __shfl(myS, base + q),      tB = __shfl(myS, base + 4 + q);
      int   tC = __shfl(myS, base + 8 + q),  tD = __shfl(myS, base + 12 + q);
      float nA = __shfl(myA, base + q),      nB = __shfl(myA, base + 4 + q);
      float nC = __shfl(myA, base + 8 + q),  nD = __shfl(myA, base + 12 + q);
      uint4 wA = hpq[tA * 16 + fl], wB = hpq[tB * 16 + fl];
      uint4 wC = hpq[tC * 16 + fl], wD = hpq[tD * 16 + fl];
      fma8(acc0, vA, aA);
      fma8(acc1, vB, aB);
      fma8(acc2, vC, aC);
      fma8(acc3, vD, aD);
      vA = wA; vB = wB; vC = wC; vD = wD;
      aA = nA; aB = nB; aC = nC; aD = nD;
    }
    fma8(acc0, vA, aA);
    fma8(acc1, vB, aB);
    fma8(acc2, vC, aC);
    fma8(acc3, vD, aD);
  }
  for (int p = o0 + 64 + q; p < o1; p += 4) {
    fma8(acc0, hpq[csr_src[p] * 16 + fl], alpha[p]);
  }
  #pragma unroll
  for (int j = 0; j < 4; ++j) {
    acc0[j].x += acc1[j].x + acc2[j].x + acc3[j].x;
    acc0[j].y += acc1[j].y + acc2[j].y + acc3[j].y;
  }
  #pragma unroll
  for (int off = 16; off <= 32; off <<= 1) {
    #pragma unroll
    for (int j = 0; j < 4; ++j) {
      acc0[j].x += __shfl_xor(acc0[j].x, off);
      acc0[j].y += __shfl_xor(acc0[j].y, off);
    }
  }
  if (q == 0) {                 // lanes 0..15 write features [fl*8 .. fl*8+7]
    float o8[8];
    #pragma unroll
    for (int j = 0; j < 4; ++j) { o8[2 * j] = acc0[j].x; o8[2 * j + 1] = acc0[j].y; }
    if (ELU) {
      #pragma unroll
      for (int j = 0; j < 8; ++j) o8[j] = (o8[j] > 0.f) ? o8[j] : expm1f(o8[j]);
    }
    if (bias) {
      float4 b0 = reinterpret_cast<const float4*>(bias)[fl * 2];
      float4 b1 = reinterpret_cast<const float4*>(bias)[fl * 2 + 1];
      o8[0] += b0.x; o8[1] += b0.y; o8[2] += b0.z; o8[3] += b0.w;
      o8[4] += b1.x; o8[5] += b1.y; o8[6] += b1.z; o8[7] += b1.w;
    }
    __half2 p0 = __floats2half2_rn(o8[0], o8[1]);
    __half2 p1 = __floats2half2_rn(o8[2], o8[3]);
    __half2 p2 = __floats2half2_rn(o8[4], o8[5]);
    __half2 p3 = __floats2half2_rn(o8[6], o8[7]);
    uint4 pk;
    pk.x = *reinterpret_cast<unsigned*>(&p0);
    pk.y = *reinterpret_cast<unsigned*>(&p1);
    pk.z = *reinterpret_cast<unsigned*>(&p2);
    pk.w = *reinterpret_cast<unsigned*>(&p3);
    *reinterpret_cast<uint4*>(&out[w * 128 + fl * 8]) = pk;
  }
}

// ---------------- agg 64-feat fp16 gather -> f32 out (final logits) ----------------
__global__ __launch_bounds__(256) void agg64h_k(const int* __restrict__ offs,
                                                const int* __restrict__ csr_src,
                                                const float* __restrict__ alpha,
                                                const __half* __restrict__ hp,
                                                const float* __restrict__ bias,
                                                float* __restrict__ out, int N) {
  int w    = (blockIdx.x * 256 + threadIdx.x) >> 6;
  int lane = threadIdx.x & 63;
  if (w >= N) return;
  int o0 = offs[w], o1 = offs[w + 1];
  int cnt = o1 - o0;
  int o   = lane >> 3;           // edge slot 0..7
  int fl  = lane & 7;            // 16B feature chunk (8 halves)
  const uint4* hpq = reinterpret_cast<const uint4*>(hp);

  int   myS = 0;
  float myA = 0.f;
  if (lane < cnt) { myS = csr_src[o0 + lane]; myA = alpha[o0 + lane]; }

  float2 acc0[4] = {}, acc1[4] = {};
  int cntc = cnt < 64 ? cnt : 64;
  if (cntc > 0) {
    int cr = (cntc + 15) & ~15;           // <= 64
    int   sA = __shfl(myS, o),     sB = __shfl(myS, 8 + o);
    float aA = __shfl(myA, o),     aB = __shfl(myA, 8 + o);
    uint4 vA = hpq[sA * 8 + fl], vB = hpq[sB * 8 + fl];
    for (int base = 16; base < cr; base += 16) {
      int   tA = __shfl(myS, base + o),     tB = __shfl(myS, base + 8 + o);
      float nA = __shfl(myA, base + o),     nB = __shfl(myA, base + 8 + o);
      uint4 wA = hpq[tA * 8 + fl], wB = hpq[tB * 8 + fl];
      fma8(acc0, vA, aA);
      fma8(acc1, vB, aB);
      vA = wA; vB = wB; aA = nA; aB = nB;
    }
    fma8(acc0, vA, aA);
    fma8(acc1, vB, aB);
  }
  for (int p = o0 + 64 + o; p < o1; p += 8) {
    fma8(acc0, hpq[csr_src[p] * 8 + fl], alpha[p]);
  }
  #pragma unroll
  for (int j = 0; j < 4; ++j) { acc0[j].x += acc1[j].x; acc0[j].y += acc1[j].y; }
  #pragma unroll
  for (int off = 8; off <= 32; off <<= 1) {
    #pragma unroll
    for (int j = 0; j < 4; ++j) {
      acc0[j].x += __shfl_xor(acc0[j].x, off);
      acc0[j].y += __shfl_xor(acc0[j].y, off);
    }
  }
  if (o == 0) {                 // lanes 0..7 write features [fl*8 .. fl*8+7]
    float o8[8];
    #pragma unroll
    for (int j = 0; j < 4; ++j) { o8[2 * j] = acc0[j].x; o8[2 * j + 1] = acc0[j].y; }
    if (bias) {
      float4 b0 = reinterpret_cast<const float4*>(bias)[fl * 2];
      float4 b1 = reinterpret_cast<const float4*>(bias)[fl * 2 + 1];
      o8[0] += b0.x; o8[1] += b0.y; o8[2] += b0.z; o8[3] += b0.w;
      o8[4] += b1.x; o8[5] += b1.y; o8[6] += b1.z; o8[7] += b1.w;
    }
    float4* outp = reinterpret_cast<float4*>(out);
    outp[w * 16 + fl * 2]     = make_float4(o8[0], o8[1], o8[2], o8[3]);
    outp[w * 16 + fl * 2 + 1] = make_float4(o8[4], o8[5], o8[6], o8[7]);
  }
}

// ---------------- launch ----------------
extern "C" void kernel_launch(void* const* d_in, const int* in_sizes, int n_in,
                              void* d_out, int out_size, void* d_ws, size_t ws_size,
                              hipStream_t stream) {
  const float* x      = (const float*)d_in[0];
  const int*   src    = (const int*)d_in[1];
  const int*   dst    = (const int*)d_in[2];
  const float* W_gat  = (const float*)d_in[3];
  const float* attn_l = (const float*)d_in[4];
  const float* attn_r = (const float*)d_in[5];
  const float* W1     = (const float*)d_in[6];
  const float* b1     = (const float*)d_in[7];
  const float* W2     = (const float*)d_in[8];
  const float* b2     = (const float*)d_in[9];
  const float* Wc     = (const float*)d_in[10];
  const float* bc     = (const float*)d_in[11];
  float* out = (float*)d_out;

  char* ws = (char*)d_ws;
  size_t off = 0;
  auto walloc = [&](size_t bytes) -> void* {
    void* p = ws + off;
    off += (bytes + 255) & ~size_t(255);
    return p;
  };
  __half* P16     = (__half*)walloc((size_t)N_NODES * 128 * 2);  // gemm out / gather operand
  __half* F16     = (__half*)walloc((size_t)N_NODES * 128 * 2);  // agg out / gemm A operand
  float*  el      = (float*)walloc((size_t)N_NODES * 4);
  float*  er      = (float*)walloc((size_t)N_NODES * 4);
  int*    deg     = (int*)walloc((size_t)N_NODES * 4);
  int*    offs    = (int*)walloc((size_t)(N_NODES + 1) * 4);
  int*    rank    = (int*)walloc((size_t)N_EDGES * 4);
  int*    csr_src = (int*)walloc((size_t)N_EDGES * 4);
  float*  alpha   = (float*)walloc((size_t)N_EDGES * 4);
  int*    bsum    = (int*)walloc(1024);
  __half* Whl     = (__half*)walloc((size_t)114688 * 2);         // hi/lo frags, 4 matrices
  __half* Wg_hl   = Whl;
  __half* W1_hl   = Whl + 32768;
  __half* W2_hl   = Whl + 65536;
  __half* Wc_hl   = Whl + 98304;

  hipMemsetAsync(deg, 0, (size_t)N_NODES * 4, stream);

  const dim3 blk(256);
  const int nwave_blocks = (N_NODES + 3) / 4;
  const int nedge_blocks = (N_EDGES + 255) / 256;
  const int nscan_blocks = (N_NODES + 255) / 256;
  const int ngemm_blocks = (N_NODES + 127) / 128;   // 391

  prep_k<<<dim3(224), blk, 0, stream>>>(W_gat, W1, W2, Wc, Whl);

  // h16 = fp16(x @ W_gat); el/er exact from f32 accs in epilogue
  mgemm_k<128, false, true><<<dim3(ngemm_blocks), blk, 0, stream>>>(
      x, Wg_hl, P16, N_NODES, attn_l, attn_r, el, er);

  hist_k<<<dim3(nedge_blocks), blk, 0, stream>>>(dst, deg, rank, N_EDGES);
  scan1_k<<<dim3(nscan_blocks), blk, 0, stream>>>(deg, offs, bsum, N_NODES);
  scan2_k<<<dim3(1), blk, 0, stream>>>(bsum, nscan_blocks);
  scan3_k<<<dim3(nscan_blocks), blk, 0, stream>>>(offs, deg, bsum, N_NODES);
  scatter_k<<<dim3(nedge_blocks), blk, 0, stream>>>(src, dst, offs, rank, csr_src, N_EDGES);
  softmax_k<<<dim3(nwave_blocks), blk, 0, stream>>>(offs, csr_src, el, er, alpha, N_NODES);

  // h1 = elu(agg(h16))  [fp16]
  agg128h_k<true><<<dim3(nwave_blocks), blk, 0, stream>>>(offs, csr_src, alpha, P16, nullptr, F16, N_NODES);
  // layer 1
  mgemm_k<128, true, false><<<dim3(ngemm_blocks), blk, 0, stream>>>(
      F16, W1_hl, P16, N_NODES, nullptr, nullptr, nullptr, nullptr);
  agg128h_k<false><<<dim3(nwave_blocks), blk, 0, stream>>>(offs, csr_src, alpha, P16, b1, F16, N_NODES);
  // layer 2
  mgemm_k<128, true, false><<<dim3(ngemm_blocks), blk, 0, stream>>>(
      F16, W2_hl, P16, N_NODES, nullptr, nullptr, nullptr, nullptr);
  agg128h_k<false><<<dim3(nwave_blocks), blk, 0, stream>>>(offs, csr_src, alpha, P16, b2, F16, N_NODES);
  // classifier
  mgemm_k<64, true, false><<<dim3(ngemm_blocks), blk, 0, stream>>>(
      F16, Wc_hl, P16, N_NODES, nullptr, nullptr, nullptr, nullptr);
  agg64h_k<<<dim3(nwave_blocks), blk, 0, stream>>>(offs, csr_src, alpha, P16, bc, out, N_NODES);
}

// Round 8
// 342.944 us; speedup vs baseline: 2.0494x; 1.0059x over previous
//
#include <hip/hip_runtime.h>
#include <hip/hip_fp16.h>
#include <math.h>

#define N_NODES 50000
#define N_EDGES 800000
// dims: IN=128, HIDDEN=128, NUM_CLASSES=64 (hard-coded)

typedef _Float16 half8 __attribute__((ext_vector_type(8)));
typedef float floatx16 __attribute__((ext_vector_type(16)));

// ---------------- weight prep: W(f32) -> [hi|lo] fp16 in MFMA-B fragment layout ----------------
__global__ __launch_bounds__(256) void prep_k(const float* __restrict__ Wg,
                                              const float* __restrict__ W1,
                                              const float* __restrict__ W2,
                                              const float* __restrict__ Wc,
                                              __half* __restrict__ out) {
  int e = blockIdx.x * 256 + threadIdx.x;
  const float* W; _Float16* o; int sh, local;
  _Float16* ob = (_Float16*)out;
  if (e < 16384)      { W = Wg; o = ob;         sh = 7; local = e; }
  else if (e < 32768) { W = W1; o = ob + 32768; sh = 7; local = e - 16384; }
  else if (e < 49152) { W = W2; o = ob + 65536; sh = 7; local = e - 32768; }
  else if (e < 57344) { W = Wc; o = ob + 98304; sh = 6; local = e - 49152; }
  else return;
  int NC = 1 << sh;
  int k = local >> sh, n = local & (NC - 1);
  float w = W[k * NC + n];
  _Float16 hi = (_Float16)w;
  float lo = w - (float)hi;
  int oi = (((k >> 3) * NC + n) << 3) | (k & 7);
  o[oi] = hi;
  o[(NC << 7) + oi] = (_Float16)lo;   // +K*NC halves
}

// ---------------- MFMA GEMM: C16[M x NCOL] = fp16( A[M x 128] @ (Whi+Wlo) ) ----------------
template <int NCOL, bool A16, bool ELR>
__global__ __launch_bounds__(256) void mgemm_k(const void* __restrict__ Ap,
                                               const __half* __restrict__ Whl,
                                               __half* __restrict__ C16, int M,
                                               const float* __restrict__ al,
                                               const float* __restrict__ ar,
                                               float* __restrict__ el,
                                               float* __restrict__ er) {
  __shared__ __half Al[16][129][8];
  const int tid  = threadIdx.x;
  const int row0 = blockIdx.x * 128;
  const int lane = tid & 63;
  const int lane31 = lane & 31;
  const int q = lane >> 5;
  const int r = tid >> 6;

  if (A16) {
    const uint4* A8 = (const uint4*)Ap;
    #pragma unroll
    for (int i = 0; i < 8; ++i) {
      int idx = tid + i * 256;
      int row = idx >> 4, c = idx & 15;
      int grow = row0 + row;
      uint4 v = make_uint4(0u, 0u, 0u, 0u);
      if (grow < M) v = A8[grow * 16 + c];
      *reinterpret_cast<uint4*>(&Al[c][row][0]) = v;
    }
  } else {
    const float4* A4 = (const float4*)Ap;
    #pragma unroll
    for (int i = 0; i < 8; ++i) {
      int idx = tid + i * 256;
      int row = idx >> 4, c = idx & 15;
      int grow = row0 + row;
      half8 hv = {};
      if (grow < M) {
        float4 a0 = A4[grow * 32 + c * 2];
        float4 a1 = A4[grow * 32 + c * 2 + 1];
        hv[0] = (_Float16)a0.x; hv[1] = (_Float16)a0.y;
        hv[2] = (_Float16)a0.z; hv[3] = (_Float16)a0.w;
        hv[4] = (_Float16)a1.x; hv[5] = (_Float16)a1.y;
        hv[6] = (_Float16)a1.z; hv[7] = (_Float16)a1.w;
      }
      *reinterpret_cast<half8*>(&Al[c][row][0]) = hv;
    }
  }
  __syncthreads();

  half8 afr[8];
  #pragma unroll
  for (int s = 0; s < 8; ++s)
    afr[s] = *reinterpret_cast<const half8*>(&Al[2 * s + q][r * 32 + lane31][0]);

  const half8* B8 = reinterpret_cast<const half8*>(Whl);
  const int KN8 = 16 * NCOL;

  float elp[16], erp[16];
  if (ELR) {
    #pragma unroll
    for (int i = 0; i < 16; ++i) { elp[i] = 0.f; erp[i] = 0.f; }
  }

  #pragma unroll
  for (int tc = 0; tc < NCOL / 32; ++tc) {
    floatx16 acc = {};
    int nbase = tc * 32 + lane31;
    #pragma unroll
    for (int s = 0; s < 8; ++s) {
      int ci = (2 * s + q) * NCOL + nbase;
      half8 bl = B8[KN8 + ci];
      half8 bh = B8[ci];
      acc = __builtin_amdgcn_mfma_f32_32x32x16_f16(afr[s], bl, acc, 0, 0, 0);
      acc = __builtin_amdgcn_mfma_f32_32x32x16_f16(afr[s], bh, acc, 0, 0, 0);
    }
    if (ELR) {
      float alv = al[nbase], arv = ar[nbase];
      #pragma unroll
      for (int i = 0; i < 16; ++i) {
        elp[i] = fmaf(acc[i], alv, elp[i]);
        erp[i] = fmaf(acc[i], arv, erp[i]);
      }
    }
    #pragma unroll
    for (int i = 0; i < 16; ++i) {
      int rl = (i & 3) + 8 * (i >> 2) + 4 * q;
      int grow = row0 + r * 32 + rl;
      if (grow < M) C16[grow * NCOL + nbase] = __float2half(acc[i]);
    }
  }

  if (ELR) {
    #pragma unroll
    for (int off = 1; off <= 16; off <<= 1) {
      #pragma unroll
      for (int i = 0; i < 16; ++i) {
        elp[i] += __shfl_xor(elp[i], off);
        erp[i] += __shfl_xor(erp[i], off);
      }
    }
    if (lane31 == 0) {
      #pragma unroll
      for (int i = 0; i < 16; ++i) {
        int rl = (i & 3) + 8 * (i >> 2) + 4 * q;
        int grow = row0 + r * 32 + rl;
        if (grow < M) { el[grow] = elp[i]; er[grow] = erp[i]; }
      }
    }
  }
}

// ---------------- CSR build ----------------
__global__ __launch_bounds__(256) void hist_k(const int* __restrict__ dst,
                                              int* __restrict__ deg,
                                              int* __restrict__ rank, int E) {
  int e = blockIdx.x * 256 + threadIdx.x;
  if (e < E) rank[e] = atomicAdd(&deg[dst[e]], 1);
}

__global__ __launch_bounds__(256) void scan1_k(const int* __restrict__ deg,
                                               int* __restrict__ offs,
                                               int* __restrict__ bsum, int N) {
  __shared__ int s[256];
  int t = threadIdx.x;
  int i = blockIdx.x * 256 + t;
  int v = (i < N) ? deg[i] : 0;
  s[t] = v;
  __syncthreads();
  for (int o = 1; o < 256; o <<= 1) {
    int add = (t >= o) ? s[t - o] : 0;
    __syncthreads();
    s[t] += add;
    __syncthreads();
  }
  if (i < N) offs[i] = s[t] - v;
  if (t == 255) bsum[blockIdx.x] = s[255];
}

__global__ __launch_bounds__(256) void scan2_k(int* __restrict__ bsum, int nb) {
  __shared__ int s[256];
  int t = threadIdx.x;
  int v = (t < nb) ? bsum[t] : 0;
  s[t] = v;
  __syncthreads();
  for (int o = 1; o < 256; o <<= 1) {
    int add = (t >= o) ? s[t - o] : 0;
    __syncthreads();
    s[t] += add;
    __syncthreads();
  }
  if (t < nb) bsum[t] = s[t] - v;
}

__global__ __launch_bounds__(256) void scan3_k(int* __restrict__ offs,
                                               const int* __restrict__ deg,
                                               const int* __restrict__ bsum, int N) {
  int i = blockIdx.x * 256 + threadIdx.x;
  if (i < N) {
    int o = offs[i] + bsum[blockIdx.x];
    offs[i] = o;
    if (i == N - 1) offs[N] = o + deg[i];
  }
}

__global__ __launch_bounds__(256) void scatter_k(const int* __restrict__ src,
                                                 const int* __restrict__ dst,
                                                 const int* __restrict__ offs,
                                                 const int* __restrict__ rank,
                                                 int* __restrict__ csr_src, int E) {
  int e = blockIdx.x * 256 + threadIdx.x;
  if (e < E) {
    csr_src[offs[dst[e]] + rank[e]] = src[e];
  }
}

__device__ inline void fma8(float2 acc[4], uint4 u, float a) {
  __half2* h = reinterpret_cast<__half2*>(&u);
  #pragma unroll
  for (int j = 0; j < 4; ++j) {
    float2 f = __half22float2(h[j]);
    acc[j].x = fmaf(a, f.x, acc[j].x);
    acc[j].y = fmaf(a, f.y, acc[j].y);
  }
}

// ---------------- fused edge-softmax + agg 128 (GAT layer) ----------------
// One wave per node. Computes alpha in-register (el gathers hit the 200KB L2-resident
// table), writes packed meta{src, alpha} for the later layers, then aggregates the
// fp16 features immediately (csr_src/alpha already in registers -> no re-read).
// Quarter-wave rows (16 lanes x 16B = 256B); 4 slot groups x 4-deep pipeline.
// Wave-uniform loops; padded slots safe (alpha=0, src=0). ELU on output.
__global__ __launch_bounds__(256) void aggsm_k(const int* __restrict__ offs,
                                               const int* __restrict__ csr_src,
                                               const float* __restrict__ el,
                                               const float* __restrict__ er,
                                               int2* __restrict__ meta,
                                               const __half* __restrict__ hp,
                                               __half* __restrict__ out, int N) {
  int w    = (blockIdx.x * 256 + threadIdx.x) >> 6;
  int lane = threadIdx.x & 63;
  if (w >= N) return;
  int o0 = offs[w], o1 = offs[w + 1];
  int cnt = o1 - o0;
  int q   = lane >> 4;
  int fl  = lane & 15;
  const uint4* hpq = reinterpret_cast<const uint4*>(hp);

  int   myS = 0;
  float myA = 0.f;

  if (cnt > 0 && cnt <= 64) {            // wave-uniform fast path
    bool valid = lane < cnt;
    float erv = er[w];
    int s = 0;
    float ev = -3.4e38f;
    if (valid) {
      s = csr_src[o0 + lane];
      float e0 = el[s] + erv;
      ev = (e0 >= 0.f) ? e0 : 0.2f * e0;
    }
    float m = ev;
    #pragma unroll
    for (int off = 32; off; off >>= 1) m = fmaxf(m, __shfl_xor(m, off));
    float ee = valid ? __expf(ev - m) : 0.f;
    float sum = ee;
    #pragma unroll
    for (int off = 32; off; off >>= 1) sum += __shfl_xor(sum, off);
    float a = ee / sum;
    if (valid) {
      meta[o0 + lane] = make_int2(s, __float_as_int(a));
      myS = s; myA = a;
    }
  } else if (cnt > 64) {                 // rare generic path: 3-pass softmax into meta
    float erv = er[w];
    float m = -3.4e38f;
    for (int i = lane; i < cnt; i += 64) {
      int s = csr_src[o0 + i];
      float ev = el[s] + erv;
      ev = (ev >= 0.f) ? ev : 0.2f * ev;
      m = fmaxf(m, ev);
    }
    #pragma unroll
    for (int off = 32; off; off >>= 1) m = fmaxf(m, __shfl_xor(m, off));
    float sum = 0.f;
    for (int i = lane; i < cnt; i += 64) {
      int s = csr_src[o0 + i];
      float ev = el[s] + erv;
      ev = (ev >= 0.f) ? ev : 0.2f * ev;
      float ee = __expf(ev - m);
      meta[o0 + i] = make_int2(s, __float_as_int(ee));
      sum += ee;
    }
    #pragma unroll
    for (int off = 32; off; off >>= 1) sum += __shfl_xor(sum, off);
    float inv = 1.f / sum;
    for (int i = lane; i < cnt; i += 64) {
      int2 mm = meta[o0 + i];
      float a = __int_as_float(mm.y) * inv;
      meta[o0 + i] = make_int2(mm.x, __float_as_int(a));
    }
    if (lane < cnt) {                    // preload first 64 for the pipelined loop
      int2 mm = meta[o0 + lane];
      myS = mm.x; myA = __int_as_float(mm.y);
    }
  }

  float2 acc0[4] = {}, acc1[4] = {}, acc2[4] = {}, acc3[4] = {};
  int cntc = cnt < 64 ? cnt : 64;
  if (cntc > 0) {
    int cr = (cntc + 15) & ~15;
    int   sA = __shfl(myS, q),          sB = __shfl(myS, 4 + q);
    int   sC = __shfl(myS, 8 + q),      sD = __shfl(myS, 12 + q);
    float aA = __shfl(myA, q),          aB = __shfl(myA, 4 + q);
    float aC = __shfl(myA, 8 + q),      aD = __shfl(myA, 12 + q);
    uint4 vA = hpq[sA * 16 + fl], vB = hpq[sB * 16 + fl];
    uint4 vC = hpq[sC * 16 + fl], vD = hpq[sD * 16 + fl];
    for (int base = 16; base < cr; base += 16) {
      int   tA = __shfl(myS, base + q),      tB = __shfl(myS, base + 4 + q);
      int   tC = __shfl(myS, base + 8 + q),  tD = __shfl(myS, base + 12 + q);
      float nA = __shfl(myA, base + q),      nB = __shfl(myA, base + 4 + q);
      float nC = __shfl(myA, base + 8 + q),  nD = __shfl(myA, base + 12 + q);
      uint4 wA = hpq[tA * 16 + fl], wB = hpq[tB * 16 + fl];
      uint4 wC = hpq[tC * 16 + fl], wD = hpq[tD * 16 + fl];
      fma8(acc0, vA, aA);
      fma8(acc1, vB, aB);
      fma8(acc2, vC, aC);
      fma8(acc3, vD, aD);
      vA = wA; vB = wB; vC = wC; vD = wD;
      aA = nA; aB = nB; aC = nC; aD = nD;
    }
    fma8(acc0, vA, aA);
    fma8(acc1, vB, aB);
    fma8(acc2, vC, aC);
    fma8(acc3, vD, aD);
  }
  for (int p = o0 + 64 + q; p < o1; p += 4) {     // rare degree>64 tail via meta
    int2 mm = meta[p];
    fma8(acc0, hpq[mm.x * 16 + fl], __int_as_float(mm.y));
  }
  #pragma unroll
  for (int j = 0; j < 4; ++j) {
    acc0[j].x += acc1[j].x + acc2[j].x + acc3[j].x;
    acc0[j].y += acc1[j].y + acc2[j].y + acc3[j].y;
  }
  #pragma unroll
  for (int off = 16; off <= 32; off <<= 1) {
    #pragma unroll
    for (int j = 0; j < 4; ++j) {
      acc0[j].x += __shfl_xor(acc0[j].x, off);
      acc0[j].y += __shfl_xor(acc0[j].y, off);
    }
  }
  if (q == 0) {
    float o8[8];
    #pragma unroll
    for (int j = 0; j < 4; ++j) { o8[2 * j] = acc0[j].x; o8[2 * j + 1] = acc0[j].y; }
    #pragma unroll
    for (int j = 0; j < 8; ++j) o8[j] = (o8[j] > 0.f) ? o8[j] : expm1f(o8[j]);
    __half2 p0 = __floats2half2_rn(o8[0], o8[1]);
    __half2 p1 = __floats2half2_rn(o8[2], o8[3]);
    __half2 p2 = __floats2half2_rn(o8[4], o8[5]);
    __half2 p3 = __floats2half2_rn(o8[6], o8[7]);
    uint4 pk;
    pk.x = *reinterpret_cast<unsigned*>(&p0);
    pk.y = *reinterpret_cast<unsigned*>(&p1);
    pk.z = *reinterpret_cast<unsigned*>(&p2);
    pk.w = *reinterpret_cast<unsigned*>(&p3);
    *reinterpret_cast<uint4*>(&out[w * 128 + fl * 8]) = pk;
  }
}

// ---------------- agg 128-feat via packed meta -> fp16 out ----------------
__global__ __launch_bounds__(256) void agg128m_k(const int* __restrict__ offs,
                                                 const int2* __restrict__ meta,
                                                 const __half* __restrict__ hp,
                                                 const float* __restrict__ bias,
                                                 __half* __restrict__ out, int N) {
  int w    = (blockIdx.x * 256 + threadIdx.x) >> 6;
  int lane = threadIdx.x & 63;
  if (w >= N) return;
  int o0 = offs[w], o1 = offs[w + 1];
  int cnt = o1 - o0;
  int q   = lane >> 4;
  int fl  = lane & 15;
  const uint4* hpq = reinterpret_cast<const uint4*>(hp);

  int   myS = 0;
  float myA = 0.f;
  if (lane < cnt) {
    int2 mm = meta[o0 + lane];
    myS = mm.x; myA = __int_as_float(mm.y);
  }

  float2 acc0[4] = {}, acc1[4] = {}, acc2[4] = {}, acc3[4] = {};
  int cntc = cnt < 64 ? cnt : 64;
  if (cntc > 0) {
    int cr = (cntc + 15) & ~15;
    int   sA = __shfl(myS, q),          sB = __shfl(myS, 4 + q);
    int   sC = __shfl(myS, 8 + q),      sD = __shfl(myS, 12 + q);
    float aA = __shfl(myA, q),          aB = __shfl(myA, 4 + q);
    float aC = __shfl(myA, 8 + q),      aD = __shfl(myA, 12 + q);
    uint4 vA = hpq[sA * 16 + fl], vB = hpq[sB * 16 + fl];
    uint4 vC = hpq[sC * 16 + fl], vD = hpq[sD * 16 + fl];
    for (int base = 16; base < cr; base += 16) {
      int   tA = __shfl(myS, base + q),      tB = __shfl(myS, base + 4 + q);
      int   tC = __shfl(myS, base + 8 + q),  tD = __shfl(myS, base + 12 + q);
      float nA = __shfl(myA, base + q),      nB = __shfl(myA, base + 4 + q);
      float nC = __shfl(myA, base + 8 + q),  nD = __shfl(myA, base + 12 + q);
      uint4 wA = hpq[tA * 16 + fl], wB = hpq[tB * 16 + fl];
      uint4 wC = hpq[tC * 16 + fl], wD = hpq[tD * 16 + fl];
      fma8(acc0, vA, aA);
      fma8(acc1, vB, aB);
      fma8(acc2, vC, aC);
      fma8(acc3, vD, aD);
      vA = wA; vB = wB; vC = wC; vD = wD;
      aA = nA; aB = nB; aC = nC; aD = nD;
    }
    fma8(acc0, vA, aA);
    fma8(acc1, vB, aB);
    fma8(acc2, vC, aC);
    fma8(acc3, vD, aD);
  }
  for (int p = o0 + 64 + q; p < o1; p += 4) {
    int2 mm = meta[p];
    fma8(acc0, hpq[mm.x * 16 + fl], __int_as_float(mm.y));
  }
  #pragma unroll
  for (int j = 0; j < 4; ++j) {
    acc0[j].x += acc1[j].x + acc2[j].x + acc3[j].x;
    acc0[j].y += acc1[j].y + acc2[j].y + acc3[j].y;
  }
  #pragma unroll
  for (int off = 16; off <= 32; off <<= 1) {
    #pragma unroll
    for (int j = 0; j < 4; ++j) {
      acc0[j].x += __shfl_xor(acc0[j].x, off);
      acc0[j].y += __shfl_xor(acc0[j].y, off);
    }
  }
  if (q == 0) {
    float o8[8];
    #pragma unroll
    for (int j = 0; j < 4; ++j) { o8[2 * j] = acc0[j].x; o8[2 * j + 1] = acc0[j].y; }
    float4 b0 = reinterpret_cast<const float4*>(bias)[fl * 2];
    float4 b1 = reinterpret_cast<const float4*>(bias)[fl * 2 + 1];
    o8[0] += b0.x; o8[1] += b0.y; o8[2] += b0.z; o8[3] += b0.w;
    o8[4] += b1.x; o8[5] += b1.y; o8[6] += b1.z; o8[7] += b1.w;
    __half2 p0 = __floats2half2_rn(o8[0], o8[1]);
    __half2 p1 = __floats2half2_rn(o8[2], o8[3]);
    __half2 p2 = __floats2half2_rn(o8[4], o8[5]);
    __half2 p3 = __floats2half2_rn(o8[6], o8[7]);
    uint4 pk;
    pk.x = *reinterpret_cast<unsigned*>(&p0);
    pk.y = *reinterpret_cast<unsigned*>(&p1);
    pk.z = *reinterpret_cast<unsigned*>(&p2);
    pk.w = *reinterpret_cast<unsigned*>(&p3);
    *reinterpret_cast<uint4*>(&out[w * 128 + fl * 8]) = pk;
  }
}

// ---------------- agg 64-feat via packed meta -> f32 out (final logits) ----------------
__global__ __launch_bounds__(256) void agg64m_k(const int* __restrict__ offs,
                                                const int2* __restrict__ meta,
                                                const __half* __restrict__ hp,
                                                const float* __restrict__ bias,
                                                float* __restrict__ out, int N) {
  int w    = (blockIdx.x * 256 + threadIdx.x) >> 6;
  int lane = threadIdx.x & 63;
  if (w >= N) return;
  int o0 = offs[w], o1 = offs[w + 1];
  int cnt = o1 - o0;
  int o   = lane >> 3;           // edge slot 0..7
  int fl  = lane & 7;            // 16B feature chunk
  const uint4* hpq = reinterpret_cast<const uint4*>(hp);

  int   myS = 0;
  float myA = 0.f;
  if (lane < cnt) {
    int2 mm = meta[o0 + lane];
    myS = mm.x; myA = __int_as_float(mm.y);
  }

  float2 acc0[4] = {}, acc1[4] = {};
  int cntc = cnt < 64 ? cnt : 64;
  if (cntc > 0) {
    int cr = (cntc + 15) & ~15;
    int   sA = __shfl(myS, o),     sB = __shfl(myS, 8 + o);
    float aA = __shfl(myA, o),     aB = __shfl(myA, 8 + o);
    uint4 vA = hpq[sA * 8 + fl], vB = hpq[sB * 8 + fl];
    for (int base = 16; base < cr; base += 16) {
      int   tA = __shfl(myS, base + o),     tB = __shfl(myS, base + 8 + o);
      float nA = __shfl(myA, base + o),     nB = __shfl(myA, base + 8 + o);
      uint4 wA = hpq[tA * 8 + fl], wB = hpq[tB * 8 + fl];
      fma8(acc0, vA, aA);
      fma8(acc1, vB, aB);
      vA = wA; vB = wB; aA = nA; aB = nB;
    }
    fma8(acc0, vA, aA);
    fma8(acc1, vB, aB);
  }
  for (int p = o0 + 64 + o; p < o1; p += 8) {
    int2 mm = meta[p];
    fma8(acc0, hpq[mm.x * 8 + fl], __int_as_float(mm.y));
  }
  #pragma unroll
  for (int j = 0; j < 4; ++j) { acc0[j].x += acc1[j].x; acc0[j].y += acc1[j].y; }
  #pragma unroll
  for (int off = 8; off <= 32; off <<= 1) {
    #pragma unroll
    for (int j = 0; j < 4; ++j) {
      acc0[j].x += __shfl_xor(acc0[j].x, off);
      acc0[j].y += __shfl_xor(acc0[j].y, off);
    }
  }
  if (o == 0) {
    float o8[8];
    #pragma unroll
    for (int j = 0; j < 4; ++j) { o8[2 * j] = acc0[j].x; o8[2 * j + 1] = acc0[j].y; }
    float4 b0 = reinterpret_cast<const float4*>(bias)[fl * 2];
    float4 b1 = reinterpret_cast<const float4*>(bias)[fl * 2 + 1];
    o8[0] += b0.x; o8[1] += b0.y; o8[2] += b0.z; o8[3] += b0.w;
    o8[4] += b1.x; o8[5] += b1.y; o8[6] += b1.z; o8[7] += b1.w;
    float4* outp = reinterpret_cast<float4*>(out);
    outp[w * 16 + fl * 2]     = make_float4(o8[0], o8[1], o8[2], o8[3]);
    outp[w * 16 + fl * 2 + 1] = make_float4(o8[4], o8[5], o8[6], o8[7]);
  }
}

// ---------------- launch ----------------
extern "C" void kernel_launch(void* const* d_in, const int* in_sizes, int n_in,
                              void* d_out, int out_size, void* d_ws, size_t ws_size,
                              hipStream_t stream) {
  const float* x      = (const float*)d_in[0];
  const int*   src    = (const int*)d_in[1];
  const int*   dst    = (const int*)d_in[2];
  const float* W_gat  = (const float*)d_in[3];
  const float* attn_l = (const float*)d_in[4];
  const float* attn_r = (const float*)d_in[5];
  const float* W1     = (const float*)d_in[6];
  const float* b1     = (const float*)d_in[7];
  const float* W2     = (const float*)d_in[8];
  const float* b2     = (const float*)d_in[9];
  const float* Wc     = (const float*)d_in[10];
  const float* bc     = (const float*)d_in[11];
  float* out = (float*)d_out;

  char* ws = (char*)d_ws;
  size_t off = 0;
  auto walloc = [&](size_t bytes) -> void* {
    void* p = ws + off;
    off += (bytes + 255) & ~size_t(255);
    return p;
  };
  __half* P16     = (__half*)walloc((size_t)N_NODES * 128 * 2);  // gemm out / gather operand
  __half* F16     = (__half*)walloc((size_t)N_NODES * 128 * 2);  // agg out / gemm A operand
  float*  el      = (float*)walloc((size_t)N_NODES * 4);
  float*  er      = (float*)walloc((size_t)N_NODES * 4);
  int*    deg     = (int*)walloc((size_t)N_NODES * 4);
  int*    offs    = (int*)walloc((size_t)(N_NODES + 1) * 4);
  int*    rank    = (int*)walloc((size_t)N_EDGES * 4);
  int*    csr_src = (int*)walloc((size_t)N_EDGES * 4);
  int2*   meta    = (int2*)walloc((size_t)N_EDGES * 8);
  int*    bsum    = (int*)walloc(1024);
  __half* Whl     = (__half*)walloc((size_t)114688 * 2);
  __half* Wg_hl   = Whl;
  __half* W1_hl   = Whl + 32768;
  __half* W2_hl   = Whl + 65536;
  __half* Wc_hl   = Whl + 98304;

  hipMemsetAsync(deg, 0, (size_t)N_NODES * 4, stream);

  const dim3 blk(256);
  const int nwave_blocks = (N_NODES + 3) / 4;
  const int nedge_blocks = (N_EDGES + 255) / 256;
  const int nscan_blocks = (N_NODES + 255) / 256;
  const int ngemm_blocks = (N_NODES + 127) / 128;   // 391

  prep_k<<<dim3(224), blk, 0, stream>>>(W_gat, W1, W2, Wc, Whl);

  // h16 = fp16(x @ W_gat); el/er exact from f32 accs in epilogue
  mgemm_k<128, false, true><<<dim3(ngemm_blocks), blk, 0, stream>>>(
      x, Wg_hl, P16, N_NODES, attn_l, attn_r, el, er);

  hist_k<<<dim3(nedge_blocks), blk, 0, stream>>>(dst, deg, rank, N_EDGES);
  scan1_k<<<dim3(nscan_blocks), blk, 0, stream>>>(deg, offs, bsum, N_NODES);
  scan2_k<<<dim3(1), blk, 0, stream>>>(bsum, nscan_blocks);
  scan3_k<<<dim3(nscan_blocks), blk, 0, stream>>>(offs, deg, bsum, N_NODES);
  scatter_k<<<dim3(nedge_blocks), blk, 0, stream>>>(src, dst, offs, rank, csr_src, N_EDGES);

  // fused: edge softmax (writes meta) + h1 = elu(agg(h16))
  aggsm_k<<<dim3(nwave_blocks), blk, 0, stream>>>(offs, csr_src, el, er, meta, P16, F16, N_NODES);
  // layer 1
  mgemm_k<128, true, false><<<dim3(ngemm_blocks), blk, 0, stream>>>(
      F16, W1_hl, P16, N_NODES, nullptr, nullptr, nullptr, nullptr);
  agg128m_k<<<dim3(nwave_blocks), blk, 0, stream>>>(offs, meta, P16, b1, F16, N_NODES);
  // layer 2
  mgemm_k<128, true, false><<<dim3(ngemm_blocks), blk, 0, stream>>>(
      F16, W2_hl, P16, N_NODES, nullptr, nullptr, nullptr, nullptr);
  agg128m_k<<<dim3(nwave_blocks), blk, 0, stream>>>(offs, meta, P16, b2, F16, N_NODES);
  // classifier
  mgemm_k<64, true, false><<<dim3(ngemm_blocks), blk, 0, stream>>>(
      F16, Wc_hl, P16, N_NODES, nullptr, nullptr, nullptr, nullptr);
  agg64m_k<<<dim3(nwave_blocks), blk, 0, stream>>>(offs, meta, P16, bc, out, N_NODES);
}

// Round 9
// 330.676 us; speedup vs baseline: 2.1254x; 1.0371x over previous
//
#include <hip/hip_runtime.h>
#include <hip/hip_fp16.h>
#include <math.h>

#define N_NODES 50000
#define N_EDGES 800000
#define PAD_EDGES (N_EDGES + 8 * N_NODES)   // degree padded to >=8, multiple of 8
// dims: IN=128, HIDDEN=128, NUM_CLASSES=64 (hard-coded)

typedef _Float16 half8 __attribute__((ext_vector_type(8)));
typedef float floatx16 __attribute__((ext_vector_type(16)));

// ---------------- weight prep: W(f32) -> [hi|lo] fp16 in MFMA-B fragment layout ----------------
__global__ __launch_bounds__(256) void prep_k(const float* __restrict__ Wg,
                                              const float* __restrict__ W1,
                                              const float* __restrict__ W2,
                                              const float* __restrict__ Wc,
                                              __half* __restrict__ out) {
  int e = blockIdx.x * 256 + threadIdx.x;
  const float* W; _Float16* o; int sh, local;
  _Float16* ob = (_Float16*)out;
  if (e < 16384)      { W = Wg; o = ob;         sh = 7; local = e; }
  else if (e < 32768) { W = W1; o = ob + 32768; sh = 7; local = e - 16384; }
  else if (e < 49152) { W = W2; o = ob + 65536; sh = 7; local = e - 32768; }
  else if (e < 57344) { W = Wc; o = ob + 98304; sh = 6; local = e - 49152; }
  else return;
  int NC = 1 << sh;
  int k = local >> sh, n = local & (NC - 1);
  float w = W[k * NC + n];
  _Float16 hi = (_Float16)w;
  float lo = w - (float)hi;
  int oi = (((k >> 3) * NC + n) << 3) | (k & 7);
  o[oi] = hi;
  o[(NC << 7) + oi] = (_Float16)lo;   // +K*NC halves
}

// ---------------- MFMA GEMM: C16[M x NCOL] = fp16( A[M x 128] @ (Whi+Wlo) ) ----------------
template <int NCOL, bool A16, bool ELR>
__global__ __launch_bounds__(256) void mgemm_k(const void* __restrict__ Ap,
                                               const __half* __restrict__ Whl,
                                               __half* __restrict__ C16, int M,
                                               const float* __restrict__ al,
                                               const float* __restrict__ ar,
                                               float* __restrict__ el,
                                               float* __restrict__ er) {
  __shared__ __half Al[16][129][8];
  const int tid  = threadIdx.x;
  const int row0 = blockIdx.x * 128;
  const int lane = tid & 63;
  const int lane31 = lane & 31;
  const int q = lane >> 5;
  const int r = tid >> 6;

  if (A16) {
    const uint4* A8 = (const uint4*)Ap;
    #pragma unroll
    for (int i = 0; i < 8; ++i) {
      int idx = tid + i * 256;
      int row = idx >> 4, c = idx & 15;
      int grow = row0 + row;
      uint4 v = make_uint4(0u, 0u, 0u, 0u);
      if (grow < M) v = A8[grow * 16 + c];
      *reinterpret_cast<uint4*>(&Al[c][row][0]) = v;
    }
  } else {
    const float4* A4 = (const float4*)Ap;
    #pragma unroll
    for (int i = 0; i < 8; ++i) {
      int idx = tid + i * 256;
      int row = idx >> 4, c = idx & 15;
      int grow = row0 + row;
      half8 hv = {};
      if (grow < M) {
        float4 a0 = A4[grow * 32 + c * 2];
        float4 a1 = A4[grow * 32 + c * 2 + 1];
        hv[0] = (_Float16)a0.x; hv[1] = (_Float16)a0.y;
        hv[2] = (_Float16)a0.z; hv[3] = (_Float16)a0.w;
        hv[4] = (_Float16)a1.x; hv[5] = (_Float16)a1.y;
        hv[6] = (_Float16)a1.z; hv[7] = (_Float16)a1.w;
      }
      *reinterpret_cast<half8*>(&Al[c][row][0]) = hv;
    }
  }
  __syncthreads();

  half8 afr[8];
  #pragma unroll
  for (int s = 0; s < 8; ++s)
    afr[s] = *reinterpret_cast<const half8*>(&Al[2 * s + q][r * 32 + lane31][0]);

  const half8* B8 = reinterpret_cast<const half8*>(Whl);
  const int KN8 = 16 * NCOL;

  float elp[16], erp[16];
  if (ELR) {
    #pragma unroll
    for (int i = 0; i < 16; ++i) { elp[i] = 0.f; erp[i] = 0.f; }
  }

  #pragma unroll
  for (int tc = 0; tc < NCOL / 32; ++tc) {
    floatx16 acc = {};
    int nbase = tc * 32 + lane31;
    #pragma unroll
    for (int s = 0; s < 8; ++s) {
      int ci = (2 * s + q) * NCOL + nbase;
      half8 bl = B8[KN8 + ci];
      half8 bh = B8[ci];
      acc = __builtin_amdgcn_mfma_f32_32x32x16_f16(afr[s], bl, acc, 0, 0, 0);
      acc = __builtin_amdgcn_mfma_f32_32x32x16_f16(afr[s], bh, acc, 0, 0, 0);
    }
    if (ELR) {
      float alv = al[nbase], arv = ar[nbase];
      #pragma unroll
      for (int i = 0; i < 16; ++i) {
        elp[i] = fmaf(acc[i], alv, elp[i]);
        erp[i] = fmaf(acc[i], arv, erp[i]);
      }
    }
    #pragma unroll
    for (int i = 0; i < 16; ++i) {
      int rl = (i & 3) + 8 * (i >> 2) + 4 * q;
      int grow = row0 + r * 32 + rl;
      if (grow < M) C16[grow * NCOL + nbase] = __float2half(acc[i]);
    }
  }

  if (ELR) {
    #pragma unroll
    for (int off = 1; off <= 16; off <<= 1) {
      #pragma unroll
      for (int i = 0; i < 16; ++i) {
        elp[i] += __shfl_xor(elp[i], off);
        erp[i] += __shfl_xor(erp[i], off);
      }
    }
    if (lane31 == 0) {
      #pragma unroll
      for (int i = 0; i < 16; ++i) {
        int rl = (i & 3) + 8 * (i >> 2) + 4 * q;
        int grow = row0 + r * 32 + rl;
        if (grow < M) { el[grow] = elp[i]; er[grow] = erp[i]; }
      }
    }
  }
}

// ---------------- CSR build (padded: per-node slot count = max(8, round8(deg))) ----------------
__global__ __launch_bounds__(256) void hist_k(const int* __restrict__ dst,
                                              int* __restrict__ deg,
                                              int* __restrict__ rank, int E) {
  int e = blockIdx.x * 256 + threadIdx.x;
  if (e < E) rank[e] = atomicAdd(&deg[dst[e]], 1);
}

__global__ __launch_bounds__(256) void scan1_k(const int* __restrict__ deg,
                                               int* __restrict__ offs,
                                               int* __restrict__ bsum, int N) {
  __shared__ int s[256];
  int t = threadIdx.x;
  int i = blockIdx.x * 256 + t;
  int v = 0;
  if (i < N) {
    int d = deg[i];
    v = (d + 7) & ~7;
    if (v < 8) v = 8;
  }
  s[t] = v;
  __syncthreads();
  for (int o = 1; o < 256; o <<= 1) {
    int add = (t >= o) ? s[t - o] : 0;
    __syncthreads();
    s[t] += add;
    __syncthreads();
  }
  if (i < N) offs[i] = s[t] - v;
  if (t == 255) bsum[blockIdx.x] = s[255];
}

__global__ __launch_bounds__(256) void scan2_k(int* __restrict__ bsum, int nb) {
  __shared__ int s[256];
  int t = threadIdx.x;
  int v = (t < nb) ? bsum[t] : 0;
  s[t] = v;
  __syncthreads();
  for (int o = 1; o < 256; o <<= 1) {
    int add = (t >= o) ? s[t - o] : 0;
    __syncthreads();
    s[t] += add;
    __syncthreads();
  }
  if (t < nb) bsum[t] = s[t] - v;
}

__global__ __launch_bounds__(256) void scan3_k(int* __restrict__ offs,
                                               const int* __restrict__ deg,
                                               const int* __restrict__ bsum, int N) {
  int i = blockIdx.x * 256 + threadIdx.x;
  if (i < N) {
    int o = offs[i] + bsum[blockIdx.x];
    offs[i] = o;
    if (i == N - 1) {
      int d = deg[i];
      int pd = (d + 7) & ~7;
      if (pd < 8) pd = 8;
      offs[N] = o + pd;
    }
  }
}

__global__ __launch_bounds__(256) void scatter_k(const int* __restrict__ src,
                                                 const int* __restrict__ dst,
                                                 const int* __restrict__ offs,
                                                 const int* __restrict__ rank,
                                                 int* __restrict__ csr_src, int E) {
  int e = blockIdx.x * 256 + threadIdx.x;
  if (e < E) {
    csr_src[offs[dst[e]] + rank[e]] = src[e];
  }
}

__device__ inline void fma8(float2 acc[4], uint4 u, float a) {
  __half2* h = reinterpret_cast<__half2*>(&u);
  #pragma unroll
  for (int j = 0; j < 4; ++j) {
    float2 f = __half22float2(h[j]);
    acc[j].x = fmaf(a, f.x, acc[j].x);
    acc[j].y = fmaf(a, f.y, acc[j].y);
  }
}

// ---------------- fused edge-softmax + agg 128 (GAT layer) ----------------
// Computes alpha in-register, writes padded meta {src*16, alpha} (pad slots = {0,0}
// so later aggs run mask-free), aggregates immediately. ELU via __expf-1 (no libm).
__global__ __launch_bounds__(256) void aggsm_k(const int* __restrict__ offs,
                                               const int* __restrict__ deg,
                                               const int* __restrict__ csr_src,
                                               const float* __restrict__ el,
                                               const float* __restrict__ er,
                                               int2* __restrict__ meta,
                                               const __half* __restrict__ hp,
                                               __half* __restrict__ out, int N) {
  int w    = (blockIdx.x * 256 + threadIdx.x) >> 6;
  int lane = threadIdx.x & 63;
  if (w >= N) return;
  int o0   = offs[w];
  int pcnt = offs[w + 1] - o0;
  int cnt  = deg[w];
  int q   = lane >> 4;
  int fl  = lane & 15;
  const uint4* hpq = reinterpret_cast<const uint4*>(hp);

  int   myS = 0;
  float myA = 0.f;

  if (cnt <= 64) {                       // wave-uniform fast path (covers cnt==0)
    bool valid = lane < cnt;
    float erv = er[w];
    int s = 0;
    float ev = -3.4e38f;
    if (valid) {
      s = csr_src[o0 + lane];
      float e0 = el[s] + erv;
      ev = (e0 >= 0.f) ? e0 : 0.2f * e0;
    }
    float m = ev;
    #pragma unroll
    for (int off = 32; off; off >>= 1) m = fmaxf(m, __shfl_xor(m, off));
    float ee = valid ? __expf(ev - m) : 0.f;
    float sum = ee;
    #pragma unroll
    for (int off = 32; off; off >>= 1) sum += __shfl_xor(sum, off);
    if (valid) {
      float a = ee / sum;
      meta[o0 + lane] = make_int2(s * 16, __float_as_int(a));
      myS = s; myA = a;
    } else if (lane < pcnt) {
      meta[o0 + lane] = make_int2(0, 0);   // zero pad slots
    }
  } else {                               // rare generic path: 3-pass softmax into meta
    float erv = er[w];
    float m = -3.4e38f;
    for (int i = lane; i < cnt; i += 64) {
      int s = csr_src[o0 + i];
      float ev = el[s] + erv;
      ev = (ev >= 0.f) ? ev : 0.2f * ev;
      m = fmaxf(m, ev);
    }
    #pragma unroll
    for (int off = 32; off; off >>= 1) m = fmaxf(m, __shfl_xor(m, off));
    float sum = 0.f;
    for (int i = lane; i < cnt; i += 64) {
      int s = csr_src[o0 + i];
      float ev = el[s] + erv;
      ev = (ev >= 0.f) ? ev : 0.2f * ev;
      float ee = __expf(ev - m);
      meta[o0 + i] = make_int2(s * 16, __float_as_int(ee));
      sum += ee;
    }
    #pragma unroll
    for (int off = 32; off; off >>= 1) sum += __shfl_xor(sum, off);
    float inv = 1.f / sum;
    for (int i = lane; i < cnt; i += 64) {
      int2 mm = meta[o0 + i];
      meta[o0 + i] = make_int2(mm.x, __float_as_int(__int_as_float(mm.y) * inv));
    }
    for (int i = cnt + lane; i < pcnt; i += 64) meta[o0 + i] = make_int2(0, 0);
    if (lane < cnt) {
      int2 mm = meta[o0 + lane];
      myS = mm.x >> 4; myA = __int_as_float(mm.y);
    }
  }

  float2 acc0[4] = {}, acc1[4] = {}, acc2[4] = {}, acc3[4] = {};
  int cntc = cnt < 64 ? cnt : 64;
  if (cntc > 0) {
    int cr = (cntc + 15) & ~15;
    int   sA = __shfl(myS, q),          sB = __shfl(myS, 4 + q);
    int   sC = __shfl(myS, 8 + q),      sD = __shfl(myS, 12 + q);
    float aA = __shfl(myA, q),          aB = __shfl(myA, 4 + q);
    float aC = __shfl(myA, 8 + q),      aD = __shfl(myA, 12 + q);
    uint4 vA = hpq[sA * 16 + fl], vB = hpq[sB * 16 + fl];
    uint4 vC = hpq[sC * 16 + fl], vD = hpq[sD * 16 + fl];
    for (int base = 16; base < cr; base += 16) {
      int   tA = __shfl(myS, base + q),      tB = __shfl(myS, base + 4 + q);
      int   tC = __shfl(myS, base + 8 + q),  tD = __shfl(myS, base + 12 + q);
      float nA = __shfl(myA, base + q),      nB = __shfl(myA, base + 4 + q);
      float nC = __shfl(myA, base + 8 + q),  nD = __shfl(myA, base + 12 + q);
      uint4 wA = hpq[tA * 16 + fl], wB = hpq[tB * 16 + fl];
      uint4 wC = hpq[tC * 16 + fl], wD = hpq[tD * 16 + fl];
      fma8(acc0, vA, aA);
      fma8(acc1, vB, aB);
      fma8(acc2, vC, aC);
      fma8(acc3, vD, aD);
      vA = wA; vB = wB; vC = wC; vD = wD;
      aA = nA; aB = nB; aC = nC; aD = nD;
    }
    fma8(acc0, vA, aA);
    fma8(acc1, vB, aB);
    fma8(acc2, vC, aC);
    fma8(acc3, vD, aD);
  }
  for (int p = o0 + 64 + q; p < o0 + cnt; p += 4) {   // rare degree>64 tail
    int2 mm = meta[p];
    fma8(acc0, hpq[mm.x + fl], __int_as_float(mm.y));
  }
  #pragma unroll
  for (int j = 0; j < 4; ++j) {
    acc0[j].x += acc1[j].x + acc2[j].x + acc3[j].x;
    acc0[j].y += acc1[j].y + acc2[j].y + acc3[j].y;
  }
  #pragma unroll
  for (int off = 16; off <= 32; off <<= 1) {
    #pragma unroll
    for (int j = 0; j < 4; ++j) {
      acc0[j].x += __shfl_xor(acc0[j].x, off);
      acc0[j].y += __shfl_xor(acc0[j].y, off);
    }
  }
  if (q == 0) {
    float o8[8];
    #pragma unroll
    for (int j = 0; j < 4; ++j) { o8[2 * j] = acc0[j].x; o8[2 * j + 1] = acc0[j].y; }
    #pragma unroll
    for (int j = 0; j < 8; ++j) o8[j] = (o8[j] > 0.f) ? o8[j] : (__expf(o8[j]) - 1.f);
    __half2 p0 = __floats2half2_rn(o8[0], o8[1]);
    __half2 p1 = __floats2half2_rn(o8[2], o8[3]);
    __half2 p2 = __floats2half2_rn(o8[4], o8[5]);
    __half2 p3 = __floats2half2_rn(o8[6], o8[7]);
    uint4 pk;
    pk.x = *reinterpret_cast<unsigned*>(&p0);
    pk.y = *reinterpret_cast<unsigned*>(&p1);
    pk.z = *reinterpret_cast<unsigned*>(&p2);
    pk.w = *reinterpret_cast<unsigned*>(&p3);
    *reinterpret_cast<uint4*>(&out[w * 128 + fl * 8]) = pk;
  }
}

// ---------------- agg 128-feat via padded meta: mask-free, shfl-free main loop ----------------
// Quarter-wave per slot group; each quarter broadcast-loads its slot's meta (same addr
// across 16 lanes -> L1 broadcast), 2 slots in flight, 2-stage meta pipeline.
__global__ __launch_bounds__(256) void agg128m_k(const int* __restrict__ offs,
                                                 const int2* __restrict__ meta,
                                                 const __half* __restrict__ hp,
                                                 const float* __restrict__ bias,
                                                 __half* __restrict__ out, int N) {
  int w    = (blockIdx.x * 256 + threadIdx.x) >> 6;
  int lane = threadIdx.x & 63;
  if (w >= N) return;
  int o0 = offs[w], o1 = offs[w + 1];    // padded: (o1-o0) >= 8, multiple of 8
  int q   = lane >> 4;
  int fl  = lane & 15;
  const uint4* hpq = reinterpret_cast<const uint4*>(hp);

  float2 acc0[4] = {}, acc1[4] = {};
  int p = o0 + q;
  int2 mA = meta[p], mB = meta[p + 4];
  for (; p + 8 < o1; p += 8) {
    int2 nA = meta[p + 8], nB = meta[p + 12];
    uint4 vA = hpq[mA.x + fl], vB = hpq[mB.x + fl];
    fma8(acc0, vA, __int_as_float(mA.y));
    fma8(acc1, vB, __int_as_float(mB.y));
    mA = nA; mB = nB;
  }
  {
    uint4 vA = hpq[mA.x + fl], vB = hpq[mB.x + fl];
    fma8(acc0, vA, __int_as_float(mA.y));
    fma8(acc1, vB, __int_as_float(mB.y));
  }
  #pragma unroll
  for (int j = 0; j < 4; ++j) { acc0[j].x += acc1[j].x; acc0[j].y += acc1[j].y; }
  #pragma unroll
  for (int off = 16; off <= 32; off <<= 1) {
    #pragma unroll
    for (int j = 0; j < 4; ++j) {
      acc0[j].x += __shfl_xor(acc0[j].x, off);
      acc0[j].y += __shfl_xor(acc0[j].y, off);
    }
  }
  if (q == 0) {
    float o8[8];
    #pragma unroll
    for (int j = 0; j < 4; ++j) { o8[2 * j] = acc0[j].x; o8[2 * j + 1] = acc0[j].y; }
    float4 b0 = reinterpret_cast<const float4*>(bias)[fl * 2];
    float4 b1 = reinterpret_cast<const float4*>(bias)[fl * 2 + 1];
    o8[0] += b0.x; o8[1] += b0.y; o8[2] += b0.z; o8[3] += b0.w;
    o8[4] += b1.x; o8[5] += b1.y; o8[6] += b1.z; o8[7] += b1.w;
    __half2 p0 = __floats2half2_rn(o8[0], o8[1]);
    __half2 p1 = __floats2half2_rn(o8[2], o8[3]);
    __half2 p2 = __floats2half2_rn(o8[4], o8[5]);
    __half2 p3 = __floats2half2_rn(o8[6], o8[7]);
    uint4 pk;
    pk.x = *reinterpret_cast<unsigned*>(&p0);
    pk.y = *reinterpret_cast<unsigned*>(&p1);
    pk.z = *reinterpret_cast<unsigned*>(&p2);
    pk.w = *reinterpret_cast<unsigned*>(&p3);
    *reinterpret_cast<uint4*>(&out[w * 128 + fl * 8]) = pk;
  }
}

// ---------------- agg 64-feat via padded meta -> f32 out (final logits) ----------------
// Eighth-wave per slot (8 slots of 8 lanes); meta broadcast loads, 2-stage pipeline.
__global__ __launch_bounds__(256) void agg64m_k(const int* __restrict__ offs,
                                                const int2* __restrict__ meta,
                                                const __half* __restrict__ hp,
                                                const float* __restrict__ bias,
                                                float* __restrict__ out, int N) {
  int w    = (blockIdx.x * 256 + threadIdx.x) >> 6;
  int lane = threadIdx.x & 63;
  if (w >= N) return;
  int o0 = offs[w], o1 = offs[w + 1];    // padded, multiple of 8
  int o   = lane >> 3;
  int fl  = lane & 7;
  const uint4* hpq = reinterpret_cast<const uint4*>(hp);

  float2 acc0[4] = {};
  int p = o0 + o;
  int2 mA = meta[p];
  for (; p + 8 < o1; p += 8) {
    int2 nA = meta[p + 8];
    uint4 vA = hpq[(mA.x >> 1) + fl];
    fma8(acc0, vA, __int_as_float(mA.y));
    mA = nA;
  }
  {
    uint4 vA = hpq[(mA.x >> 1) + fl];
    fma8(acc0, vA, __int_as_float(mA.y));
  }
  #pragma unroll
  for (int off = 8; off <= 32; off <<= 1) {
    #pragma unroll
    for (int j = 0; j < 4; ++j) {
      acc0[j].x += __shfl_xor(acc0[j].x, off);
      acc0[j].y += __shfl_xor(acc0[j].y, off);
    }
  }
  if (o == 0) {
    float o8[8];
    #pragma unroll
    for (int j = 0; j < 4; ++j) { o8[2 * j] = acc0[j].x; o8[2 * j + 1] = acc0[j].y; }
    float4 b0 = reinterpret_cast<const float4*>(bias)[fl * 2];
    float4 b1 = reinterpret_cast<const float4*>(bias)[fl * 2 + 1];
    o8[0] += b0.x; o8[1] += b0.y; o8[2] += b0.z; o8[3] += b0.w;
    o8[4] += b1.x; o8[5] += b1.y; o8[6] += b1.z; o8[7] += b1.w;
    float4* outp = reinterpret_cast<float4*>(out);
    outp[w * 16 + fl * 2]     = make_float4(o8[0], o8[1], o8[2], o8[3]);
    outp[w * 16 + fl * 2 + 1] = make_float4(o8[4], o8[5], o8[6], o8[7]);
  }
}

// ---------------- launch ----------------
extern "C" void kernel_launch(void* const* d_in, const int* in_sizes, int n_in,
                              void* d_out, int out_size, void* d_ws, size_t ws_size,
                              hipStream_t stream) {
  const float* x      = (const float*)d_in[0];
  const int*   src    = (const int*)d_in[1];
  const int*   dst    = (const int*)d_in[2];
  const float* W_gat  = (const float*)d_in[3];
  const float* attn_l = (const float*)d_in[4];
  const float* attn_r = (const float*)d_in[5];
  const float* W1     = (const float*)d_in[6];
  const float* b1     = (const float*)d_in[7];
  const float* W2     = (const float*)d_in[8];
  const float* b2     = (const float*)d_in[9];
  const float* Wc     = (const float*)d_in[10];
  const float* bc     = (const float*)d_in[11];
  float* out = (float*)d_out;

  char* ws = (char*)d_ws;
  size_t off = 0;
  auto walloc = [&](size_t bytes) -> void* {
    void* p = ws + off;
    off += (bytes + 255) & ~size_t(255);
    return p;
  };
  __half* P16     = (__half*)walloc((size_t)N_NODES * 128 * 2);  // gemm out / gather operand
  __half* F16     = (__half*)walloc((size_t)N_NODES * 128 * 2);  // agg out / gemm A operand
  float*  el      = (float*)walloc((size_t)N_NODES * 4);
  float*  er      = (float*)walloc((size_t)N_NODES * 4);
  int*    deg     = (int*)walloc((size_t)N_NODES * 4);
  int*    offs    = (int*)walloc((size_t)(N_NODES + 1) * 4);
  int*    rank    = (int*)walloc((size_t)N_EDGES * 4);
  int*    csr_src = (int*)walloc((size_t)PAD_EDGES * 4);
  int2*   meta    = (int2*)walloc((size_t)PAD_EDGES * 8);
  int*    bsum    = (int*)walloc(1024);
  __half* Whl     = (__half*)walloc((size_t)114688 * 2);
  __half* Wg_hl   = Whl;
  __half* W1_hl   = Whl + 32768;
  __half* W2_hl   = Whl + 65536;
  __half* Wc_hl   = Whl + 98304;

  hipMemsetAsync(deg, 0, (size_t)N_NODES * 4, stream);

  const dim3 blk(256);
  const int nwave_blocks = (N_NODES + 3) / 4;
  const int nedge_blocks = (N_EDGES + 255) / 256;
  const int nscan_blocks = (N_NODES + 255) / 256;
  const int ngemm_blocks = (N_NODES + 127) / 128;   // 391

  prep_k<<<dim3(224), blk, 0, stream>>>(W_gat, W1, W2, Wc, Whl);

  // h16 = fp16(x @ W_gat); el/er exact from f32 accs in epilogue
  mgemm_k<128, false, true><<<dim3(ngemm_blocks), blk, 0, stream>>>(
      x, Wg_hl, P16, N_NODES, attn_l, attn_r, el, er);

  hist_k<<<dim3(nedge_blocks), blk, 0, stream>>>(dst, deg, rank, N_EDGES);
  scan1_k<<<dim3(nscan_blocks), blk, 0, stream>>>(deg, offs, bsum, N_NODES);
  scan2_k<<<dim3(1), blk, 0, stream>>>(bsum, nscan_blocks);
  scan3_k<<<dim3(nscan_blocks), blk, 0, stream>>>(offs, deg, bsum, N_NODES);
  scatter_k<<<dim3(nedge_blocks), blk, 0, stream>>>(src, dst, offs, rank, csr_src, N_EDGES);

  // fused: edge softmax (writes padded meta) + h1 = elu(agg(h16))
  aggsm_k<<<dim3(nwave_blocks), blk, 0, stream>>>(offs, deg, csr_src, el, er, meta, P16, F16, N_NODES);
  // layer 1
  mgemm_k<128, true, false><<<dim3(ngemm_blocks), blk, 0, stream>>>(
      F16, W1_hl, P16, N_NODES, nullptr, nullptr, nullptr, nullptr);
  agg128m_k<<<dim3(nwave_blocks), blk, 0, stream>>>(offs, meta, P16, b1, F16, N_NODES);
  // layer 2
  mgemm_k<128, true, false><<<dim3(ngemm_blocks), blk, 0, stream>>>(
      F16, W2_hl, P16, N_NODES, nullptr, nullptr, nullptr, nullptr);
  agg128m_k<<<dim3(nwave_blocks), blk, 0, stream>>>(offs, meta, P16, b2, F16, N_NODES);
  // classifier
  mgemm_k<64, true, false><<<dim3(ngemm_blocks), blk, 0, stream>>>(
      F16, Wc_hl, P16, N_NODES, nullptr, nullptr, nullptr, nullptr);
  agg64m_k<<<dim3(nwave_blocks), blk, 0, stream>>>(offs, meta, P16, bc, out, N_NODES);
}

// Round 10
// 298.097 us; speedup vs baseline: 2.3577x; 1.1093x over previous
//
#include <hip/hip_runtime.h>
#include <hip/hip_fp16.h>
#include <math.h>

#define N_NODES 50000
#define N_EDGES 800000
#define PAD_EDGES (N_EDGES + 8 * N_NODES)   // degree padded to >=8, multiple of 8
// dims: IN=128, HIDDEN=128, NUM_CLASSES=64 (hard-coded)
// Algebra: GraphConv chain is linear ->
//   logits = A^3 (h1 @ Wp) + t*c1 + d*c2 + bc
//   Wp = W1@W2@Wc, c1 = b1@W2@Wc, c2 = b2@Wc, d[v] = [deg_v>0] (=sum alpha), t = A d.

typedef _Float16 half8 __attribute__((ext_vector_type(8)));
typedef float floatx16 __attribute__((ext_vector_type(16)));

// ---------------- prep: Wg(f32) -> [hi|lo] fp16 MFMA-B fragments ----------------
__global__ __launch_bounds__(256) void prep_k(const float* __restrict__ Wg,
                                              __half* __restrict__ out) {
  int e = blockIdx.x * 256 + threadIdx.x;
  if (e >= 16384) return;
  _Float16* o = (_Float16*)out;
  int k = e >> 7, n = e & 127;
  float w = Wg[k * 128 + n];
  _Float16 hi = (_Float16)w;
  float lo = w - (float)hi;
  int oi = (((k >> 3) * 128 + n) << 3) | (k & 7);
  o[oi] = hi;
  o[16384 + oi] = (_Float16)lo;
}

// ---------------- prep12: W12 = W1@W2 (f32), c12 = b1@W2 ----------------
__global__ __launch_bounds__(256) void prep12_k(const float* __restrict__ W1,
                                                const float* __restrict__ W2,
                                                const float* __restrict__ b1,
                                                float* __restrict__ W12,
                                                float* __restrict__ c12) {
  int e = blockIdx.x * 256 + threadIdx.x;
  if (e < 16384) {
    int k = e >> 7, n = e & 127;
    float acc = 0.f;
    for (int j = 0; j < 128; ++j) acc = fmaf(W1[k * 128 + j], W2[j * 128 + n], acc);
    W12[k * 128 + n] = acc;
  } else if (e < 16512) {
    int n = e - 16384;
    float acc = 0.f;
    for (int j = 0; j < 128; ++j) acc = fmaf(b1[j], W2[j * 128 + n], acc);
    c12[n] = acc;
  }
}

// ---------------- prepP: Wp = W12@Wc -> hi/lo frags (NCOL=64); c1 = c12@Wc; c2 = b2@Wc ----------------
__global__ __launch_bounds__(256) void prepP_k(const float* __restrict__ W12,
                                               const float* __restrict__ c12,
                                               const float* __restrict__ Wc,
                                               const float* __restrict__ b2,
                                               __half* __restrict__ WPhl,
                                               float* __restrict__ c1,
                                               float* __restrict__ c2) {
  int e = blockIdx.x * 256 + threadIdx.x;
  _Float16* o = (_Float16*)WPhl;
  if (e < 8192) {
    int k = e >> 6, n = e & 63;
    float acc = 0.f;
    for (int j = 0; j < 128; ++j) acc = fmaf(W12[k * 128 + j], Wc[j * 64 + n], acc);
    _Float16 hi = (_Float16)acc;
    float lo = acc - (float)hi;
    int oi = (((k >> 3) * 64 + n) << 3) | (k & 7);
    o[oi] = hi;
    o[8192 + oi] = (_Float16)lo;
  } else if (e < 8256) {
    int n = e - 8192;
    float acc = 0.f;
    for (int j = 0; j < 128; ++j) acc = fmaf(c12[j], Wc[j * 64 + n], acc);
    c1[n] = acc;
  } else if (e < 8320) {
    int n = e - 8256;
    float acc = 0.f;
    for (int j = 0; j < 128; ++j) acc = fmaf(b2[j], Wc[j * 64 + n], acc);
    c2[n] = acc;
  }
}

// ---------------- MFMA GEMM: C16[M x NCOL] = fp16( A[M x 128] @ (Whi+Wlo) ) ----------------
template <int NCOL, bool A16, bool ELR>
__global__ __launch_bounds__(256) void mgemm_k(const void* __restrict__ Ap,
                                               const __half* __restrict__ Whl,
                                               __half* __restrict__ C16, int M,
                                               const float* __restrict__ al,
                                               const float* __restrict__ ar,
                                               float* __restrict__ el,
                                               float* __restrict__ er) {
  __shared__ __half Al[16][129][8];
  const int tid  = threadIdx.x;
  const int row0 = blockIdx.x * 128;
  const int lane = tid & 63;
  const int lane31 = lane & 31;
  const int q = lane >> 5;
  const int r = tid >> 6;

  if (A16) {
    const uint4* A8 = (const uint4*)Ap;
    #pragma unroll
    for (int i = 0; i < 8; ++i) {
      int idx = tid + i * 256;
      int row = idx >> 4, c = idx & 15;
      int grow = row0 + row;
      uint4 v = make_uint4(0u, 0u, 0u, 0u);
      if (grow < M) v = A8[grow * 16 + c];
      *reinterpret_cast<uint4*>(&Al[c][row][0]) = v;
    }
  } else {
    const float4* A4 = (const float4*)Ap;
    #pragma unroll
    for (int i = 0; i < 8; ++i) {
      int idx = tid + i * 256;
      int row = idx >> 4, c = idx & 15;
      int grow = row0 + row;
      half8 hv = {};
      if (grow < M) {
        float4 a0 = A4[grow * 32 + c * 2];
        float4 a1 = A4[grow * 32 + c * 2 + 1];
        hv[0] = (_Float16)a0.x; hv[1] = (_Float16)a0.y;
        hv[2] = (_Float16)a0.z; hv[3] = (_Float16)a0.w;
        hv[4] = (_Float16)a1.x; hv[5] = (_Float16)a1.y;
        hv[6] = (_Float16)a1.z; hv[7] = (_Float16)a1.w;
      }
      *reinterpret_cast<half8*>(&Al[c][row][0]) = hv;
    }
  }
  __syncthreads();

  half8 afr[8];
  #pragma unroll
  for (int s = 0; s < 8; ++s)
    afr[s] = *reinterpret_cast<const half8*>(&Al[2 * s + q][r * 32 + lane31][0]);

  const half8* B8 = reinterpret_cast<const half8*>(Whl);
  const int KN8 = 16 * NCOL;

  float elp[16], erp[16];
  if (ELR) {
    #pragma unroll
    for (int i = 0; i < 16; ++i) { elp[i] = 0.f; erp[i] = 0.f; }
  }

  #pragma unroll
  for (int tc = 0; tc < NCOL / 32; ++tc) {
    floatx16 acc = {};
    int nbase = tc * 32 + lane31;
    #pragma unroll
    for (int s = 0; s < 8; ++s) {
      int ci = (2 * s + q) * NCOL + nbase;
      half8 bl = B8[KN8 + ci];
      half8 bh = B8[ci];
      acc = __builtin_amdgcn_mfma_f32_32x32x16_f16(afr[s], bl, acc, 0, 0, 0);
      acc = __builtin_amdgcn_mfma_f32_32x32x16_f16(afr[s], bh, acc, 0, 0, 0);
    }
    if (ELR) {
      float alv = al[nbase], arv = ar[nbase];
      #pragma unroll
      for (int i = 0; i < 16; ++i) {
        elp[i] = fmaf(acc[i], alv, elp[i]);
        erp[i] = fmaf(acc[i], arv, erp[i]);
      }
    }
    #pragma unroll
    for (int i = 0; i < 16; ++i) {
      int rl = (i & 3) + 8 * (i >> 2) + 4 * q;
      int grow = row0 + r * 32 + rl;
      if (grow < M) C16[grow * NCOL + nbase] = __float2half(acc[i]);
    }
  }

  if (ELR) {
    #pragma unroll
    for (int off = 1; off <= 16; off <<= 1) {
      #pragma unroll
      for (int i = 0; i < 16; ++i) {
        elp[i] += __shfl_xor(elp[i], off);
        erp[i] += __shfl_xor(erp[i], off);
      }
    }
    if (lane31 == 0) {
      #pragma unroll
      for (int i = 0; i < 16; ++i) {
        int rl = (i & 3) + 8 * (i >> 2) + 4 * q;
        int grow = row0 + r * 32 + rl;
        if (grow < M) { el[grow] = elp[i]; er[grow] = erp[i]; }
      }
    }
  }
}

// ---------------- CSR build (padded: per-node slot count = max(8, round8(deg))) ----------------
__global__ __launch_bounds__(256) void hist_k(const int* __restrict__ dst,
                                              int* __restrict__ deg,
                                              int* __restrict__ rank, int E) {
  int e = blockIdx.x * 256 + threadIdx.x;
  if (e < E) rank[e] = atomicAdd(&deg[dst[e]], 1);
}

__global__ __launch_bounds__(256) void scan1_k(const int* __restrict__ deg,
                                               int* __restrict__ offs,
                                               int* __restrict__ bsum, int N) {
  __shared__ int s[256];
  int t = threadIdx.x;
  int i = blockIdx.x * 256 + t;
  int v = 0;
  if (i < N) {
    int d = deg[i];
    v = (d + 7) & ~7;
    if (v < 8) v = 8;
  }
  s[t] = v;
  __syncthreads();
  for (int o = 1; o < 256; o <<= 1) {
    int add = (t >= o) ? s[t - o] : 0;
    __syncthreads();
    s[t] += add;
    __syncthreads();
  }
  if (i < N) offs[i] = s[t] - v;
  if (t == 255) bsum[blockIdx.x] = s[255];
}

__global__ __launch_bounds__(256) void scan2_k(int* __restrict__ bsum, int nb) {
  __shared__ int s[256];
  int t = threadIdx.x;
  int v = (t < nb) ? bsum[t] : 0;
  s[t] = v;
  __syncthreads();
  for (int o = 1; o < 256; o <<= 1) {
    int add = (t >= o) ? s[t - o] : 0;
    __syncthreads();
    s[t] += add;
    __syncthreads();
  }
  if (t < nb) bsum[t] = s[t] - v;
}

__global__ __launch_bounds__(256) void scan3_k(int* __restrict__ offs,
                                               const int* __restrict__ deg,
                                               const int* __restrict__ bsum, int N) {
  int i = blockIdx.x * 256 + threadIdx.x;
  if (i < N) {
    int o = offs[i] + bsum[blockIdx.x];
    offs[i] = o;
    if (i == N - 1) {
      int d = deg[i];
      int pd = (d + 7) & ~7;
      if (pd < 8) pd = 8;
      offs[N] = o + pd;
    }
  }
}

__global__ __launch_bounds__(256) void scatter_k(const int* __restrict__ src,
                                                 const int* __restrict__ dst,
                                                 const int* __restrict__ offs,
                                                 const int* __restrict__ rank,
                                                 int* __restrict__ csr_src, int E) {
  int e = blockIdx.x * 256 + threadIdx.x;
  if (e < E) {
    csr_src[offs[dst[e]] + rank[e]] = src[e];
  }
}

__device__ inline void fma8(float2 acc[4], uint4 u, float a) {
  __half2* h = reinterpret_cast<__half2*>(&u);
  #pragma unroll
  for (int j = 0; j < 4; ++j) {
    float2 f = __half22float2(h[j]);
    acc[j].x = fmaf(a, f.x, acc[j].x);
    acc[j].y = fmaf(a, f.y, acc[j].y);
  }
}

// ---------------- fused edge-softmax + t + agg 128 (GAT layer) ----------------
// alpha in-register; padded meta {src*16, alpha} (pads {0,0}); t[w] = sum alpha*[deg[src]>0];
// aggregates h16 immediately -> h1 = elu(.) fp16.
__global__ __launch_bounds__(256) void aggsm_k(const int* __restrict__ offs,
                                               const int* __restrict__ deg,
                                               const int* __restrict__ csr_src,
                                               const float* __restrict__ el,
                                               const float* __restrict__ er,
                                               int2* __restrict__ meta,
                                               float* __restrict__ t,
                                               const __half* __restrict__ hp,
                                               __half* __restrict__ out, int N) {
  int w    = (blockIdx.x * 256 + threadIdx.x) >> 6;
  int lane = threadIdx.x & 63;
  if (w >= N) return;
  int o0   = offs[w];
  int pcnt = offs[w + 1] - o0;
  int cnt  = deg[w];
  int q   = lane >> 4;
  int fl  = lane & 15;
  const uint4* hpq = reinterpret_cast<const uint4*>(hp);

  int   myS = 0;
  float myA = 0.f;

  if (cnt <= 64) {                       // wave-uniform fast path (covers cnt==0)
    bool valid = lane < cnt;
    float erv = er[w];
    int s = 0;
    float ev = -3.4e38f;
    if (valid) {
      s = csr_src[o0 + lane];
      float e0 = el[s] + erv;
      ev = (e0 >= 0.f) ? e0 : 0.2f * e0;
    }
    float m = ev;
    #pragma unroll
    for (int off = 32; off; off >>= 1) m = fmaxf(m, __shfl_xor(m, off));
    float ee = valid ? __expf(ev - m) : 0.f;
    float sum = ee;
    #pragma unroll
    for (int off = 32; off; off >>= 1) sum += __shfl_xor(sum, off);
    float tp = 0.f;
    if (valid) {
      float a = ee / sum;
      meta[o0 + lane] = make_int2(s * 16, __float_as_int(a));
      myS = s; myA = a;
      tp = (deg[s] > 0) ? a : 0.f;
    } else if (lane < pcnt) {
      meta[o0 + lane] = make_int2(0, 0);   // zero pad slots
    }
    #pragma unroll
    for (int off = 32; off; off >>= 1) tp += __shfl_xor(tp, off);
    if (lane == 0) t[w] = tp;
  } else {                               // rare generic path
    float erv = er[w];
    float m = -3.4e38f;
    for (int i = lane; i < cnt; i += 64) {
      int s = csr_src[o0 + i];
      float ev = el[s] + erv;
      ev = (ev >= 0.f) ? ev : 0.2f * ev;
      m = fmaxf(m, ev);
    }
    #pragma unroll
    for (int off = 32; off; off >>= 1) m = fmaxf(m, __shfl_xor(m, off));
    float sum = 0.f, tacc = 0.f;
    for (int i = lane; i < cnt; i += 64) {
      int s = csr_src[o0 + i];
      float ev = el[s] + erv;
      ev = (ev >= 0.f) ? ev : 0.2f * ev;
      float ee = __expf(ev - m);
      meta[o0 + i] = make_int2(s * 16, __float_as_int(ee));
      sum += ee;
      tacc += (deg[s] > 0) ? ee : 0.f;
    }
    #pragma unroll
    for (int off = 32; off; off >>= 1) {
      sum += __shfl_xor(sum, off);
      tacc += __shfl_xor(tacc, off);
    }
    float inv = 1.f / sum;
    if (lane == 0) t[w] = tacc * inv;
    for (int i = lane; i < cnt; i += 64) {
      int2 mm = meta[o0 + i];
      meta[o0 + i] = make_int2(mm.x, __float_as_int(__int_as_float(mm.y) * inv));
    }
    for (int i = cnt + lane; i < pcnt; i += 64) meta[o0 + i] = make_int2(0, 0);
    if (lane < cnt) {
      int2 mm = meta[o0 + lane];
      myS = mm.x >> 4; myA = __int_as_float(mm.y);
    }
  }

  float2 acc0[4] = {}, acc1[4] = {}, acc2[4] = {}, acc3[4] = {};
  int cntc = cnt < 64 ? cnt : 64;
  if (cntc > 0) {
    int cr = (cntc + 15) & ~15;
    int   sA = __shfl(myS, q),          sB = __shfl(myS, 4 + q);
    int   sC = __shfl(myS, 8 + q),      sD = __shfl(myS, 12 + q);
    float aA = __shfl(myA, q),          aB = __shfl(myA, 4 + q);
    float aC = __shfl(myA, 8 + q),      aD = __shfl(myA, 12 + q);
    uint4 vA = hpq[sA * 16 + fl], vB = hpq[sB * 16 + fl];
    uint4 vC = hpq[sC * 16 + fl], vD = hpq[sD * 16 + fl];
    for (int base = 16; base < cr; base += 16) {
      int   tA = __shfl(myS, base + q),      tB = __shfl(myS, base + 4 + q);
      int   tC = __shfl(myS, base + 8 + q),  tD = __shfl(myS, base + 12 + q);
      float nA = __shfl(myA, base + q),      nB = __shfl(myA, base + 4 + q);
      float nC = __shfl(myA, base + 8 + q),  nD = __shfl(myA, base + 12 + q);
      uint4 wA = hpq[tA * 16 + fl], wB = hpq[tB * 16 + fl];
      uint4 wC = hpq[tC * 16 + fl], wD = hpq[tD * 16 + fl];
      fma8(acc0, vA, aA);
      fma8(acc1, vB, aB);
      fma8(acc2, vC, aC);
      fma8(acc3, vD, aD);
      vA = wA; vB = wB; vC = wC; vD = wD;
      aA = nA; aB = nB; aC = nC; aD = nD;
    }
    fma8(acc0, vA, aA);
    fma8(acc1, vB, aB);
    fma8(acc2, vC, aC);
    fma8(acc3, vD, aD);
  }
  for (int p = o0 + 64 + q; p < o0 + cnt; p += 4) {   // rare degree>64 tail
    int2 mm = meta[p];
    fma8(acc0, hpq[mm.x + fl], __int_as_float(mm.y));
  }
  #pragma unroll
  for (int j = 0; j < 4; ++j) {
    acc0[j].x += acc1[j].x + acc2[j].x + acc3[j].x;
    acc0[j].y += acc1[j].y + acc2[j].y + acc3[j].y;
  }
  #pragma unroll
  for (int off = 16; off <= 32; off <<= 1) {
    #pragma unroll
    for (int j = 0; j < 4; ++j) {
      acc0[j].x += __shfl_xor(acc0[j].x, off);
      acc0[j].y += __shfl_xor(acc0[j].y, off);
    }
  }
  if (q == 0) {
    float o8[8];
    #pragma unroll
    for (int j = 0; j < 4; ++j) { o8[2 * j] = acc0[j].x; o8[2 * j + 1] = acc0[j].y; }
    #pragma unroll
    for (int j = 0; j < 8; ++j) o8[j] = (o8[j] > 0.f) ? o8[j] : (__expf(o8[j]) - 1.f);
    __half2 p0 = __floats2half2_rn(o8[0], o8[1]);
    __half2 p1 = __floats2half2_rn(o8[2], o8[3]);
    __half2 p2 = __floats2half2_rn(o8[4], o8[5]);
    __half2 p3 = __floats2half2_rn(o8[6], o8[7]);
    uint4 pk;
    pk.x = *reinterpret_cast<unsigned*>(&p0);
    pk.y = *reinterpret_cast<unsigned*>(&p1);
    pk.z = *reinterpret_cast<unsigned*>(&p2);
    pk.w = *reinterpret_cast<unsigned*>(&p3);
    *reinterpret_cast<uint4*>(&out[w * 128 + fl * 8]) = pk;
  }
}

// ---------------- agg 64-feat via padded meta, mask-free ----------------
// Eighth-wave per slot; FINAL adds t*c1 + d*c2 + bc and writes f32; else fp16.
template <bool FINAL>
__global__ __launch_bounds__(256) void agg64v_k(const int* __restrict__ offs,
                                                const int2* __restrict__ meta,
                                                const __half* __restrict__ zp,
                                                const float* __restrict__ t,
                                                const int* __restrict__ deg,
                                                const float* __restrict__ c1,
                                                const float* __restrict__ c2,
                                                const float* __restrict__ bc,
                                                void* __restrict__ outp, int N) {
  int w    = (blockIdx.x * 256 + threadIdx.x) >> 6;
  int lane = threadIdx.x & 63;
  if (w >= N) return;
  int o0 = offs[w], o1 = offs[w + 1];    // padded, multiple of 8
  int o   = lane >> 3;
  int fl  = lane & 7;
  const uint4* hpq = reinterpret_cast<const uint4*>(zp);

  float2 acc0[4] = {};
  int p = o0 + o;
  int2 mA = meta[p];
  for (; p + 8 < o1; p += 8) {
    int2 nA = meta[p + 8];
    uint4 vA = hpq[(mA.x >> 1) + fl];
    fma8(acc0, vA, __int_as_float(mA.y));
    mA = nA;
  }
  {
    uint4 vA = hpq[(mA.x >> 1) + fl];
    fma8(acc0, vA, __int_as_float(mA.y));
  }
  #pragma unroll
  for (int off = 8; off <= 32; off <<= 1) {
    #pragma unroll
    for (int j = 0; j < 4; ++j) {
      acc0[j].x += __shfl_xor(acc0[j].x, off);
      acc0[j].y += __shfl_xor(acc0[j].y, off);
    }
  }
  if (o == 0) {
    float o8[8];
    #pragma unroll
    for (int j = 0; j < 4; ++j) { o8[2 * j] = acc0[j].x; o8[2 * j + 1] = acc0[j].y; }
    if (FINAL) {
      float tw = t[w];
      float dw = (deg[w] > 0) ? 1.f : 0.f;
      float4 a0 = reinterpret_cast<const float4*>(c1)[fl * 2];
      float4 a1 = reinterpret_cast<const float4*>(c1)[fl * 2 + 1];
      float4 d0 = reinterpret_cast<const float4*>(c2)[fl * 2];
      float4 d1 = reinterpret_cast<const float4*>(c2)[fl * 2 + 1];
      float4 b0 = reinterpret_cast<const float4*>(bc)[fl * 2];
      float4 b1v = reinterpret_cast<const float4*>(bc)[fl * 2 + 1];
      o8[0] += tw * a0.x + dw * d0.x + b0.x;
      o8[1] += tw * a0.y + dw * d0.y + b0.y;
      o8[2] += tw * a0.z + dw * d0.z + b0.z;
      o8[3] += tw * a0.w + dw * d0.w + b0.w;
      o8[4] += tw * a1.x + dw * d1.x + b1v.x;
      o8[5] += tw * a1.y + dw * d1.y + b1v.y;
      o8[6] += tw * a1.z + dw * d1.z + b1v.z;
      o8[7] += tw * a1.w + dw * d1.w + b1v.w;
      float4* of = reinterpret_cast<float4*>(outp);
      of[w * 16 + fl * 2]     = make_float4(o8[0], o8[1], o8[2], o8[3]);
      of[w * 16 + fl * 2 + 1] = make_float4(o8[4], o8[5], o8[6], o8[7]);
    } else {
      __half2 p0 = __floats2half2_rn(o8[0], o8[1]);
      __half2 p1 = __floats2half2_rn(o8[2], o8[3]);
      __half2 p2 = __floats2half2_rn(o8[4], o8[5]);
      __half2 p3 = __floats2half2_rn(o8[6], o8[7]);
      uint4 pk;
      pk.x = *reinterpret_cast<unsigned*>(&p0);
      pk.y = *reinterpret_cast<unsigned*>(&p1);
      pk.z = *reinterpret_cast<unsigned*>(&p2);
      pk.w = *reinterpret_cast<unsigned*>(&p3);
      reinterpret_cast<uint4*>(outp)[w * 8 + fl] = pk;
    }
  }
}

// ---------------- launch ----------------
extern "C" void kernel_launch(void* const* d_in, const int* in_sizes, int n_in,
                              void* d_out, int out_size, void* d_ws, size_t ws_size,
                              hipStream_t stream) {
  const float* x      = (const float*)d_in[0];
  const int*   src    = (const int*)d_in[1];
  const int*   dst    = (const int*)d_in[2];
  const float* W_gat  = (const float*)d_in[3];
  const float* attn_l = (const float*)d_in[4];
  const float* attn_r = (const float*)d_in[5];
  const float* W1     = (const float*)d_in[6];
  const float* b1     = (const float*)d_in[7];
  const float* W2     = (const float*)d_in[8];
  const float* b2     = (const float*)d_in[9];
  const float* Wc     = (const float*)d_in[10];
  const float* bc     = (const float*)d_in[11];
  float* out = (float*)d_out;

  char* ws = (char*)d_ws;
  size_t off = 0;
  auto walloc = [&](size_t bytes) -> void* {
    void* p = ws + off;
    off += (bytes + 255) & ~size_t(255);
    return p;
  };
  __half* P16     = (__half*)walloc((size_t)N_NODES * 128 * 2);  // h16 / z / z3
  __half* F16     = (__half*)walloc((size_t)N_NODES * 128 * 2);  // h1 / z2
  float*  el      = (float*)walloc((size_t)N_NODES * 4);
  float*  er      = (float*)walloc((size_t)N_NODES * 4);
  float*  tbuf    = (float*)walloc((size_t)N_NODES * 4);
  int*    deg     = (int*)walloc((size_t)N_NODES * 4);
  int*    offs    = (int*)walloc((size_t)(N_NODES + 1) * 4);
  int*    rank    = (int*)walloc((size_t)N_EDGES * 4);
  int*    csr_src = (int*)walloc((size_t)PAD_EDGES * 4);
  int2*   meta    = (int2*)walloc((size_t)PAD_EDGES * 8);
  int*    bsum    = (int*)walloc(1024);
  __half* Wg_hl   = (__half*)walloc((size_t)32768 * 2);
  __half* WP_hl   = (__half*)walloc((size_t)16384 * 2);
  float*  W12     = (float*)walloc((size_t)16384 * 4);
  float*  c12     = (float*)walloc((size_t)128 * 4);
  float*  c1      = (float*)walloc((size_t)64 * 4);
  float*  c2      = (float*)walloc((size_t)64 * 4);

  hipMemsetAsync(deg, 0, (size_t)N_NODES * 4, stream);

  const dim3 blk(256);
  const int nwave_blocks = (N_NODES + 3) / 4;
  const int nedge_blocks = (N_EDGES + 255) / 256;
  const int nscan_blocks = (N_NODES + 255) / 256;
  const int ngemm_blocks = (N_NODES + 127) / 128;   // 391

  prep_k<<<dim3(64), blk, 0, stream>>>(W_gat, Wg_hl);
  prep12_k<<<dim3(65), blk, 0, stream>>>(W1, W2, b1, W12, c12);
  prepP_k<<<dim3(33), blk, 0, stream>>>(W12, c12, Wc, b2, WP_hl, c1, c2);

  // h16 = fp16(x @ W_gat); el/er exact from f32 accs in epilogue
  mgemm_k<128, false, true><<<dim3(ngemm_blocks), blk, 0, stream>>>(
      x, Wg_hl, P16, N_NODES, attn_l, attn_r, el, er);

  hist_k<<<dim3(nedge_blocks), blk, 0, stream>>>(dst, deg, rank, N_EDGES);
  scan1_k<<<dim3(nscan_blocks), blk, 0, stream>>>(deg, offs, bsum, N_NODES);
  scan2_k<<<dim3(1), blk, 0, stream>>>(bsum, nscan_blocks);
  scan3_k<<<dim3(nscan_blocks), blk, 0, stream>>>(offs, deg, bsum, N_NODES);
  scatter_k<<<dim3(nedge_blocks), blk, 0, stream>>>(src, dst, offs, rank, csr_src, N_EDGES);

  // fused: edge softmax (padded meta + t) + h1 = elu(A h16)  [F16]
  aggsm_k<<<dim3(nwave_blocks), blk, 0, stream>>>(offs, deg, csr_src, el, er, meta, tbuf, P16, F16, N_NODES);
  // z = fp16(h1 @ Wp)  [P16, 64-dim]
  mgemm_k<64, true, false><<<dim3(ngemm_blocks), blk, 0, stream>>>(
      F16, WP_hl, P16, N_NODES, nullptr, nullptr, nullptr, nullptr);
  // z2 = A z  [F16], z3 = A z2  [P16], logits = A z3 + t*c1 + d*c2 + bc
  agg64v_k<false><<<dim3(nwave_blocks), blk, 0, stream>>>(offs, meta, P16, nullptr, nullptr, nullptr, nullptr, nullptr, F16, N_NODES);
  agg64v_k<false><<<dim3(nwave_blocks), blk, 0, stream>>>(offs, meta, F16, nullptr, nullptr, nullptr, nullptr, nullptr, P16, N_NODES);
  agg64v_k<true><<<dim3(nwave_blocks), blk, 0, stream>>>(offs, meta, P16, tbuf, deg, c1, c2, bc, out, N_NODES);
}

// Round 11
// 284.003 us; speedup vs baseline: 2.4747x; 1.0496x over previous
//
#include <hip/hip_runtime.h>
#include <hip/hip_fp16.h>
#include <math.h>

#define N_NODES 50000
#define N_EDGES 800000
#define PAD_EDGES (N_EDGES + 8 * N_NODES)   // degree padded to >=8, multiple of 8
// dims: IN=128, HIDDEN=128, NUM_CLASSES=64 (hard-coded)
// Algebra: GraphConv chain is linear ->
//   logits = A^3 (h1 @ Wp) + t*c1 + d*c2 + bc
//   Wp = W1@W2@Wc, c1 = b1@W2@Wc, c2 = b2@Wc, d[v] = [deg_v>0] (=sum alpha), t = A d.

typedef _Float16 half8 __attribute__((ext_vector_type(8)));
typedef float floatx16 __attribute__((ext_vector_type(16)));

// ---------------- prep A: Wg -> hi/lo frags; W12 = W1@W2; c12 = b1@W2 ----------------
__global__ __launch_bounds__(256) void prep_a_k(const float* __restrict__ Wg,
                                                const float* __restrict__ W1,
                                                const float* __restrict__ W2,
                                                const float* __restrict__ b1,
                                                __half* __restrict__ Wg_hl,
                                                float* __restrict__ W12,
                                                float* __restrict__ c12) {
  int e = blockIdx.x * 256 + threadIdx.x;
  if (e < 16384) {
    _Float16* o = (_Float16*)Wg_hl;
    int k = e >> 7, n = e & 127;
    float w = Wg[k * 128 + n];
    _Float16 hi = (_Float16)w;
    float lo = w - (float)hi;
    int oi = (((k >> 3) * 128 + n) << 3) | (k & 7);
    o[oi] = hi;
    o[16384 + oi] = (_Float16)lo;
  } else if (e < 32768) {
    int local = e - 16384;
    int k = local >> 7, n = local & 127;
    float acc = 0.f;
    for (int j = 0; j < 128; ++j) acc = fmaf(W1[k * 128 + j], W2[j * 128 + n], acc);
    W12[k * 128 + n] = acc;
  } else if (e < 32896) {
    int n = e - 32768;
    float acc = 0.f;
    for (int j = 0; j < 128; ++j) acc = fmaf(b1[j], W2[j * 128 + n], acc);
    c12[n] = acc;
  }
}

// ---------------- prepP: Wp = W12@Wc -> hi/lo frags (NCOL=64); c1 = c12@Wc; c2 = b2@Wc ----------------
__global__ __launch_bounds__(256) void prepP_k(const float* __restrict__ W12,
                                               const float* __restrict__ c12,
                                               const float* __restrict__ Wc,
                                               const float* __restrict__ b2,
                                               __half* __restrict__ WPhl,
                                               float* __restrict__ c1,
                                               float* __restrict__ c2) {
  int e = blockIdx.x * 256 + threadIdx.x;
  _Float16* o = (_Float16*)WPhl;
  if (e < 8192) {
    int k = e >> 6, n = e & 63;
    float acc = 0.f;
    for (int j = 0; j < 128; ++j) acc = fmaf(W12[k * 128 + j], Wc[j * 64 + n], acc);
    _Float16 hi = (_Float16)acc;
    float lo = acc - (float)hi;
    int oi = (((k >> 3) * 64 + n) << 3) | (k & 7);
    o[oi] = hi;
    o[8192 + oi] = (_Float16)lo;
  } else if (e < 8256) {
    int n = e - 8192;
    float acc = 0.f;
    for (int j = 0; j < 128; ++j) acc = fmaf(c12[j], Wc[j * 64 + n], acc);
    c1[n] = acc;
  } else if (e < 8320) {
    int n = e - 8256;
    float acc = 0.f;
    for (int j = 0; j < 128; ++j) acc = fmaf(b2[j], Wc[j * 64 + n], acc);
    c2[n] = acc;
  }
}

// ---------------- MFMA GEMM: C16[M x NCOL] = fp16( A[M x 128] @ (Whi+Wlo) ) ----------------
template <int NCOL, bool A16, bool ELR>
__global__ __launch_bounds__(256) void mgemm_k(const void* __restrict__ Ap,
                                               const __half* __restrict__ Whl,
                                               __half* __restrict__ C16, int M,
                                               const float* __restrict__ al,
                                               const float* __restrict__ ar,
                                               float* __restrict__ el,
                                               float* __restrict__ er) {
  __shared__ __half Al[16][129][8];
  const int tid  = threadIdx.x;
  const int row0 = blockIdx.x * 128;
  const int lane = tid & 63;
  const int lane31 = lane & 31;
  const int q = lane >> 5;
  const int r = tid >> 6;

  if (A16) {
    const uint4* A8 = (const uint4*)Ap;
    #pragma unroll
    for (int i = 0; i < 8; ++i) {
      int idx = tid + i * 256;
      int row = idx >> 4, c = idx & 15;
      int grow = row0 + row;
      uint4 v = make_uint4(0u, 0u, 0u, 0u);
      if (grow < M) v = A8[grow * 16 + c];
      *reinterpret_cast<uint4*>(&Al[c][row][0]) = v;
    }
  } else {
    const float4* A4 = (const float4*)Ap;
    #pragma unroll
    for (int i = 0; i < 8; ++i) {
      int idx = tid + i * 256;
      int row = idx >> 4, c = idx & 15;
      int grow = row0 + row;
      half8 hv = {};
      if (grow < M) {
        float4 a0 = A4[grow * 32 + c * 2];
        float4 a1 = A4[grow * 32 + c * 2 + 1];
        hv[0] = (_Float16)a0.x; hv[1] = (_Float16)a0.y;
        hv[2] = (_Float16)a0.z; hv[3] = (_Float16)a0.w;
        hv[4] = (_Float16)a1.x; hv[5] = (_Float16)a1.y;
        hv[6] = (_Float16)a1.z; hv[7] = (_Float16)a1.w;
      }
      *reinterpret_cast<half8*>(&Al[c][row][0]) = hv;
    }
  }
  __syncthreads();

  half8 afr[8];
  #pragma unroll
  for (int s = 0; s < 8; ++s)
    afr[s] = *reinterpret_cast<const half8*>(&Al[2 * s + q][r * 32 + lane31][0]);

  const half8* B8 = reinterpret_cast<const half8*>(Whl);
  const int KN8 = 16 * NCOL;

  float elp[16], erp[16];
  if (ELR) {
    #pragma unroll
    for (int i = 0; i < 16; ++i) { elp[i] = 0.f; erp[i] = 0.f; }
  }

  #pragma unroll
  for (int tc = 0; tc < NCOL / 32; ++tc) {
    floatx16 acc = {};
    int nbase = tc * 32 + lane31;
    #pragma unroll
    for (int s = 0; s < 8; ++s) {
      int ci = (2 * s + q) * NCOL + nbase;
      half8 bl = B8[KN8 + ci];
      half8 bh = B8[ci];
      acc = __builtin_amdgcn_mfma_f32_32x32x16_f16(afr[s], bl, acc, 0, 0, 0);
      acc = __builtin_amdgcn_mfma_f32_32x32x16_f16(afr[s], bh, acc, 0, 0, 0);
    }
    if (ELR) {
      float alv = al[nbase], arv = ar[nbase];
      #pragma unroll
      for (int i = 0; i < 16; ++i) {
        elp[i] = fmaf(acc[i], alv, elp[i]);
        erp[i] = fmaf(acc[i], arv, erp[i]);
      }
    }
    #pragma unroll
    for (int i = 0; i < 16; ++i) {
      int rl = (i & 3) + 8 * (i >> 2) + 4 * q;
      int grow = row0 + r * 32 + rl;
      if (grow < M) C16[grow * NCOL + nbase] = __float2half(acc[i]);
    }
  }

  if (ELR) {
    #pragma unroll
    for (int off = 1; off <= 16; off <<= 1) {
      #pragma unroll
      for (int i = 0; i < 16; ++i) {
        elp[i] += __shfl_xor(elp[i], off);
        erp[i] += __shfl_xor(erp[i], off);
      }
    }
    if (lane31 == 0) {
      #pragma unroll
      for (int i = 0; i < 16; ++i) {
        int rl = (i & 3) + 8 * (i >> 2) + 4 * q;
        int grow = row0 + r * 32 + rl;
        if (grow < M) { el[grow] = elp[i]; er[grow] = erp[i]; }
      }
    }
  }
}

// ---------------- CSR build (padded: per-node slot count = max(8, round8(deg))) ----------------
__global__ __launch_bounds__(256) void hist_k(const int* __restrict__ dst,
                                              int* __restrict__ deg,
                                              int* __restrict__ rank, int E) {
  int e = blockIdx.x * 256 + threadIdx.x;
  if (e < E) rank[e] = atomicAdd(&deg[dst[e]], 1);
}

__global__ __launch_bounds__(256) void scan1_k(const int* __restrict__ deg,
                                               int* __restrict__ offs,
                                               int* __restrict__ bsum, int N) {
  __shared__ int s[256];
  int t = threadIdx.x;
  int i = blockIdx.x * 256 + t;
  int v = 0;
  if (i < N) {
    int d = deg[i];
    v = (d + 7) & ~7;
    if (v < 8) v = 8;
  }
  s[t] = v;
  __syncthreads();
  for (int o = 1; o < 256; o <<= 1) {
    int add = (t >= o) ? s[t - o] : 0;
    __syncthreads();
    s[t] += add;
    __syncthreads();
  }
  if (i < N) offs[i] = s[t] - v;
  if (t == 255) bsum[blockIdx.x] = s[255];
}

__global__ __launch_bounds__(256) void scan2_k(int* __restrict__ bsum, int nb) {
  __shared__ int s[256];
  int t = threadIdx.x;
  int v = (t < nb) ? bsum[t] : 0;
  s[t] = v;
  __syncthreads();
  for (int o = 1; o < 256; o <<= 1) {
    int add = (t >= o) ? s[t - o] : 0;
    __syncthreads();
    s[t] += add;
    __syncthreads();
  }
  if (t < nb) bsum[t] = s[t] - v;
}

// scan3 also packs el2[i] = {el[i], deg[i]>0 ? 1 : 0} -> one random line/edge in softmax
__global__ __launch_bounds__(256) void scan3_k(int* __restrict__ offs,
                                               const int* __restrict__ deg,
                                               const int* __restrict__ bsum,
                                               const float* __restrict__ el,
                                               float2* __restrict__ el2, int N) {
  int i = blockIdx.x * 256 + threadIdx.x;
  if (i < N) {
    int o = offs[i] + bsum[blockIdx.x];
    offs[i] = o;
    int d = deg[i];
    el2[i] = make_float2(el[i], (d > 0) ? 1.f : 0.f);
    if (i == N - 1) {
      int pd = (d + 7) & ~7;
      if (pd < 8) pd = 8;
      offs[N] = o + pd;
    }
  }
}

__global__ __launch_bounds__(256) void scatter_k(const int* __restrict__ src,
                                                 const int* __restrict__ dst,
                                                 const int* __restrict__ offs,
                                                 const int* __restrict__ rank,
                                                 int* __restrict__ csr_src, int E) {
  int e = blockIdx.x * 256 + threadIdx.x;
  if (e < E) {
    csr_src[offs[dst[e]] + rank[e]] = src[e];
  }
}

__device__ inline void fma8(float2 acc[4], uint4 u, float a) {
  __half2* h = reinterpret_cast<__half2*>(&u);
  #pragma unroll
  for (int j = 0; j < 4; ++j) {
    float2 f = __half22float2(h[j]);
    acc[j].x = fmaf(a, f.x, acc[j].x);
    acc[j].y = fmaf(a, f.y, acc[j].y);
  }
}

// ---------------- fused edge-softmax + t + agg 128 (GAT layer), LDS-staged meta ----------------
// Softmax in-register -> padded global meta {src*16, alpha} (pads {0,0}) AND per-wave
// LDS copy. Aggregation loop then runs mask-free off LDS (2 ds_read_b64 broadcasts
// per 8 edges -- no shfl machinery, no lane<cnt masks). t[w] = sum alpha*[deg_src>0].
__global__ __launch_bounds__(256) void aggsm_k(const int* __restrict__ offs,
                                               const int* __restrict__ deg,
                                               const int* __restrict__ csr_src,
                                               const float2* __restrict__ el2,
                                               const float* __restrict__ er,
                                               int2* __restrict__ meta,
                                               float* __restrict__ t,
                                               const __half* __restrict__ hp,
                                               __half* __restrict__ out, int N) {
  __shared__ int2 lmeta[4][64];
  int wv   = threadIdx.x >> 6;
  int w    = (blockIdx.x * 256 + threadIdx.x) >> 6;
  int lane = threadIdx.x & 63;
  if (w >= N) return;
  int o0   = offs[w];
  int pcnt = offs[w + 1] - o0;
  int cnt  = deg[w];
  int q  = lane >> 4;
  int fl = lane & 15;
  const uint4* hpq = reinterpret_cast<const uint4*>(hp);

  if (cnt <= 64) {                       // wave-uniform fast path (covers cnt==0)
    bool valid = lane < cnt;
    float erv = er[w];
    int s = 0;
    float ev = -3.4e38f, flag = 0.f;
    if (valid) {
      s = csr_src[o0 + lane];
      float2 e2 = el2[s];
      float e0 = e2.x + erv;
      ev = (e0 >= 0.f) ? e0 : 0.2f * e0;
      flag = e2.y;
    }
    float m = ev;
    #pragma unroll
    for (int off = 32; off; off >>= 1) m = fmaxf(m, __shfl_xor(m, off));
    float ee = valid ? __expf(ev - m) : 0.f;
    float sum = ee, tp = ee * flag;
    #pragma unroll
    for (int off = 32; off; off >>= 1) {
      sum += __shfl_xor(sum, off);
      tp  += __shfl_xor(tp, off);
    }
    float inv = (cnt > 0) ? 1.f / sum : 0.f;
    int2 mm = make_int2(0, 0);
    if (valid) mm = make_int2(s * 16, __float_as_int(ee * inv));
    if (lane < pcnt) meta[o0 + lane] = mm;
    lmeta[wv][lane] = mm;
    if (lane == 0) t[w] = tp * inv;
  } else {                               // rare generic path (degree > 64)
    float erv = er[w];
    float m = -3.4e38f;
    for (int i = lane; i < cnt; i += 64) {
      int s = csr_src[o0 + i];
      float2 e2 = el2[s];
      float ev = e2.x + erv;
      ev = (ev >= 0.f) ? ev : 0.2f * ev;
      m = fmaxf(m, ev);
    }
    #pragma unroll
    for (int off = 32; off; off >>= 1) m = fmaxf(m, __shfl_xor(m, off));
    float sum = 0.f, tacc = 0.f;
    int myS = 0; float myE = 0.f;
    for (int i = lane; i < cnt; i += 64) {
      int s = csr_src[o0 + i];
      float2 e2 = el2[s];
      float ev = e2.x + erv;
      ev = (ev >= 0.f) ? ev : 0.2f * ev;
      float ee = __expf(ev - m);
      meta[o0 + i] = make_int2(s * 16, __float_as_int(ee));
      sum += ee;
      tacc += ee * e2.y;
      if (i == lane) { myS = s; myE = ee; }   // register-capture slot 'lane'
    }
    #pragma unroll
    for (int off = 32; off; off >>= 1) {
      sum  += __shfl_xor(sum, off);
      tacc += __shfl_xor(tacc, off);
    }
    float inv = 1.f / sum;
    if (lane == 0) t[w] = tacc * inv;
    for (int i = lane; i < cnt; i += 64) {
      int2 mm = meta[o0 + i];
      meta[o0 + i] = make_int2(mm.x, __float_as_int(__int_as_float(mm.y) * inv));
    }
    for (int i = cnt + lane; i < pcnt; i += 64) meta[o0 + i] = make_int2(0, 0);
    lmeta[wv][lane] = make_int2(myS * 16, __float_as_int(myE * inv));
  }

  // mask-free aggregation: LDS meta for first <=64 slots, global meta for rare tail.
  float2 acc0[4] = {}, acc1[4] = {};
  int pc = pcnt < 64 ? pcnt : 64;        // multiple of 8, >= 8
  int2 mA = lmeta[wv][q], mB = lmeta[wv][4 + q];
  for (int base = 8; base < pc; base += 8) {
    int2 nA = lmeta[wv][base + q], nB = lmeta[wv][base + 4 + q];
    uint4 vA = hpq[mA.x + fl], vB = hpq[mB.x + fl];
    fma8(acc0, vA, __int_as_float(mA.y));
    fma8(acc1, vB, __int_as_float(mB.y));
    mA = nA; mB = nB;
  }
  {
    uint4 vA = hpq[mA.x + fl], vB = hpq[mB.x + fl];
    fma8(acc0, vA, __int_as_float(mA.y));
    fma8(acc1, vB, __int_as_float(mB.y));
  }
  for (int p = o0 + 64 + q; p < o0 + pcnt; p += 4) {   // degree>64 tail (pads zeroed)
    int2 mm = meta[p];
    fma8(acc0, hpq[mm.x + fl], __int_as_float(mm.y));
  }
  #pragma unroll
  for (int j = 0; j < 4; ++j) { acc0[j].x += acc1[j].x; acc0[j].y += acc1[j].y; }
  #pragma unroll
  for (int off = 16; off <= 32; off <<= 1) {
    #pragma unroll
    for (int j = 0; j < 4; ++j) {
      acc0[j].x += __shfl_xor(acc0[j].x, off);
      acc0[j].y += __shfl_xor(acc0[j].y, off);
    }
  }
  if (q == 0) {
    float o8[8];
    #pragma unroll
    for (int j = 0; j < 4; ++j) { o8[2 * j] = acc0[j].x; o8[2 * j + 1] = acc0[j].y; }
    #pragma unroll
    for (int j = 0; j < 8; ++j) o8[j] = (o8[j] > 0.f) ? o8[j] : (__expf(o8[j]) - 1.f);
    __half2 p0 = __floats2half2_rn(o8[0], o8[1]);
    __half2 p1 = __floats2half2_rn(o8[2], o8[3]);
    __half2 p2 = __floats2half2_rn(o8[4], o8[5]);
    __half2 p3 = __floats2half2_rn(o8[6], o8[7]);
    uint4 pk;
    pk.x = *reinterpret_cast<unsigned*>(&p0);
    pk.y = *reinterpret_cast<unsigned*>(&p1);
    pk.z = *reinterpret_cast<unsigned*>(&p2);
    pk.w = *reinterpret_cast<unsigned*>(&p3);
    *reinterpret_cast<uint4*>(&out[w * 128 + fl * 8]) = pk;
  }
}

// ---------------- agg 64-feat via padded meta, mask-free ----------------
// Eighth-wave per slot; FINAL adds t*c1 + d*c2 + bc and writes f32; else fp16.
template <bool FINAL>
__global__ __launch_bounds__(256) void agg64v_k(const int* __restrict__ offs,
                                                const int2* __restrict__ meta,
                                                const __half* __restrict__ zp,
                                                const float* __restrict__ t,
                                                const int* __restrict__ deg,
                                                const float* __restrict__ c1,
                                                const float* __restrict__ c2,
                                                const float* __restrict__ bc,
                                                void* __restrict__ outp, int N) {
  int w    = (blockIdx.x * 256 + threadIdx.x) >> 6;
  int lane = threadIdx.x & 63;
  if (w >= N) return;
  int o0 = offs[w], o1 = offs[w + 1];    // padded, multiple of 8
  int o   = lane >> 3;
  int fl  = lane & 7;
  const uint4* hpq = reinterpret_cast<const uint4*>(zp);

  float2 acc0[4] = {};
  int p = o0 + o;
  int2 mA = meta[p];
  for (; p + 8 < o1; p += 8) {
    int2 nA = meta[p + 8];
    uint4 vA = hpq[(mA.x >> 1) + fl];
    fma8(acc0, vA, __int_as_float(mA.y));
    mA = nA;
  }
  {
    uint4 vA = hpq[(mA.x >> 1) + fl];
    fma8(acc0, vA, __int_as_float(mA.y));
  }
  #pragma unroll
  for (int off = 8; off <= 32; off <<= 1) {
    #pragma unroll
    for (int j = 0; j < 4; ++j) {
      acc0[j].x += __shfl_xor(acc0[j].x, off);
      acc0[j].y += __shfl_xor(acc0[j].y, off);
    }
  }
  if (o == 0) {
    float o8[8];
    #pragma unroll
    for (int j = 0; j < 4; ++j) { o8[2 * j] = acc0[j].x; o8[2 * j + 1] = acc0[j].y; }
    if (FINAL) {
      float tw = t[w];
      float dw = (deg[w] > 0) ? 1.f : 0.f;
      float4 a0 = reinterpret_cast<const float4*>(c1)[fl * 2];
      float4 a1 = reinterpret_cast<const float4*>(c1)[fl * 2 + 1];
      float4 d0 = reinterpret_cast<const float4*>(c2)[fl * 2];
      float4 d1 = reinterpret_cast<const float4*>(c2)[fl * 2 + 1];
      float4 b0 = reinterpret_cast<const float4*>(bc)[fl * 2];
      float4 b1v = reinterpret_cast<const float4*>(bc)[fl * 2 + 1];
      o8[0] += tw * a0.x + dw * d0.x + b0.x;
      o8[1] += tw * a0.y + dw * d0.y + b0.y;
      o8[2] += tw * a0.z + dw * d0.z + b0.z;
      o8[3] += tw * a0.w + dw * d0.w + b0.w;
      o8[4] += tw * a1.x + dw * d1.x + b1v.x;
      o8[5] += tw * a1.y + dw * d1.y + b1v.y;
      o8[6] += tw * a1.z + dw * d1.z + b1v.z;
      o8[7] += tw * a1.w + dw * d1.w + b1v.w;
      float4* of = reinterpret_cast<float4*>(outp);
      of[w * 16 + fl * 2]     = make_float4(o8[0], o8[1], o8[2], o8[3]);
      of[w * 16 + fl * 2 + 1] = make_float4(o8[4], o8[5], o8[6], o8[7]);
    } else {
      __half2 p0 = __floats2half2_rn(o8[0], o8[1]);
      __half2 p1 = __floats2half2_rn(o8[2], o8[3]);
      __half2 p2 = __floats2half2_rn(o8[4], o8[5]);
      __half2 p3 = __floats2half2_rn(o8[6], o8[7]);
      uint4 pk;
      pk.x = *reinterpret_cast<unsigned*>(&p0);
      pk.y = *reinterpret_cast<unsigned*>(&p1);
      pk.z = *reinterpret_cast<unsigned*>(&p2);
      pk.w = *reinterpret_cast<unsigned*>(&p3);
      reinterpret_cast<uint4*>(outp)[w * 8 + fl] = pk;
    }
  }
}

// ---------------- launch ----------------
extern "C" void kernel_launch(void* const* d_in, const int* in_sizes, int n_in,
                              void* d_out, int out_size, void* d_ws, size_t ws_size,
                              hipStream_t stream) {
  const float* x      = (const float*)d_in[0];
  const int*   src    = (const int*)d_in[1];
  const int*   dst    = (const int*)d_in[2];
  const float* W_gat  = (const float*)d_in[3];
  const float* attn_l = (const float*)d_in[4];
  const float* attn_r = (const float*)d_in[5];
  const float* W1     = (const float*)d_in[6];
  const float* b1     = (const float*)d_in[7];
  const float* W2     = (const float*)d_in[8];
  const float* b2     = (const float*)d_in[9];
  const float* Wc     = (const float*)d_in[10];
  const float* bc     = (const float*)d_in[11];
  float* out = (float*)d_out;

  char* ws = (char*)d_ws;
  size_t off = 0;
  auto walloc = [&](size_t bytes) -> void* {
    void* p = ws + off;
    off += (bytes + 255) & ~size_t(255);
    return p;
  };
  __half* P16     = (__half*)walloc((size_t)N_NODES * 128 * 2);  // h16 / z / z3
  __half* F16     = (__half*)walloc((size_t)N_NODES * 128 * 2);  // h1 / z2
  float*  el      = (float*)walloc((size_t)N_NODES * 4);
  float*  er      = (float*)walloc((size_t)N_NODES * 4);
  float2* el2     = (float2*)walloc((size_t)N_NODES * 8);
  float*  tbuf    = (float*)walloc((size_t)N_NODES * 4);
  int*    deg     = (int*)walloc((size_t)N_NODES * 4);
  int*    offs    = (int*)walloc((size_t)(N_NODES + 1) * 4);
  int*    rank    = (int*)walloc((size_t)N_EDGES * 4);
  int*    csr_src = (int*)walloc((size_t)PAD_EDGES * 4);
  int2*   meta    = (int2*)walloc((size_t)PAD_EDGES * 8);
  int*    bsum    = (int*)walloc(1024);
  __half* Wg_hl   = (__half*)walloc((size_t)32768 * 2);
  __half* WP_hl   = (__half*)walloc((size_t)16384 * 2);
  float*  W12     = (float*)walloc((size_t)16384 * 4);
  float*  c12     = (float*)walloc((size_t)128 * 4);
  float*  c1      = (float*)walloc((size_t)64 * 4);
  float*  c2      = (float*)walloc((size_t)64 * 4);

  hipMemsetAsync(deg, 0, (size_t)N_NODES * 4, stream);

  const dim3 blk(256);
  const int nwave_blocks = (N_NODES + 3) / 4;
  const int nedge_blocks = (N_EDGES + 255) / 256;
  const int nscan_blocks = (N_NODES + 255) / 256;
  const int ngemm_blocks = (N_NODES + 127) / 128;   // 391

  prep_a_k<<<dim3(129), blk, 0, stream>>>(W_gat, W1, W2, b1, Wg_hl, W12, c12);
  prepP_k<<<dim3(33), blk, 0, stream>>>(W12, c12, Wc, b2, WP_hl, c1, c2);

  // h16 = fp16(x @ W_gat); el/er exact from f32 accs in epilogue
  mgemm_k<128, false, true><<<dim3(ngemm_blocks), blk, 0, stream>>>(
      x, Wg_hl, P16, N_NODES, attn_l, attn_r, el, er);

  hist_k<<<dim3(nedge_blocks), blk, 0, stream>>>(dst, deg, rank, N_EDGES);
  scan1_k<<<dim3(nscan_blocks), blk, 0, stream>>>(deg, offs, bsum, N_NODES);
  scan2_k<<<dim3(1), blk, 0, stream>>>(bsum, nscan_blocks);
  scan3_k<<<dim3(nscan_blocks), blk, 0, stream>>>(offs, deg, bsum, el, el2, N_NODES);
  scatter_k<<<dim3(nedge_blocks), blk, 0, stream>>>(src, dst, offs, rank, csr_src, N_EDGES);

  // fused: edge softmax (padded meta + t) + h1 = elu(A h16)  [F16]
  aggsm_k<<<dim3(nwave_blocks), blk, 0, stream>>>(offs, deg, csr_src, el2, er, meta, tbuf, P16, F16, N_NODES);
  // z = fp16(h1 @ Wp)  [P16, 64-dim]
  mgemm_k<64, true, false><<<dim3(ngemm_blocks), blk, 0, stream>>>(
      F16, WP_hl, P16, N_NODES, nullptr, nullptr, nullptr, nullptr);
  // z2 = A z  [F16], z3 = A z2  [P16], logits = A z3 + t*c1 + d*c2 + bc
  agg64v_k<false><<<dim3(nwave_blocks), blk, 0, stream>>>(offs, meta, P16, nullptr, nullptr, nullptr, nullptr, nullptr, F16, N_NODES);
  agg64v_k<false><<<dim3(nwave_blocks), blk, 0, stream>>>(offs, meta, F16, nullptr, nullptr, nullptr, nullptr, nullptr, P16, N_NODES);
  agg64v_k<true><<<dim3(nwave_blocks), blk, 0, stream>>>(offs, meta, P16, tbuf, deg, c1, c2, bc, out, N_NODES);
}